// Round 14
// baseline (716.689 us; speedup 1.0000x reference)
//
#include <hip/hip_runtime.h>
#include <cstdint>
#include <cstddef>

// ---------------------------------------------------------------------------
// ParityGameGATNetwork: 3x GATConv -> JK bidirectional LSTM -> node/edge MLPs
// Round 14: (a) edge MLP processed in CSR order (k_edge3): P[row] loaded once
// per node into regs (205MB -> 12.8MB of P gathers), output scattered via
// eidx recorded in k_fill; (b) LSTM score reduction via per-wave partials
// scoreW[12][64] instead of ~2300 contended LDS atomics per block;
// (c) k_zeroi -> hipMemsetAsync. Everything else = round 13.
// ---------------------------------------------------------------------------

#define NIN 28
#define MAXJOBS 20

struct InPtrs { const void* p[NIN]; int n[NIN]; };

struct ConvJobs {
    const void* src[MAXJOBS];
    float* dst[MAXJOBS];
    int n[MAXJOBS];
    int ai[MAXJOBS];
    int blk0[MAXJOBS + 1];
    int njobs;
};

typedef short s16x4 __attribute__((ext_vector_type(4)));
typedef short s16x8 __attribute__((ext_vector_type(8)));
typedef float f32x4 __attribute__((ext_vector_type(4)));
typedef unsigned short u16x8 __attribute__((ext_vector_type(8)));

__device__ __forceinline__ float bf2f(unsigned short v) {
    unsigned int u = ((unsigned int)v) << 16;
    return __uint_as_float(u);
}

__device__ __forceinline__ unsigned short f2bf(float x) {
    unsigned int u = __float_as_uint(x);
    unsigned int r = u + 0x7fffu + ((u >> 16) & 1u);
    return (unsigned short)(r >> 16);
}

__device__ __forceinline__ float rdx(const void* p, size_t i, int isf32) {
    return isf32 ? ((const float*)p)[i] : bf2f(((const unsigned short*)p)[i]);
}

__device__ __forceinline__ float frcp(float x) {        // raw v_rcp_f32 (~1ulp)
    return __builtin_amdgcn_rcpf(x);
}

__device__ __forceinline__ float sigm(float x) {
    return frcp(1.f + __expf(-x));
}

__device__ __forceinline__ float fast_tanh(float x) {
    return 1.f - 2.f * frcp(__expf(2.f * x) + 1.f);
}

// ---------------- dtype sniffing -------------------------------------------
__global__ void k_sniff(InPtrs in, int* flags) {
    int ai = blockIdx.x;
    if (ai >= NIN) return;
    __shared__ int cnt;
    if (threadIdx.x == 0) cnt = 0;
    __syncthreads();
    if (ai == 1) {
        const int* w = (const int*)in.p[1];
        int nw = in.n[1] < 512 ? in.n[1] : 512;
        int local = 0;
        for (int i = threadIdx.x; i < nw; i += blockDim.x)
            if ((i & 1) && w[i] != 0) local++;
        atomicAdd(&cnt, local);
        __syncthreads();
        if (threadIdx.x == 0) flags[1] = (cnt < 4) ? 1 : 0;
        return;
    }
    const unsigned short* u = (const unsigned short*)in.p[ai];
    int ns = in.n[ai] < 256 ? in.n[ai] : 256;
    int local = 0;
    for (int i = threadIdx.x; i < ns; i += blockDim.x) {
        if (i & 1) continue;
        unsigned short v = u[i];
        int e = (v >> 7) & 0xff;
        if ((v & 0x7fff) != 0 && (e < 100 || e > 154)) local++;
    }
    atomicAdd(&cnt, local);
    __syncthreads();
    if (threadIdx.x == 0) flags[ai] = (cnt * 4 >= ns) ? 1 : 0;
}

// ---------------- batched canonicalization ---------------------------------
__global__ void k_convall(ConvJobs J, const int* __restrict__ flags) {
    int b = blockIdx.x;
    int j = 0;
    while (j + 1 < J.njobs && b >= J.blk0[j + 1]) ++j;
    int i = (b - J.blk0[j]) * 256 + threadIdx.x;
    if (i >= J.n[j]) return;
    J.dst[j][i] = rdx(J.src[j], i, flags[J.ai[j]]);
}

__global__ void k_conve(const void* src, int* row, int* col, int E, const int* flags) {
    int i = blockIdx.x * blockDim.x + threadIdx.x;
    if (i >= E) return;
    if (flags[1]) {
        const long long* s = (const long long*)src;
        row[i] = (int)s[i];
        col[i] = (int)s[(size_t)E + i];
    } else {
        const int* s = (const int*)src;
        row[i] = s[i];
        col[i] = s[(size_t)E + i];
    }
}

// ---------------- CSR build ------------------------------------------------
__global__ void k_hist(const int* __restrict__ row, int* __restrict__ cnt, int E) {
    int i = blockIdx.x * blockDim.x + threadIdx.x;
    if (i < E) atomicAdd(&cnt[row[i]], 1);
}

__global__ void k_scan1(const int* __restrict__ deg, int* __restrict__ indptr,
                        int* __restrict__ bsums, int N) {
    __shared__ int buf[1024];
    const int t = threadIdx.x;
    const int base = blockIdx.x * 1024;
    int v = (base + t < N) ? deg[base + t] : 0;
    buf[t] = v;
    __syncthreads();
    for (int ofs = 1; ofs < 1024; ofs <<= 1) {
        int add = (t >= ofs) ? buf[t - ofs] : 0;
        __syncthreads();
        buf[t] += add;
        __syncthreads();
    }
    if (base + t < N) indptr[base + t] = buf[t] - v;
    if (t == 1023) bsums[blockIdx.x] = buf[1023];
}

__global__ void k_scan2(int* bsums, int nb) {
    if (threadIdx.x == 0 && blockIdx.x == 0) {
        int acc = 0;
        for (int j = 0; j < nb; ++j) { int v = bsums[j]; bsums[j] = acc; acc += v; }
        bsums[nb] = acc;
    }
}

__global__ void k_scan3(const int* __restrict__ bsums, int* __restrict__ indptr,
                        int N, int nb) {
    int i = blockIdx.x * blockDim.x + threadIdx.x;
    if (i < N) indptr[i] += bsums[i >> 10];
    if (i == 0) indptr[N] = bsums[nb];
}

__global__ void k_fill(const int* __restrict__ row, const int* __restrict__ col,
                       const int* __restrict__ indptr, int* __restrict__ cur,
                       int* __restrict__ colS, int* __restrict__ eidx, int E) {
    int i = blockIdx.x * blockDim.x + threadIdx.x;
    if (i >= E) return;
    int r = row[i];
    int p = indptr[r] + atomicAdd(&cur[r], 1);
    colS[p] = col[i];
    eidx[p] = i;
}

// ---------------- GAT linear layer 0 (in=3), hlin out bf16 -----------------
__global__ __launch_bounds__(256) void k_lin0(
    const float* __restrict__ x, const float* __restrict__ W0,
    const float* __restrict__ asrc, const float* __restrict__ adst,
    unsigned short* __restrict__ hlin, float* __restrict__ hs, float* __restrict__ hd,
    int N) {
    const int wid = threadIdx.x >> 6, lane = threadIdx.x & 63;
    const int n = blockIdx.x * 4 + wid;
    if (n >= N) return;
    float x0 = x[(size_t)n * 3], x1 = x[(size_t)n * 3 + 1], x2 = x[(size_t)n * 3 + 2];
    const int c0 = lane, c1 = lane + 64;
    float h0 = x0 * W0[c0] + x1 * W0[128 + c0] + x2 * W0[256 + c0];
    float h1 = x0 * W0[c1] + x1 * W0[128 + c1] + x2 * W0[256 + c1];
    hlin[(size_t)n * 128 + c0] = f2bf(h0);
    hlin[(size_t)n * 128 + c1] = f2bf(h1);
    float sp = h0 * asrc[c0] + h1 * asrc[c1];
    float dp = h0 * adst[c0] + h1 * adst[c1];
    for (int o = 32; o; o >>= 1) { sp += __shfl_down(sp, o); dp += __shfl_down(dp, o); }
    if (lane == 0) { hs[n] = sp; hd[n] = dp; }
}

// ---------------- GAT linear (bf16 in/out), 4 nodes/wave -------------------
__global__ __launch_bounds__(256) void k_lin(
    const unsigned short* __restrict__ xin, const float* __restrict__ W,
    const float* __restrict__ asrc, const float* __restrict__ adst,
    unsigned short* __restrict__ hlin, float* __restrict__ hs, float* __restrict__ hd,
    int N) {
    __shared__ float xl[16][128];
    const int t = threadIdx.x;
    const int wid = t >> 6, lane = t & 63;
    const int nb = blockIdx.x * 16;
    for (int i = t; i < 2048; i += 256) {
        int r = i >> 7, k = i & 127;
        int n = nb + r;
        xl[r][k] = (n < N) ? bf2f(xin[(size_t)n * 128 + k]) : 0.f;
    }
    __syncthreads();
    const int c0 = lane, c1 = lane + 64;
    const int r0 = wid * 4;
    float h0[4], h1[4];
    #pragma unroll
    for (int j = 0; j < 4; ++j) { h0[j] = 0.f; h1[j] = 0.f; }
    #pragma unroll 2
    for (int k = 0; k < 128; ++k) {
        float w0 = W[k * 128 + c0], w1 = W[k * 128 + c1];
        #pragma unroll
        for (int j = 0; j < 4; ++j) {
            float xv = xl[r0 + j][k];
            h0[j] += xv * w0;
            h1[j] += xv * w1;
        }
    }
    float sp[4], dp[4];
    #pragma unroll
    for (int j = 0; j < 4; ++j) {
        sp[j] = h0[j] * asrc[c0] + h1[j] * asrc[c1];
        dp[j] = h0[j] * adst[c0] + h1[j] * adst[c1];
    }
    #pragma unroll
    for (int o = 32; o; o >>= 1) {
        #pragma unroll
        for (int j = 0; j < 4; ++j) {
            sp[j] += __shfl_down(sp[j], o);
            dp[j] += __shfl_down(dp[j], o);
        }
    }
    #pragma unroll
    for (int j = 0; j < 4; ++j) {
        int n = nb + r0 + j;
        if (n < N) {
            hlin[(size_t)n * 128 + c0] = f2bf(h0[j]);
            hlin[(size_t)n * 128 + c1] = f2bf(h1[j]);
            if (lane == 0) { hs[n] = sp[j]; hd[n] = dp[j]; }
        }
    }
}

// ---------------- GAT aggregation: online segment softmax, 8-way unrolled --
__global__ __launch_bounds__(256) void k_aggr(
    const unsigned short* __restrict__ hlin, const float* __restrict__ hs,
    const float* __restrict__ hd,
    const int* __restrict__ indptr, const int* __restrict__ colS,
    const float* __restrict__ b, unsigned short* __restrict__ xout, int N) {
    const int wid = threadIdx.x >> 6, lane = threadIdx.x & 63;
    const int n = blockIdx.x * 4 + wid;
    if (n >= N) return;
    const int s = indptr[n], epos = indptr[n + 1];
    const float hdv = hd[n];
    const int c0 = lane, c1 = lane + 64;
    float m = -1e30f, d = 0.f, a0 = 0.f, a1 = 0.f;
    int idx = s;
    for (; idx + 8 <= epos; idx += 8) {
        int cl[8];
        #pragma unroll
        for (int j = 0; j < 8; ++j) cl[j] = colS[idx + j];
        float e[8];
        #pragma unroll
        for (int j = 0; j < 8; ++j) {
            float ev = hs[cl[j]] + hdv;
            e[j] = (ev > 0.f) ? ev : 0.2f * ev;
        }
        float v0[8], v1[8];
        #pragma unroll
        for (int j = 0; j < 8; ++j) {
            const unsigned short* hp = hlin + (size_t)cl[j] * 128;
            v0[j] = bf2f(hp[c0]);
            v1[j] = bf2f(hp[c1]);
        }
        float m8 = e[0];
        #pragma unroll
        for (int j = 1; j < 8; ++j) m8 = fmaxf(m8, e[j]);
        if (m8 > m) {
            float sc = __expf(m - m8);
            a0 *= sc; a1 *= sc; d *= sc; m = m8;
        }
        #pragma unroll
        for (int j = 0; j < 8; ++j) {
            float w = __expf(e[j] - m);
            a0 += w * v0[j];
            a1 += w * v1[j];
            d  += w;
        }
    }
    for (; idx < epos; ++idx) {
        int col = colS[idx];
        float e = hs[col] + hdv;
        e = (e > 0.f) ? e : 0.2f * e;
        const unsigned short* hr = hlin + (size_t)col * 128;
        float v0 = bf2f(hr[c0]), v1 = bf2f(hr[c1]);
        if (e > m) {
            float sc = __expf(m - e);
            a0 = a0 * sc + v0;
            a1 = a1 * sc + v1;
            d  = d * sc + 1.f;
            m  = e;
        } else {
            float w = __expf(e - m);
            a0 += w * v0;
            a1 += w * v1;
            d  += w;
        }
    }
    float inv = frcp(d + 1e-16f);
    float r0 = a0 * inv + b[c0];
    float r1 = a1 * inv + b[c1];
    xout[(size_t)n * 128 + c0] = f2bf(fmaxf(r0, 0.f));
    xout[(size_t)n * 128 + c1] = f2bf(fmaxf(r1, 0.f));
}

// ---------------- LSTM weight pack into MFMA fragment order ----------------
__global__ void k_wpack(const void* Wihf, const void* Whhf,
                        const void* Wihb, const void* Whhb,
                        const void* bihf, const void* bhhf,
                        const void* bihb, const void* bhhb,
                        const int* __restrict__ flags,
                        unsigned short* __restrict__ Bpack, float* __restrict__ bsum) {
    int idx = blockIdx.x * blockDim.x + threadIdx.x;
    const int TOT = 2 * 10 * 48 * 512;
    if (idx < TOT) {
        int dir = idx / (10 * 48 * 512);
        int r   = idx % (10 * 48 * 512);
        int kb  = r / (48 * 512);
        int r2  = r % (48 * 512);
        int f   = r2 / 512;
        int q   = r2 % 512;
        int lane = q >> 3, j = q & 7;
        int k   = kb * 32 + ((j >> 2) * 16) + ((lane >> 4) * 4) + (j & 3);
        int col = f * 16 + (lane & 15);
        float v;
        if (k < 128)
            v = dir ? rdx(Wihb, (size_t)col * 128 + k, flags[14])
                    : rdx(Wihf, (size_t)col * 128 + k, flags[10]);
        else
            v = dir ? rdx(Whhb, (size_t)col * 192 + (k - 128), flags[15])
                    : rdx(Whhf, (size_t)col * 192 + (k - 128), flags[11]);
        Bpack[idx] = f2bf(v);
    }
    if (idx < 2 * 768) {
        int d = idx / 768, j = idx % 768;
        bsum[idx] = d ? rdx(bihb, j, flags[16]) + rdx(bhhb, j, flags[17])
                      : rdx(bihf, j, flags[12]) + rdx(bhhf, j, flags[13]);
    }
}

// ---------------- fused bidirectional LSTM: 64 rows, 12 waves --------------
// Grid (ceil(N/64), 2); 768 threads = 12 waves. Wave bf owns gate-frags
// {bf, bf+12, bf+24, bf+36} across 4 row-frags. B ping-pong prefetch.
// Score reduction via race-free per-wave partials scoreW[12][64] (no atomics).
__global__ __launch_bounds__(768, 3) void k_lstm_mfma(
    const unsigned short* __restrict__ xsb,  // [3][N][128] bf16
    const unsigned short* __restrict__ Bpack,// [2][10][48][512] bf16
    const float* __restrict__ bsum,          // [2][768]
    const float* __restrict__ attW,          // [384]
    float* __restrict__ scoreP,              // [2][3][N]
    int N) {
    __shared__ unsigned short AS[64][332];   // x:[0,128)  h:[128,320)
    __shared__ float scoreW[12][64];
    const int t = threadIdx.x;
    const int bf = t >> 6, lane = t & 63;
    const int dir = blockIdx.y;
    const int n0 = blockIdx.x * 64;
    const int ccol = lane & 15;
    const int klane = lane >> 4;
    const int lrow = klane * 4;
    const int akl = klane * 4;
    const int m = bf * 16 + ccol;            // this thread's hidden unit

    const float bI = bsum[dir * 768 + m];
    const float bF = bsum[dir * 768 + 192 + m];
    const float bG = bsum[dir * 768 + 384 + m];
    const float bO = bsum[dir * 768 + 576 + m];
    const float awt = attW[dir * 192 + m];
    float cst[16];
    #pragma unroll
    for (int i = 0; i < 16; ++i) cst[i] = 0.f;

    const unsigned short* Bd = Bpack + (size_t)dir * 10 * 48 * 512;

    for (int s = 0; s < 3; ++s) {
        const int l = dir ? (2 - s) : s;
        // ---- stage x tile: 64x128 bf16 ----
        {
            const unsigned short* xsrc = xsb + ((size_t)l * N + n0) * 128;
            for (int i = t; i < 1024; i += 768) {
                int r = i >> 4, kq = (i & 15) * 8;
                u16x8 v = (u16x8)(0);
                if (n0 + r < N) v = *(const u16x8*)(xsrc + (size_t)r * 128 + kq);
                *(u16x8*)&AS[r][kq] = v;
            }
        }
        __syncthreads();

        // ---- MFMA GEMM over K, B ping-pong prefetch ----
        const int KB = s ? 10 : 4;               // both even
        f32x4 acc[4][4];
        #pragma unroll
        for (int rf = 0; rf < 4; ++rf)
            #pragma unroll
            for (int g = 0; g < 4; ++g) acc[rf][g] = (f32x4)(0.f);
        s16x8 bA[4], bB[4];
        {
            const unsigned short* bb = Bd + (size_t)bf * 512 + lane * 8;   // kb=0
            #pragma unroll
            for (int g = 0; g < 4; ++g) bA[g] = *(const s16x8*)(bb + (size_t)g * 6144);
        }
        for (int kb = 0; kb < KB; kb += 2) {
            {   // prefetch kb+1
                const unsigned short* bb = Bd + ((size_t)(kb + 1) * 48 + bf) * 512 + lane * 8;
                #pragma unroll
                for (int g = 0; g < 4; ++g) bB[g] = *(const s16x8*)(bb + (size_t)g * 6144);
            }
            {   // compute kb on bA
                const int k0 = kb * 32 + akl;
                s16x8 av[4];
                #pragma unroll
                for (int rf = 0; rf < 4; ++rf) {
                    s16x4 alo = *(const s16x4*)&AS[rf * 16 + ccol][k0];
                    s16x4 ahi = *(const s16x4*)&AS[rf * 16 + ccol][k0 + 16];
                    av[rf] = __builtin_shufflevector(alo, ahi, 0, 1, 2, 3, 4, 5, 6, 7);
                }
                #pragma unroll
                for (int rf = 0; rf < 4; ++rf)
                    #pragma unroll
                    for (int g = 0; g < 4; ++g)
                        acc[rf][g] = __builtin_amdgcn_mfma_f32_16x16x32_bf16(
                            av[rf], bA[g], acc[rf][g], 0, 0, 0);
            }
            if (kb + 2 < KB) {   // prefetch kb+2
                const unsigned short* bb = Bd + ((size_t)(kb + 2) * 48 + bf) * 512 + lane * 8;
                #pragma unroll
                for (int g = 0; g < 4; ++g) bA[g] = *(const s16x8*)(bb + (size_t)g * 6144);
            }
            {   // compute kb+1 on bB
                const int k0 = (kb + 1) * 32 + akl;
                s16x8 av[4];
                #pragma unroll
                for (int rf = 0; rf < 4; ++rf) {
                    s16x4 alo = *(const s16x4*)&AS[rf * 16 + ccol][k0];
                    s16x4 ahi = *(const s16x4*)&AS[rf * 16 + ccol][k0 + 16];
                    av[rf] = __builtin_shufflevector(alo, ahi, 0, 1, 2, 3, 4, 5, 6, 7);
                }
                #pragma unroll
                for (int rf = 0; rf < 4; ++rf)
                    #pragma unroll
                    for (int g = 0; g < 4; ++g)
                        acc[rf][g] = __builtin_amdgcn_mfma_f32_16x16x32_bf16(
                            av[rf], bB[g], acc[rf][g], 0, 0, 0);
            }
        }
        __syncthreads();   // all A reads done before h overwrite

        // ---- cell epilogue: one unit per thread, 16 rows (rcp-based) ----
        float sp[16];
        #pragma unroll
        for (int rf = 0; rf < 4; ++rf) {
            #pragma unroll
            for (int reg = 0; reg < 4; ++reg) {
                float gI = acc[rf][0][reg] + bI;
                float gF = acc[rf][1][reg] + bF;
                float gG = acc[rf][2][reg] + bG;
                float gO = acc[rf][3][reg] + bO;
                float ig = sigm(gI);
                float fg = sigm(gF);
                float gt = fast_tanh(gG);
                float og = sigm(gO);
                int ci = rf * 4 + reg;
                float cn = fg * cst[ci] + ig * gt;
                cst[ci] = cn;
                float hh = og * fast_tanh(cn);
                AS[rf * 16 + lrow + reg][128 + m] = f2bf(hh);
                sp[ci] = hh * awt;
            }
        }
        #pragma unroll
        for (int o = 1; o < 16; o <<= 1) {
            #pragma unroll
            for (int i = 0; i < 16; ++i) sp[i] += __shfl_xor(sp[i], o);
        }
        if (ccol == 0) {
            // group klane holds rows (i>>2)*16 + klane*4 + (i&3): disjoint per wave
            #pragma unroll
            for (int i = 0; i < 16; ++i)
                scoreW[bf][(i >> 2) * 16 + lrow + (i & 3)] = sp[i];
        }
        __syncthreads();
        if (t < 64 && n0 + t < N) {
            float ss = 0.f;
            #pragma unroll
            for (int b2 = 0; b2 < 12; ++b2) ss += scoreW[b2][t];
            scoreP[(size_t)(dir * 3 + l) * N + n0 + t] = ss;
        }
    }
}

// ---------------- fused tail: JK softmax-sum + node MLP + P/Q, 16 nodes ----
__global__ __launch_bounds__(256) void k_tail(
    const unsigned short* __restrict__ xsb, const float* __restrict__ scoreP,
    const float* __restrict__ nW1, const float* __restrict__ nb1,
    const float* __restrict__ nW2, const float* __restrict__ nb2,
    const float* __restrict__ eW1, const float* __restrict__ eb1,
    unsigned short* __restrict__ P, unsigned short* __restrict__ Q,
    float* __restrict__ out, int N) {
    __shared__ float xl[16][128];
    __shared__ float al[16][4];
    const int t = threadIdx.x;
    const int wid = t >> 6, lane = t & 63;
    const int nb = blockIdx.x * 16;
    if (t < 16) {
        int n = nb + t;
        float e0 = 0.f, e1 = 0.f, e2 = 0.f;
        if (n < N) {
            float s0 = scoreP[n]                 + scoreP[(size_t)3 * N + n];
            float s1 = scoreP[(size_t)N + n]     + scoreP[(size_t)4 * N + n];
            float s2 = scoreP[(size_t)2 * N + n] + scoreP[(size_t)5 * N + n];
            float mm = fmaxf(s0, fmaxf(s1, s2));
            e0 = __expf(s0 - mm); e1 = __expf(s1 - mm); e2 = __expf(s2 - mm);
            float inv = frcp(e0 + e1 + e2);
            e0 *= inv; e1 *= inv; e2 *= inv;
        }
        al[t][0] = e0; al[t][1] = e1; al[t][2] = e2;
    }
    __syncthreads();
    const size_t L1o = (size_t)N * 128, L2o = 2 * L1o;
    for (int i = t; i < 2048; i += 256) {
        int r = i >> 7, k = i & 127;
        int n = nb + r;
        float v = 0.f;
        if (n < N) {
            size_t p = (size_t)n * 128 + k;
            v = al[r][0] * bf2f(xsb[p]) + al[r][1] * bf2f(xsb[L1o + p])
              + al[r][2] * bf2f(xsb[L2o + p]);
        }
        xl[r][k] = v;
    }
    __syncthreads();
    const int c0 = lane, c1 = lane + 64;
    const int r0 = wid * 4;
    // ---- node MLP (4 nodes/wave) ----
    {
        float h0[4], h1[4];
        #pragma unroll
        for (int j = 0; j < 4; ++j) { h0[j] = 0.f; h1[j] = 0.f; }
        #pragma unroll 2
        for (int k = 0; k < 128; ++k) {
            float w0 = nW1[k * 128 + c0], w1 = nW1[k * 128 + c1];
            #pragma unroll
            for (int j = 0; j < 4; ++j) {
                float xv = xl[r0 + j][k];
                h0[j] += xv * w0;
                h1[j] += xv * w1;
            }
        }
        float p0[4], p1[4];
        #pragma unroll
        for (int j = 0; j < 4; ++j) {
            float a = fmaxf(h0[j] + nb1[c0], 0.f);
            float bq = fmaxf(h1[j] + nb1[c1], 0.f);
            p0[j] = a * nW2[c0 * 2 + 0] + bq * nW2[c1 * 2 + 0];
            p1[j] = a * nW2[c0 * 2 + 1] + bq * nW2[c1 * 2 + 1];
        }
        #pragma unroll
        for (int o = 32; o; o >>= 1) {
            #pragma unroll
            for (int j = 0; j < 4; ++j) {
                p0[j] += __shfl_down(p0[j], o);
                p1[j] += __shfl_down(p1[j], o);
            }
        }
        if (lane == 0) {
            #pragma unroll
            for (int j = 0; j < 4; ++j) {
                int n = nb + r0 + j;
                if (n < N) {
                    float l0 = p0[j] + nb2[0], l1 = p1[j] + nb2[1];
                    float mm = fmaxf(l0, l1);
                    float e0 = __expf(l0 - mm), e1 = __expf(l1 - mm);
                    float inv = frcp(e0 + e1);
                    out[2 * (size_t)n]     = e0 * inv;
                    out[2 * (size_t)n + 1] = e1 * inv;
                }
            }
        }
    }
    // ---- P/Q precompute (bf16 out, 4 nodes/wave) ----
    {
        float pp0[4], pp1[4], qq0[4], qq1[4];
        #pragma unroll
        for (int j = 0; j < 4; ++j) { pp0[j] = 0.f; pp1[j] = 0.f; qq0[j] = 0.f; qq1[j] = 0.f; }
        for (int k = 0; k < 128; ++k) {
            float wp0 = eW1[k * 128 + c0], wp1 = eW1[k * 128 + c1];
            float wq0 = eW1[(128 + k) * 128 + c0], wq1 = eW1[(128 + k) * 128 + c1];
            #pragma unroll
            for (int j = 0; j < 4; ++j) {
                float xv = xl[r0 + j][k];
                pp0[j] += xv * wp0; pp1[j] += xv * wp1;
                qq0[j] += xv * wq0; qq1[j] += xv * wq1;
            }
        }
        #pragma unroll
        for (int j = 0; j < 4; ++j) {
            int n = nb + r0 + j;
            if (n < N) {
                P[(size_t)n * 128 + c0] = f2bf(pp0[j] + eb1[c0]);
                P[(size_t)n * 128 + c1] = f2bf(pp1[j] + eb1[c1]);
                Q[(size_t)n * 128 + c0] = f2bf(qq0[j]);
                Q[(size_t)n * 128 + c1] = f2bf(qq1[j]);
            }
        }
    }
}

// ---------------- edge MLP finish: CSR order, P amortized per node ---------
// One wave per node; lane = 16*g + sl. P row loaded once into regs; groups
// g=0..3 iterate the node's CSR edges (2-deep unrolled), gather Q[col],
// reduce over 16 lanes, scatter via eidx to original edge position.
__global__ __launch_bounds__(256) void k_edge3(
    const unsigned short* __restrict__ P, const unsigned short* __restrict__ Q,
    const int* __restrict__ indptr, const int* __restrict__ colS,
    const int* __restrict__ eidx,
    const float* __restrict__ W2, const float* __restrict__ b2,
    float* __restrict__ out, int N) {
    const int wid = threadIdx.x >> 6, lane = threadIdx.x & 63;
    const int n = blockIdx.x * 4 + wid;
    if (n >= N) return;
    const int sl = lane & 15, g = lane >> 4;
    const int s = indptr[n], e = indptr[n + 1];
    // P fragment for this node (same 16B per lane-slot, broadcast across groups)
    float pf[8];
    {
        u16x8 pv = *(const u16x8*)(P + (size_t)n * 128 + sl * 8);
        #pragma unroll
        for (int j = 0; j < 8; ++j) pf[j] = bf2f(pv[j]);
    }
    float w2v[8];
    {
        const float4* w2 = (const float4*)W2 + sl * 4;
        #pragma unroll
        for (int jj = 0; jj < 4; ++jj) {
            float4 wv = w2[jj];
            w2v[2 * jj]     = wv.x;  // ch even -> logit0 ; wv.y -> logit1
            w2v[2 * jj + 1] = wv.z;  // packed below
        }
    }
    // keep full pairs: reload as scalars for logit1
    const float* W2f = W2;
    const float b20 = b2[0], b21 = b2[1];
    for (int p = s + g; p < e; p += 8) {
        int p1 = p + 4;
        bool v1 = p1 < e;
        int col0 = colS[p],  eo0 = eidx[p];
        int col1 = v1 ? colS[p1] : col0;
        int eo1  = v1 ? eidx[p1] : 0;
        u16x8 qv0 = *(const u16x8*)(Q + (size_t)col0 * 128 + sl * 8);
        u16x8 qv1 = *(const u16x8*)(Q + (size_t)col1 * 128 + sl * 8);
        float l00 = 0.f, l01 = 0.f, l10 = 0.f, l11 = 0.f;
        #pragma unroll
        for (int j = 0; j < 8; ++j) {
            int ch = sl * 8 + j;
            float wA = W2f[ch * 2], wB = W2f[ch * 2 + 1];
            float h0 = fmaxf(pf[j] + bf2f(qv0[j]), 0.f);
            float h1 = fmaxf(pf[j] + bf2f(qv1[j]), 0.f);
            l00 += h0 * wA; l01 += h0 * wB;
            l10 += h1 * wA; l11 += h1 * wB;
        }
        #pragma unroll
        for (int o = 1; o < 16; o <<= 1) {
            l00 += __shfl_xor(l00, o); l01 += __shfl_xor(l01, o);
            l10 += __shfl_xor(l10, o); l11 += __shfl_xor(l11, o);
        }
        if (sl == 0) {
            {
                float a = l00 + b20, b = l01 + b21;
                float mm = fmaxf(a, b);
                float e0 = __expf(a - mm), e1 = __expf(b - mm);
                float inv = frcp(e0 + e1);
                out[2 * (size_t)N + 2 * (size_t)eo0]     = e0 * inv;
                out[2 * (size_t)N + 2 * (size_t)eo0 + 1] = e1 * inv;
            }
            if (v1) {
                float a = l10 + b20, b = l11 + b21;
                float mm = fmaxf(a, b);
                float e0 = __expf(a - mm), e1 = __expf(b - mm);
                float inv = frcp(e0 + e1);
                out[2 * (size_t)N + 2 * (size_t)eo1]     = e0 * inv;
                out[2 * (size_t)N + 2 * (size_t)eo1 + 1] = e1 * inv;
            }
        }
    }
}

// ---------------------------------------------------------------------------
extern "C" void kernel_launch(void* const* d_in, const int* in_sizes, int n_in,
                              void* d_out, int out_size, void* d_ws, size_t ws_size,
                              hipStream_t stream) {
    if (n_in < NIN) return;
    const int N = in_sizes[0] / 3;
    const int E = in_sizes[1] / 2;

    char* ws = (char*)d_ws;
    size_t off = 0;
    auto alloc = [&](size_t bytes) -> char* {
        char* p = ws + off;
        off = (off + bytes + 255) & ~(size_t)255;
        return p;
    };
    int* flags = (int*)alloc(32 * sizeof(int));
    int* bsums = (int*)alloc(128 * sizeof(int));
    float* canon[NIN];
    for (int i = 0; i < NIN; ++i) canon[i] = nullptr;
    for (int i = 0; i < NIN; ++i) {
        if (i == 1 || (i >= 10 && i <= 17)) continue;   // LSTM weights read raw
        canon[i] = (float*)alloc((size_t)in_sizes[i] * 4);
    }
    int* row32  = (int*)alloc((size_t)E * 4);
    int* col32  = (int*)alloc((size_t)E * 4);
    int* indptr = (int*)alloc((size_t)(N + 1) * 4);
    int* cnt    = (int*)alloc((size_t)N * 4);
    int* colS   = (int*)alloc((size_t)E * 4);
    int* eidx   = (int*)alloc((size_t)E * 4);
    float* hs   = (float*)alloc((size_t)N * 4);
    float* hd   = (float*)alloc((size_t)N * 4);
    // hJK buffer: bf16 hlin during GAT phase; bf16 P/Q after the LSTM
    float* hJK  = (float*)alloc((size_t)N * 128 * 4);
    unsigned short* hlin = (unsigned short*)hJK;
    unsigned short* xsb = (unsigned short*)alloc((size_t)3 * N * 128 * 2);  // bf16 xs
    unsigned short* Bpack = (unsigned short*)alloc((size_t)2 * 10 * 48 * 512 * 2);
    float* bsum = (float*)alloc((size_t)2 * 768 * 4);
    float* scoreP = (float*)alloc((size_t)6 * N * 4);
    if (off > ws_size) return;
    unsigned short* P = (unsigned short*)hJK;           // bf16, N*128
    unsigned short* Q = (unsigned short*)hJK + (size_t)N * 128;

    InPtrs ip;
    for (int i = 0; i < NIN; ++i) { ip.p[i] = d_in[i]; ip.n[i] = in_sizes[i]; }

    k_sniff<<<NIN, 256, 0, stream>>>(ip, flags);

    // batched canonicalization of all f32/bf16 inputs
    {
        ConvJobs J;
        int nj = 0, blk = 0;
        for (int i = 0; i < NIN; ++i) {
            if (i == 1 || (i >= 10 && i <= 17)) continue;
            J.src[nj] = d_in[i];
            J.dst[nj] = canon[i];
            J.n[nj] = in_sizes[i];
            J.ai[nj] = i;
            J.blk0[nj] = blk;
            blk += (in_sizes[i] + 255) / 256;
            ++nj;
        }
        J.blk0[nj] = blk;
        J.njobs = nj;
        k_convall<<<blk, 256, 0, stream>>>(J, flags);
    }
    k_conve<<<(E + 255) / 256, 256, 0, stream>>>(d_in[1], row32, col32, E, flags);
    k_wpack<<<(2 * 10 * 48 * 512 + 255) / 256, 256, 0, stream>>>(
        d_in[10], d_in[11], d_in[14], d_in[15],
        d_in[12], d_in[13], d_in[16], d_in[17], flags, Bpack, bsum);

    // CSR by row (shared across all 3 GAT layers + edge MLP); parallel scan
    const int nb1k = (N + 1023) / 1024;
    hipMemsetAsync(cnt, 0, (size_t)N * 4, stream);
    k_hist<<<(E + 255) / 256, 256, 0, stream>>>(row32, cnt, E);
    k_scan1<<<nb1k, 1024, 0, stream>>>(cnt, indptr, bsums, N);
    k_scan2<<<1, 64, 0, stream>>>(bsums, nb1k);
    k_scan3<<<(N + 255) / 256, 256, 0, stream>>>(bsums, indptr, N, nb1k);
    hipMemsetAsync(cnt, 0, (size_t)N * 4, stream);
    k_fill<<<(E + 255) / 256, 256, 0, stream>>>(row32, col32, indptr, cnt, colS, eidx, E);

    // GAT layer 0 (in=3)
    k_lin0<<<(N + 3) / 4, 256, 0, stream>>>(canon[0], canon[2], canon[4], canon[5],
                                            hlin, hs, hd, N);
    k_aggr<<<(N + 3) / 4, 256, 0, stream>>>(hlin, hs, hd, indptr, colS, canon[3], xsb, N);
    // GAT layers 1..2 (in=128, bf16 in/out)
    for (int l = 1; l < 3; ++l) {
        const float* W  = canon[6] + (size_t)(l - 1) * 128 * 128;
        const float* bb = canon[7] + (size_t)(l - 1) * 128;
        const float* as = canon[8] + (size_t)(l - 1) * 128;
        const float* ad = canon[9] + (size_t)(l - 1) * 128;
        k_lin<<<(N + 15) / 16, 256, 0, stream>>>(xsb + (size_t)(l - 1) * N * 128, W, as, ad,
                                                 hlin, hs, hd, N);
        k_aggr<<<(N + 3) / 4, 256, 0, stream>>>(hlin, hs, hd, indptr, colS, bb,
                                                xsb + (size_t)l * N * 128, N);
    }

    // fused bidirectional LSTM (MFMA, 64-row 12-wave) -> scores
    dim3 lgrid((N + 63) / 64, 2);
    k_lstm_mfma<<<lgrid, 768, 0, stream>>>(xsb, Bpack, bsum, canon[18], scoreP, N);

    float* out = (float*)d_out;
    // fused tail: JK finish + node MLP + P/Q (P/Q overwrite dead hlin buffer)
    k_tail<<<(N + 15) / 16, 256, 0, stream>>>(xsb, scoreP,
                                              canon[20], canon[21], canon[22], canon[23],
                                              canon[24], canon[25], P, Q, out, N);
    // edge MLP in CSR order (P amortized per node; scatter via eidx)
    k_edge3<<<(N + 3) / 4, 256, 0, stream>>>(P, Q, indptr, colS, eidx,
                                             canon[26], canon[27], out, N);
}

// Round 15
// 703.560 us; speedup vs baseline: 1.0187x; 1.0187x over previous
//
#include <hip/hip_runtime.h>
#include <cstdint>
#include <cstddef>

// ---------------------------------------------------------------------------
// ParityGameGATNetwork: 3x GATConv -> JK bidirectional LSTM -> node/edge MLPs
// Round 15: (a) revert LSTM score reduction to round-13 atomicAdd form (the
// scoreW[12][64] LDS-partial variant regressed 227->243us: strided same-bank
// readback + extra LDS; atomics were never the critical path); (b) keep CSR
// edge MLP; (c) fuse hist into conve and cnt-reset into scan3 (-3 launches).
// ---------------------------------------------------------------------------

#define NIN 28
#define MAXJOBS 20

struct InPtrs { const void* p[NIN]; int n[NIN]; };

struct ConvJobs {
    const void* src[MAXJOBS];
    float* dst[MAXJOBS];
    int n[MAXJOBS];
    int ai[MAXJOBS];
    int blk0[MAXJOBS + 1];
    int njobs;
};

typedef short s16x4 __attribute__((ext_vector_type(4)));
typedef short s16x8 __attribute__((ext_vector_type(8)));
typedef float f32x4 __attribute__((ext_vector_type(4)));
typedef unsigned short u16x8 __attribute__((ext_vector_type(8)));

__device__ __forceinline__ float bf2f(unsigned short v) {
    unsigned int u = ((unsigned int)v) << 16;
    return __uint_as_float(u);
}

__device__ __forceinline__ unsigned short f2bf(float x) {
    unsigned int u = __float_as_uint(x);
    unsigned int r = u + 0x7fffu + ((u >> 16) & 1u);
    return (unsigned short)(r >> 16);
}

__device__ __forceinline__ float rdx(const void* p, size_t i, int isf32) {
    return isf32 ? ((const float*)p)[i] : bf2f(((const unsigned short*)p)[i]);
}

__device__ __forceinline__ float frcp(float x) {        // raw v_rcp_f32 (~1ulp)
    return __builtin_amdgcn_rcpf(x);
}

__device__ __forceinline__ float sigm(float x) {
    return frcp(1.f + __expf(-x));
}

__device__ __forceinline__ float fast_tanh(float x) {
    return 1.f - 2.f * frcp(__expf(2.f * x) + 1.f);
}

// ---------------- dtype sniffing -------------------------------------------
__global__ void k_sniff(InPtrs in, int* flags) {
    int ai = blockIdx.x;
    if (ai >= NIN) return;
    __shared__ int cnt;
    if (threadIdx.x == 0) cnt = 0;
    __syncthreads();
    if (ai == 1) {
        const int* w = (const int*)in.p[1];
        int nw = in.n[1] < 512 ? in.n[1] : 512;
        int local = 0;
        for (int i = threadIdx.x; i < nw; i += blockDim.x)
            if ((i & 1) && w[i] != 0) local++;
        atomicAdd(&cnt, local);
        __syncthreads();
        if (threadIdx.x == 0) flags[1] = (cnt < 4) ? 1 : 0;
        return;
    }
    const unsigned short* u = (const unsigned short*)in.p[ai];
    int ns = in.n[ai] < 256 ? in.n[ai] : 256;
    int local = 0;
    for (int i = threadIdx.x; i < ns; i += blockDim.x) {
        if (i & 1) continue;
        unsigned short v = u[i];
        int e = (v >> 7) & 0xff;
        if ((v & 0x7fff) != 0 && (e < 100 || e > 154)) local++;
    }
    atomicAdd(&cnt, local);
    __syncthreads();
    if (threadIdx.x == 0) flags[ai] = (cnt * 4 >= ns) ? 1 : 0;
}

// ---------------- batched canonicalization ---------------------------------
__global__ void k_convall(ConvJobs J, const int* __restrict__ flags) {
    int b = blockIdx.x;
    int j = 0;
    while (j + 1 < J.njobs && b >= J.blk0[j + 1]) ++j;
    int i = (b - J.blk0[j]) * 256 + threadIdx.x;
    if (i >= J.n[j]) return;
    J.dst[j][i] = rdx(J.src[j], i, flags[J.ai[j]]);
}

// edge decode + row histogram fused (cnt pre-zeroed)
__global__ void k_conve(const void* src, int* row, int* col, int* cnt,
                        int E, const int* flags) {
    int i = blockIdx.x * blockDim.x + threadIdx.x;
    if (i >= E) return;
    int r, c;
    if (flags[1]) {
        const long long* s = (const long long*)src;
        r = (int)s[i];
        c = (int)s[(size_t)E + i];
    } else {
        const int* s = (const int*)src;
        r = s[i];
        c = s[(size_t)E + i];
    }
    row[i] = r;
    col[i] = c;
    atomicAdd(&cnt[r], 1);
}

// ---------------- CSR build ------------------------------------------------
__global__ void k_scan1(const int* __restrict__ deg, int* __restrict__ indptr,
                        int* __restrict__ bsums, int N) {
    __shared__ int buf[1024];
    const int t = threadIdx.x;
    const int base = blockIdx.x * 1024;
    int v = (base + t < N) ? deg[base + t] : 0;
    buf[t] = v;
    __syncthreads();
    for (int ofs = 1; ofs < 1024; ofs <<= 1) {
        int add = (t >= ofs) ? buf[t - ofs] : 0;
        __syncthreads();
        buf[t] += add;
        __syncthreads();
    }
    if (base + t < N) indptr[base + t] = buf[t] - v;
    if (t == 1023) bsums[blockIdx.x] = buf[1023];
}

__global__ void k_scan2(int* bsums, int nb) {
    if (threadIdx.x == 0 && blockIdx.x == 0) {
        int acc = 0;
        for (int j = 0; j < nb; ++j) { int v = bsums[j]; bsums[j] = acc; acc += v; }
        bsums[nb] = acc;
    }
}

// adds block offsets AND resets cnt for k_fill
__global__ void k_scan3(const int* __restrict__ bsums, int* __restrict__ indptr,
                        int* __restrict__ cnt, int N, int nb) {
    int i = blockIdx.x * blockDim.x + threadIdx.x;
    if (i < N) {
        indptr[i] += bsums[i >> 10];
        cnt[i] = 0;
    }
    if (i == 0) indptr[N] = bsums[nb];
}

__global__ void k_fill(const int* __restrict__ row, const int* __restrict__ col,
                       const int* __restrict__ indptr, int* __restrict__ cur,
                       int* __restrict__ colS, int* __restrict__ eidx, int E) {
    int i = blockIdx.x * blockDim.x + threadIdx.x;
    if (i >= E) return;
    int r = row[i];
    int p = indptr[r] + atomicAdd(&cur[r], 1);
    colS[p] = col[i];
    eidx[p] = i;
}

// ---------------- GAT linear layer 0 (in=3), hlin out bf16 -----------------
__global__ __launch_bounds__(256) void k_lin0(
    const float* __restrict__ x, const float* __restrict__ W0,
    const float* __restrict__ asrc, const float* __restrict__ adst,
    unsigned short* __restrict__ hlin, float* __restrict__ hs, float* __restrict__ hd,
    int N) {
    const int wid = threadIdx.x >> 6, lane = threadIdx.x & 63;
    const int n = blockIdx.x * 4 + wid;
    if (n >= N) return;
    float x0 = x[(size_t)n * 3], x1 = x[(size_t)n * 3 + 1], x2 = x[(size_t)n * 3 + 2];
    const int c0 = lane, c1 = lane + 64;
    float h0 = x0 * W0[c0] + x1 * W0[128 + c0] + x2 * W0[256 + c0];
    float h1 = x0 * W0[c1] + x1 * W0[128 + c1] + x2 * W0[256 + c1];
    hlin[(size_t)n * 128 + c0] = f2bf(h0);
    hlin[(size_t)n * 128 + c1] = f2bf(h1);
    float sp = h0 * asrc[c0] + h1 * asrc[c1];
    float dp = h0 * adst[c0] + h1 * adst[c1];
    for (int o = 32; o; o >>= 1) { sp += __shfl_down(sp, o); dp += __shfl_down(dp, o); }
    if (lane == 0) { hs[n] = sp; hd[n] = dp; }
}

// ---------------- GAT linear (bf16 in/out), 4 nodes/wave -------------------
__global__ __launch_bounds__(256) void k_lin(
    const unsigned short* __restrict__ xin, const float* __restrict__ W,
    const float* __restrict__ asrc, const float* __restrict__ adst,
    unsigned short* __restrict__ hlin, float* __restrict__ hs, float* __restrict__ hd,
    int N) {
    __shared__ float xl[16][128];
    const int t = threadIdx.x;
    const int wid = t >> 6, lane = t & 63;
    const int nb = blockIdx.x * 16;
    for (int i = t; i < 2048; i += 256) {
        int r = i >> 7, k = i & 127;
        int n = nb + r;
        xl[r][k] = (n < N) ? bf2f(xin[(size_t)n * 128 + k]) : 0.f;
    }
    __syncthreads();
    const int c0 = lane, c1 = lane + 64;
    const int r0 = wid * 4;
    float h0[4], h1[4];
    #pragma unroll
    for (int j = 0; j < 4; ++j) { h0[j] = 0.f; h1[j] = 0.f; }
    #pragma unroll 2
    for (int k = 0; k < 128; ++k) {
        float w0 = W[k * 128 + c0], w1 = W[k * 128 + c1];
        #pragma unroll
        for (int j = 0; j < 4; ++j) {
            float xv = xl[r0 + j][k];
            h0[j] += xv * w0;
            h1[j] += xv * w1;
        }
    }
    float sp[4], dp[4];
    #pragma unroll
    for (int j = 0; j < 4; ++j) {
        sp[j] = h0[j] * asrc[c0] + h1[j] * asrc[c1];
        dp[j] = h0[j] * adst[c0] + h1[j] * adst[c1];
    }
    #pragma unroll
    for (int o = 32; o; o >>= 1) {
        #pragma unroll
        for (int j = 0; j < 4; ++j) {
            sp[j] += __shfl_down(sp[j], o);
            dp[j] += __shfl_down(dp[j], o);
        }
    }
    #pragma unroll
    for (int j = 0; j < 4; ++j) {
        int n = nb + r0 + j;
        if (n < N) {
            hlin[(size_t)n * 128 + c0] = f2bf(h0[j]);
            hlin[(size_t)n * 128 + c1] = f2bf(h1[j]);
            if (lane == 0) { hs[n] = sp[j]; hd[n] = dp[j]; }
        }
    }
}

// ---------------- GAT aggregation: online segment softmax, 8-way unrolled --
__global__ __launch_bounds__(256) void k_aggr(
    const unsigned short* __restrict__ hlin, const float* __restrict__ hs,
    const float* __restrict__ hd,
    const int* __restrict__ indptr, const int* __restrict__ colS,
    const float* __restrict__ b, unsigned short* __restrict__ xout, int N) {
    const int wid = threadIdx.x >> 6, lane = threadIdx.x & 63;
    const int n = blockIdx.x * 4 + wid;
    if (n >= N) return;
    const int s = indptr[n], epos = indptr[n + 1];
    const float hdv = hd[n];
    const int c0 = lane, c1 = lane + 64;
    float m = -1e30f, d = 0.f, a0 = 0.f, a1 = 0.f;
    int idx = s;
    for (; idx + 8 <= epos; idx += 8) {
        int cl[8];
        #pragma unroll
        for (int j = 0; j < 8; ++j) cl[j] = colS[idx + j];
        float e[8];
        #pragma unroll
        for (int j = 0; j < 8; ++j) {
            float ev = hs[cl[j]] + hdv;
            e[j] = (ev > 0.f) ? ev : 0.2f * ev;
        }
        float v0[8], v1[8];
        #pragma unroll
        for (int j = 0; j < 8; ++j) {
            const unsigned short* hp = hlin + (size_t)cl[j] * 128;
            v0[j] = bf2f(hp[c0]);
            v1[j] = bf2f(hp[c1]);
        }
        float m8 = e[0];
        #pragma unroll
        for (int j = 1; j < 8; ++j) m8 = fmaxf(m8, e[j]);
        if (m8 > m) {
            float sc = __expf(m - m8);
            a0 *= sc; a1 *= sc; d *= sc; m = m8;
        }
        #pragma unroll
        for (int j = 0; j < 8; ++j) {
            float w = __expf(e[j] - m);
            a0 += w * v0[j];
            a1 += w * v1[j];
            d  += w;
        }
    }
    for (; idx < epos; ++idx) {
        int col = colS[idx];
        float e = hs[col] + hdv;
        e = (e > 0.f) ? e : 0.2f * e;
        const unsigned short* hr = hlin + (size_t)col * 128;
        float v0 = bf2f(hr[c0]), v1 = bf2f(hr[c1]);
        if (e > m) {
            float sc = __expf(m - e);
            a0 = a0 * sc + v0;
            a1 = a1 * sc + v1;
            d  = d * sc + 1.f;
            m  = e;
        } else {
            float w = __expf(e - m);
            a0 += w * v0;
            a1 += w * v1;
            d  += w;
        }
    }
    float inv = frcp(d + 1e-16f);
    float r0 = a0 * inv + b[c0];
    float r1 = a1 * inv + b[c1];
    xout[(size_t)n * 128 + c0] = f2bf(fmaxf(r0, 0.f));
    xout[(size_t)n * 128 + c1] = f2bf(fmaxf(r1, 0.f));
}

// ---------------- LSTM weight pack into MFMA fragment order ----------------
__global__ void k_wpack(const void* Wihf, const void* Whhf,
                        const void* Wihb, const void* Whhb,
                        const void* bihf, const void* bhhf,
                        const void* bihb, const void* bhhb,
                        const int* __restrict__ flags,
                        unsigned short* __restrict__ Bpack, float* __restrict__ bsum) {
    int idx = blockIdx.x * blockDim.x + threadIdx.x;
    const int TOT = 2 * 10 * 48 * 512;
    if (idx < TOT) {
        int dir = idx / (10 * 48 * 512);
        int r   = idx % (10 * 48 * 512);
        int kb  = r / (48 * 512);
        int r2  = r % (48 * 512);
        int f   = r2 / 512;
        int q   = r2 % 512;
        int lane = q >> 3, j = q & 7;
        int k   = kb * 32 + ((j >> 2) * 16) + ((lane >> 4) * 4) + (j & 3);
        int col = f * 16 + (lane & 15);
        float v;
        if (k < 128)
            v = dir ? rdx(Wihb, (size_t)col * 128 + k, flags[14])
                    : rdx(Wihf, (size_t)col * 128 + k, flags[10]);
        else
            v = dir ? rdx(Whhb, (size_t)col * 192 + (k - 128), flags[15])
                    : rdx(Whhf, (size_t)col * 192 + (k - 128), flags[11]);
        Bpack[idx] = f2bf(v);
    }
    if (idx < 2 * 768) {
        int d = idx / 768, j = idx % 768;
        bsum[idx] = d ? rdx(bihb, j, flags[16]) + rdx(bhhb, j, flags[17])
                      : rdx(bihf, j, flags[12]) + rdx(bhhf, j, flags[13]);
    }
}

// ---------------- fused bidirectional LSTM: 64 rows, 12 waves --------------
// Round-13 configuration (atomicAdd score reduction).
__global__ __launch_bounds__(768, 3) void k_lstm_mfma(
    const unsigned short* __restrict__ xsb,  // [3][N][128] bf16
    const unsigned short* __restrict__ Bpack,// [2][10][48][512] bf16
    const float* __restrict__ bsum,          // [2][768]
    const float* __restrict__ attW,          // [384]
    float* __restrict__ scoreP,              // [2][3][N]
    int N) {
    __shared__ unsigned short AS[64][332];   // x:[0,128)  h:[128,320)
    __shared__ float scoreS[64];
    const int t = threadIdx.x;
    const int bf = t >> 6, lane = t & 63;
    const int dir = blockIdx.y;
    const int n0 = blockIdx.x * 64;
    const int ccol = lane & 15;
    const int klane = lane >> 4;
    const int lrow = klane * 4;
    const int akl = klane * 4;
    const int m = bf * 16 + ccol;            // this thread's hidden unit

    const float bI = bsum[dir * 768 + m];
    const float bF = bsum[dir * 768 + 192 + m];
    const float bG = bsum[dir * 768 + 384 + m];
    const float bO = bsum[dir * 768 + 576 + m];
    const float awt = attW[dir * 192 + m];
    float cst[16];
    #pragma unroll
    for (int i = 0; i < 16; ++i) cst[i] = 0.f;

    const unsigned short* Bd = Bpack + (size_t)dir * 10 * 48 * 512;

    for (int s = 0; s < 3; ++s) {
        const int l = dir ? (2 - s) : s;
        // ---- stage x tile: 64x128 bf16 ----
        {
            const unsigned short* xsrc = xsb + ((size_t)l * N + n0) * 128;
            for (int i = t; i < 1024; i += 768) {
                int r = i >> 4, kq = (i & 15) * 8;
                u16x8 v = (u16x8)(0);
                if (n0 + r < N) v = *(const u16x8*)(xsrc + (size_t)r * 128 + kq);
                *(u16x8*)&AS[r][kq] = v;
            }
        }
        if (t < 64) scoreS[t] = 0.f;
        __syncthreads();

        // ---- MFMA GEMM over K, B ping-pong prefetch ----
        const int KB = s ? 10 : 4;               // both even
        f32x4 acc[4][4];
        #pragma unroll
        for (int rf = 0; rf < 4; ++rf)
            #pragma unroll
            for (int g = 0; g < 4; ++g) acc[rf][g] = (f32x4)(0.f);
        s16x8 bA[4], bB[4];
        {
            const unsigned short* bb = Bd + (size_t)bf * 512 + lane * 8;   // kb=0
            #pragma unroll
            for (int g = 0; g < 4; ++g) bA[g] = *(const s16x8*)(bb + (size_t)g * 6144);
        }
        for (int kb = 0; kb < KB; kb += 2) {
            {   // prefetch kb+1
                const unsigned short* bb = Bd + ((size_t)(kb + 1) * 48 + bf) * 512 + lane * 8;
                #pragma unroll
                for (int g = 0; g < 4; ++g) bB[g] = *(const s16x8*)(bb + (size_t)g * 6144);
            }
            {   // compute kb on bA
                const int k0 = kb * 32 + akl;
                s16x8 av[4];
                #pragma unroll
                for (int rf = 0; rf < 4; ++rf) {
                    s16x4 alo = *(const s16x4*)&AS[rf * 16 + ccol][k0];
                    s16x4 ahi = *(const s16x4*)&AS[rf * 16 + ccol][k0 + 16];
                    av[rf] = __builtin_shufflevector(alo, ahi, 0, 1, 2, 3, 4, 5, 6, 7);
                }
                #pragma unroll
                for (int rf = 0; rf < 4; ++rf)
                    #pragma unroll
                    for (int g = 0; g < 4; ++g)
                        acc[rf][g] = __builtin_amdgcn_mfma_f32_16x16x32_bf16(
                            av[rf], bA[g], acc[rf][g], 0, 0, 0);
            }
            if (kb + 2 < KB) {   // prefetch kb+2
                const unsigned short* bb = Bd + ((size_t)(kb + 2) * 48 + bf) * 512 + lane * 8;
                #pragma unroll
                for (int g = 0; g < 4; ++g) bA[g] = *(const s16x8*)(bb + (size_t)g * 6144);
            }
            {   // compute kb+1 on bB
                const int k0 = (kb + 1) * 32 + akl;
                s16x8 av[4];
                #pragma unroll
                for (int rf = 0; rf < 4; ++rf) {
                    s16x4 alo = *(const s16x4*)&AS[rf * 16 + ccol][k0];
                    s16x4 ahi = *(const s16x4*)&AS[rf * 16 + ccol][k0 + 16];
                    av[rf] = __builtin_shufflevector(alo, ahi, 0, 1, 2, 3, 4, 5, 6, 7);
                }
                #pragma unroll
                for (int rf = 0; rf < 4; ++rf)
                    #pragma unroll
                    for (int g = 0; g < 4; ++g)
                        acc[rf][g] = __builtin_amdgcn_mfma_f32_16x16x32_bf16(
                            av[rf], bB[g], acc[rf][g], 0, 0, 0);
            }
        }
        __syncthreads();   // all A reads done before h overwrite

        // ---- cell epilogue: one unit per thread, 16 rows (rcp-based) ----
        float sp[16];
        #pragma unroll
        for (int rf = 0; rf < 4; ++rf) {
            #pragma unroll
            for (int reg = 0; reg < 4; ++reg) {
                float gI = acc[rf][0][reg] + bI;
                float gF = acc[rf][1][reg] + bF;
                float gG = acc[rf][2][reg] + bG;
                float gO = acc[rf][3][reg] + bO;
                float ig = sigm(gI);
                float fg = sigm(gF);
                float gt = fast_tanh(gG);
                float og = sigm(gO);
                int ci = rf * 4 + reg;
                float cn = fg * cst[ci] + ig * gt;
                cst[ci] = cn;
                float hh = og * fast_tanh(cn);
                AS[rf * 16 + lrow + reg][128 + m] = f2bf(hh);
                sp[ci] = hh * awt;
            }
        }
        #pragma unroll
        for (int o = 1; o < 16; o <<= 1) {
            #pragma unroll
            for (int i = 0; i < 16; ++i) sp[i] += __shfl_xor(sp[i], o);
        }
        if (ccol == 0) {
            #pragma unroll
            for (int i = 0; i < 16; ++i)
                atomicAdd(&scoreS[(i >> 2) * 16 + lrow + (i & 3)], sp[i]);
        }
        __syncthreads();
        if (t < 64 && n0 + t < N)
            scoreP[(size_t)(dir * 3 + l) * N + n0 + t] = scoreS[t];
    }
}

// ---------------- fused tail: JK softmax-sum + node MLP + P/Q, 16 nodes ----
__global__ __launch_bounds__(256) void k_tail(
    const unsigned short* __restrict__ xsb, const float* __restrict__ scoreP,
    const float* __restrict__ nW1, const float* __restrict__ nb1,
    const float* __restrict__ nW2, const float* __restrict__ nb2,
    const float* __restrict__ eW1, const float* __restrict__ eb1,
    unsigned short* __restrict__ P, unsigned short* __restrict__ Q,
    float* __restrict__ out, int N) {
    __shared__ float xl[16][128];
    __shared__ float al[16][4];
    const int t = threadIdx.x;
    const int wid = t >> 6, lane = t & 63;
    const int nb = blockIdx.x * 16;
    if (t < 16) {
        int n = nb + t;
        float e0 = 0.f, e1 = 0.f, e2 = 0.f;
        if (n < N) {
            float s0 = scoreP[n]                 + scoreP[(size_t)3 * N + n];
            float s1 = scoreP[(size_t)N + n]     + scoreP[(size_t)4 * N + n];
            float s2 = scoreP[(size_t)2 * N + n] + scoreP[(size_t)5 * N + n];
            float mm = fmaxf(s0, fmaxf(s1, s2));
            e0 = __expf(s0 - mm); e1 = __expf(s1 - mm); e2 = __expf(s2 - mm);
            float inv = frcp(e0 + e1 + e2);
            e0 *= inv; e1 *= inv; e2 *= inv;
        }
        al[t][0] = e0; al[t][1] = e1; al[t][2] = e2;
    }
    __syncthreads();
    const size_t L1o = (size_t)N * 128, L2o = 2 * L1o;
    for (int i = t; i < 2048; i += 256) {
        int r = i >> 7, k = i & 127;
        int n = nb + r;
        float v = 0.f;
        if (n < N) {
            size_t p = (size_t)n * 128 + k;
            v = al[r][0] * bf2f(xsb[p]) + al[r][1] * bf2f(xsb[L1o + p])
              + al[r][2] * bf2f(xsb[L2o + p]);
        }
        xl[r][k] = v;
    }
    __syncthreads();
    const int c0 = lane, c1 = lane + 64;
    const int r0 = wid * 4;
    // ---- node MLP (4 nodes/wave) ----
    {
        float h0[4], h1[4];
        #pragma unroll
        for (int j = 0; j < 4; ++j) { h0[j] = 0.f; h1[j] = 0.f; }
        #pragma unroll 2
        for (int k = 0; k < 128; ++k) {
            float w0 = nW1[k * 128 + c0], w1 = nW1[k * 128 + c1];
            #pragma unroll
            for (int j = 0; j < 4; ++j) {
                float xv = xl[r0 + j][k];
                h0[j] += xv * w0;
                h1[j] += xv * w1;
            }
        }
        float p0[4], p1[4];
        #pragma unroll
        for (int j = 0; j < 4; ++j) {
            float a = fmaxf(h0[j] + nb1[c0], 0.f);
            float bq = fmaxf(h1[j] + nb1[c1], 0.f);
            p0[j] = a * nW2[c0 * 2 + 0] + bq * nW2[c1 * 2 + 0];
            p1[j] = a * nW2[c0 * 2 + 1] + bq * nW2[c1 * 2 + 1];
        }
        #pragma unroll
        for (int o = 32; o; o >>= 1) {
            #pragma unroll
            for (int j = 0; j < 4; ++j) {
                p0[j] += __shfl_down(p0[j], o);
                p1[j] += __shfl_down(p1[j], o);
            }
        }
        if (lane == 0) {
            #pragma unroll
            for (int j = 0; j < 4; ++j) {
                int n = nb + r0 + j;
                if (n < N) {
                    float l0 = p0[j] + nb2[0], l1 = p1[j] + nb2[1];
                    float mm = fmaxf(l0, l1);
                    float e0 = __expf(l0 - mm), e1 = __expf(l1 - mm);
                    float inv = frcp(e0 + e1);
                    out[2 * (size_t)n]     = e0 * inv;
                    out[2 * (size_t)n + 1] = e1 * inv;
                }
            }
        }
    }
    // ---- P/Q precompute (bf16 out, 4 nodes/wave) ----
    {
        float pp0[4], pp1[4], qq0[4], qq1[4];
        #pragma unroll
        for (int j = 0; j < 4; ++j) { pp0[j] = 0.f; pp1[j] = 0.f; qq0[j] = 0.f; qq1[j] = 0.f; }
        for (int k = 0; k < 128; ++k) {
            float wp0 = eW1[k * 128 + c0], wp1 = eW1[k * 128 + c1];
            float wq0 = eW1[(128 + k) * 128 + c0], wq1 = eW1[(128 + k) * 128 + c1];
            #pragma unroll
            for (int j = 0; j < 4; ++j) {
                float xv = xl[r0 + j][k];
                pp0[j] += xv * wp0; pp1[j] += xv * wp1;
                qq0[j] += xv * wq0; qq1[j] += xv * wq1;
            }
        }
        #pragma unroll
        for (int j = 0; j < 4; ++j) {
            int n = nb + r0 + j;
            if (n < N) {
                P[(size_t)n * 128 + c0] = f2bf(pp0[j] + eb1[c0]);
                P[(size_t)n * 128 + c1] = f2bf(pp1[j] + eb1[c1]);
                Q[(size_t)n * 128 + c0] = f2bf(qq0[j]);
                Q[(size_t)n * 128 + c1] = f2bf(qq1[j]);
            }
        }
    }
}

// ---------------- edge MLP finish: CSR order, P amortized per node ---------
__global__ __launch_bounds__(256) void k_edge3(
    const unsigned short* __restrict__ P, const unsigned short* __restrict__ Q,
    const int* __restrict__ indptr, const int* __restrict__ colS,
    const int* __restrict__ eidx,
    const float* __restrict__ W2, const float* __restrict__ b2,
    float* __restrict__ out, int N) {
    const int wid = threadIdx.x >> 6, lane = threadIdx.x & 63;
    const int n = blockIdx.x * 4 + wid;
    if (n >= N) return;
    const int sl = lane & 15, g = lane >> 4;
    const int s = indptr[n], e = indptr[n + 1];
    float pf[8];
    {
        u16x8 pv = *(const u16x8*)(P + (size_t)n * 128 + sl * 8);
        #pragma unroll
        for (int j = 0; j < 8; ++j) pf[j] = bf2f(pv[j]);
    }
    const float* W2f = W2;
    const float b20 = b2[0], b21 = b2[1];
    for (int p = s + g; p < e; p += 8) {
        int p1 = p + 4;
        bool v1 = p1 < e;
        int col0 = colS[p],  eo0 = eidx[p];
        int col1 = v1 ? colS[p1] : col0;
        int eo1  = v1 ? eidx[p1] : 0;
        u16x8 qv0 = *(const u16x8*)(Q + (size_t)col0 * 128 + sl * 8);
        u16x8 qv1 = *(const u16x8*)(Q + (size_t)col1 * 128 + sl * 8);
        float l00 = 0.f, l01 = 0.f, l10 = 0.f, l11 = 0.f;
        #pragma unroll
        for (int j = 0; j < 8; ++j) {
            int ch = sl * 8 + j;
            float wA = W2f[ch * 2], wB = W2f[ch * 2 + 1];
            float h0 = fmaxf(pf[j] + bf2f(qv0[j]), 0.f);
            float h1 = fmaxf(pf[j] + bf2f(qv1[j]), 0.f);
            l00 += h0 * wA; l01 += h0 * wB;
            l10 += h1 * wA; l11 += h1 * wB;
        }
        #pragma unroll
        for (int o = 1; o < 16; o <<= 1) {
            l00 += __shfl_xor(l00, o); l01 += __shfl_xor(l01, o);
            l10 += __shfl_xor(l10, o); l11 += __shfl_xor(l11, o);
        }
        if (sl == 0) {
            {
                float a = l00 + b20, b = l01 + b21;
                float mm = fmaxf(a, b);
                float e0 = __expf(a - mm), e1 = __expf(b - mm);
                float inv = frcp(e0 + e1);
                out[2 * (size_t)N + 2 * (size_t)eo0]     = e0 * inv;
                out[2 * (size_t)N + 2 * (size_t)eo0 + 1] = e1 * inv;
            }
            if (v1) {
                float a = l10 + b20, b = l11 + b21;
                float mm = fmaxf(a, b);
                float e0 = __expf(a - mm), e1 = __expf(b - mm);
                float inv = frcp(e0 + e1);
                out[2 * (size_t)N + 2 * (size_t)eo1]     = e0 * inv;
                out[2 * (size_t)N + 2 * (size_t)eo1 + 1] = e1 * inv;
            }
        }
    }
}

// ---------------------------------------------------------------------------
extern "C" void kernel_launch(void* const* d_in, const int* in_sizes, int n_in,
                              void* d_out, int out_size, void* d_ws, size_t ws_size,
                              hipStream_t stream) {
    if (n_in < NIN) return;
    const int N = in_sizes[0] / 3;
    const int E = in_sizes[1] / 2;

    char* ws = (char*)d_ws;
    size_t off = 0;
    auto alloc = [&](size_t bytes) -> char* {
        char* p = ws + off;
        off = (off + bytes + 255) & ~(size_t)255;
        return p;
    };
    int* flags = (int*)alloc(32 * sizeof(int));
    int* bsums = (int*)alloc(128 * sizeof(int));
    float* canon[NIN];
    for (int i = 0; i < NIN; ++i) canon[i] = nullptr;
    for (int i = 0; i < NIN; ++i) {
        if (i == 1 || (i >= 10 && i <= 17)) continue;   // LSTM weights read raw
        canon[i] = (float*)alloc((size_t)in_sizes[i] * 4);
    }
    int* row32  = (int*)alloc((size_t)E * 4);
    int* col32  = (int*)alloc((size_t)E * 4);
    int* indptr = (int*)alloc((size_t)(N + 1) * 4);
    int* cnt    = (int*)alloc((size_t)N * 4);
    int* colS   = (int*)alloc((size_t)E * 4);
    int* eidx   = (int*)alloc((size_t)E * 4);
    float* hs   = (float*)alloc((size_t)N * 4);
    float* hd   = (float*)alloc((size_t)N * 4);
    // hJK buffer: bf16 hlin during GAT phase; bf16 P/Q after the LSTM
    float* hJK  = (float*)alloc((size_t)N * 128 * 4);
    unsigned short* hlin = (unsigned short*)hJK;
    unsigned short* xsb = (unsigned short*)alloc((size_t)3 * N * 128 * 2);  // bf16 xs
    unsigned short* Bpack = (unsigned short*)alloc((size_t)2 * 10 * 48 * 512 * 2);
    float* bsum = (float*)alloc((size_t)2 * 768 * 4);
    float* scoreP = (float*)alloc((size_t)6 * N * 4);
    if (off > ws_size) return;
    unsigned short* P = (unsigned short*)hJK;           // bf16, N*128
    unsigned short* Q = (unsigned short*)hJK + (size_t)N * 128;

    InPtrs ip;
    for (int i = 0; i < NIN; ++i) { ip.p[i] = d_in[i]; ip.n[i] = in_sizes[i]; }

    k_sniff<<<NIN, 256, 0, stream>>>(ip, flags);

    // batched canonicalization of all f32/bf16 inputs
    {
        ConvJobs J;
        int nj = 0, blk = 0;
        for (int i = 0; i < NIN; ++i) {
            if (i == 1 || (i >= 10 && i <= 17)) continue;
            J.src[nj] = d_in[i];
            J.dst[nj] = canon[i];
            J.n[nj] = in_sizes[i];
            J.ai[nj] = i;
            J.blk0[nj] = blk;
            blk += (in_sizes[i] + 255) / 256;
            ++nj;
        }
        J.blk0[nj] = blk;
        J.njobs = nj;
        k_convall<<<blk, 256, 0, stream>>>(J, flags);
    }
    // edge decode + histogram (cnt pre-zeroed by memset)
    hipMemsetAsync(cnt, 0, (size_t)N * 4, stream);
    k_conve<<<(E + 255) / 256, 256, 0, stream>>>(d_in[1], row32, col32, cnt, E, flags);
    k_wpack<<<(2 * 10 * 48 * 512 + 255) / 256, 256, 0, stream>>>(
        d_in[10], d_in[11], d_in[14], d_in[15],
        d_in[12], d_in[13], d_in[16], d_in[17], flags, Bpack, bsum);

    // CSR scan (scan3 also resets cnt for k_fill)
    const int nb1k = (N + 1023) / 1024;
    k_scan1<<<nb1k, 1024, 0, stream>>>(cnt, indptr, bsums, N);
    k_scan2<<<1, 64, 0, stream>>>(bsums, nb1k);
    k_scan3<<<(N + 255) / 256, 256, 0, stream>>>(bsums, indptr, cnt, N, nb1k);
    k_fill<<<(E + 255) / 256, 256, 0, stream>>>(row32, col32, indptr, cnt, colS, eidx, E);

    // GAT layer 0 (in=3)
    k_lin0<<<(N + 3) / 4, 256, 0, stream>>>(canon[0], canon[2], canon[4], canon[5],
                                            hlin, hs, hd, N);
    k_aggr<<<(N + 3) / 4, 256, 0, stream>>>(hlin, hs, hd, indptr, colS, canon[3], xsb, N);
    // GAT layers 1..2 (in=128, bf16 in/out)
    for (int l = 1; l < 3; ++l) {
        const float* W  = canon[6] + (size_t)(l - 1) * 128 * 128;
        const float* bb = canon[7] + (size_t)(l - 1) * 128;
        const float* as = canon[8] + (size_t)(l - 1) * 128;
        const float* ad = canon[9] + (size_t)(l - 1) * 128;
        k_lin<<<(N + 15) / 16, 256, 0, stream>>>(xsb + (size_t)(l - 1) * N * 128, W, as, ad,
                                                 hlin, hs, hd, N);
        k_aggr<<<(N + 3) / 4, 256, 0, stream>>>(hlin, hs, hd, indptr, colS, bb,
                                                xsb + (size_t)l * N * 128, N);
    }

    // fused bidirectional LSTM (MFMA, 64-row 12-wave) -> scores
    dim3 lgrid((N + 63) / 64, 2);
    k_lstm_mfma<<<lgrid, 768, 0, stream>>>(xsb, Bpack, bsum, canon[18], scoreP, N);

    float* out = (float*)d_out;
    // fused tail: JK finish + node MLP + P/Q (P/Q overwrite dead hlin buffer)
    k_tail<<<(N + 15) / 16, 256, 0, stream>>>(xsb, scoreP,
                                              canon[20], canon[21], canon[22], canon[23],
                                              canon[24], canon[25], P, Q, out, N);
    // edge MLP in CSR order (P amortized per node; scatter via eidx)
    k_edge3<<<(N + 3) / 4, 256, 0, stream>>>(P, Q, indptr, colS, eidx,
                                             canon[26], canon[27], out, N);
}

// Round 16
// 671.693 us; speedup vs baseline: 1.0670x; 1.0474x over previous
//
#include <hip/hip_runtime.h>
#include <cstdint>
#include <cstddef>

// ---------------------------------------------------------------------------
// ParityGameGATNetwork: 3x GATConv -> JK bidirectional LSTM -> node/edge MLPs
// Round 16: GAT linear layers 1-2 moved to bf16 MFMA (k_linm): same fragment
// layout/staging as the validated LSTM kernel; W packed once by k_wpackg;
// hs/hd epilogue via shfl16+LDS-atomic (the LSTM score pattern). Everything
// else identical to round 15 (LSTM 226us config, CSR edge MLP, fused prep).
// ---------------------------------------------------------------------------

#define NIN 28
#define MAXJOBS 20

struct InPtrs { const void* p[NIN]; int n[NIN]; };

struct ConvJobs {
    const void* src[MAXJOBS];
    float* dst[MAXJOBS];
    int n[MAXJOBS];
    int ai[MAXJOBS];
    int blk0[MAXJOBS + 1];
    int njobs;
};

typedef short s16x4 __attribute__((ext_vector_type(4)));
typedef short s16x8 __attribute__((ext_vector_type(8)));
typedef float f32x4 __attribute__((ext_vector_type(4)));
typedef unsigned short u16x8 __attribute__((ext_vector_type(8)));

__device__ __forceinline__ float bf2f(unsigned short v) {
    unsigned int u = ((unsigned int)v) << 16;
    return __uint_as_float(u);
}

__device__ __forceinline__ unsigned short f2bf(float x) {
    unsigned int u = __float_as_uint(x);
    unsigned int r = u + 0x7fffu + ((u >> 16) & 1u);
    return (unsigned short)(r >> 16);
}

__device__ __forceinline__ float rdx(const void* p, size_t i, int isf32) {
    return isf32 ? ((const float*)p)[i] : bf2f(((const unsigned short*)p)[i]);
}

__device__ __forceinline__ float frcp(float x) {        // raw v_rcp_f32 (~1ulp)
    return __builtin_amdgcn_rcpf(x);
}

__device__ __forceinline__ float sigm(float x) {
    return frcp(1.f + __expf(-x));
}

__device__ __forceinline__ float fast_tanh(float x) {
    return 1.f - 2.f * frcp(__expf(2.f * x) + 1.f);
}

// ---------------- dtype sniffing -------------------------------------------
__global__ void k_sniff(InPtrs in, int* flags) {
    int ai = blockIdx.x;
    if (ai >= NIN) return;
    __shared__ int cnt;
    if (threadIdx.x == 0) cnt = 0;
    __syncthreads();
    if (ai == 1) {
        const int* w = (const int*)in.p[1];
        int nw = in.n[1] < 512 ? in.n[1] : 512;
        int local = 0;
        for (int i = threadIdx.x; i < nw; i += blockDim.x)
            if ((i & 1) && w[i] != 0) local++;
        atomicAdd(&cnt, local);
        __syncthreads();
        if (threadIdx.x == 0) flags[1] = (cnt < 4) ? 1 : 0;
        return;
    }
    const unsigned short* u = (const unsigned short*)in.p[ai];
    int ns = in.n[ai] < 256 ? in.n[ai] : 256;
    int local = 0;
    for (int i = threadIdx.x; i < ns; i += blockDim.x) {
        if (i & 1) continue;
        unsigned short v = u[i];
        int e = (v >> 7) & 0xff;
        if ((v & 0x7fff) != 0 && (e < 100 || e > 154)) local++;
    }
    atomicAdd(&cnt, local);
    __syncthreads();
    if (threadIdx.x == 0) flags[ai] = (cnt * 4 >= ns) ? 1 : 0;
}

// ---------------- batched canonicalization ---------------------------------
__global__ void k_convall(ConvJobs J, const int* __restrict__ flags) {
    int b = blockIdx.x;
    int j = 0;
    while (j + 1 < J.njobs && b >= J.blk0[j + 1]) ++j;
    int i = (b - J.blk0[j]) * 256 + threadIdx.x;
    if (i >= J.n[j]) return;
    J.dst[j][i] = rdx(J.src[j], i, flags[J.ai[j]]);
}

// edge decode + row histogram fused (cnt pre-zeroed)
__global__ void k_conve(const void* src, int* row, int* col, int* cnt,
                        int E, const int* flags) {
    int i = blockIdx.x * blockDim.x + threadIdx.x;
    if (i >= E) return;
    int r, c;
    if (flags[1]) {
        const long long* s = (const long long*)src;
        r = (int)s[i];
        c = (int)s[(size_t)E + i];
    } else {
        const int* s = (const int*)src;
        r = s[i];
        c = s[(size_t)E + i];
    }
    row[i] = r;
    col[i] = c;
    atomicAdd(&cnt[r], 1);
}

// ---------------- CSR build ------------------------------------------------
__global__ void k_scan1(const int* __restrict__ deg, int* __restrict__ indptr,
                        int* __restrict__ bsums, int N) {
    __shared__ int buf[1024];
    const int t = threadIdx.x;
    const int base = blockIdx.x * 1024;
    int v = (base + t < N) ? deg[base + t] : 0;
    buf[t] = v;
    __syncthreads();
    for (int ofs = 1; ofs < 1024; ofs <<= 1) {
        int add = (t >= ofs) ? buf[t - ofs] : 0;
        __syncthreads();
        buf[t] += add;
        __syncthreads();
    }
    if (base + t < N) indptr[base + t] = buf[t] - v;
    if (t == 1023) bsums[blockIdx.x] = buf[1023];
}

__global__ void k_scan2(int* bsums, int nb) {
    if (threadIdx.x == 0 && blockIdx.x == 0) {
        int acc = 0;
        for (int j = 0; j < nb; ++j) { int v = bsums[j]; bsums[j] = acc; acc += v; }
        bsums[nb] = acc;
    }
}

// adds block offsets AND resets cnt for k_fill
__global__ void k_scan3(const int* __restrict__ bsums, int* __restrict__ indptr,
                        int* __restrict__ cnt, int N, int nb) {
    int i = blockIdx.x * blockDim.x + threadIdx.x;
    if (i < N) {
        indptr[i] += bsums[i >> 10];
        cnt[i] = 0;
    }
    if (i == 0) indptr[N] = bsums[nb];
}

__global__ void k_fill(const int* __restrict__ row, const int* __restrict__ col,
                       const int* __restrict__ indptr, int* __restrict__ cur,
                       int* __restrict__ colS, int* __restrict__ eidx, int E) {
    int i = blockIdx.x * blockDim.x + threadIdx.x;
    if (i >= E) return;
    int r = row[i];
    int p = indptr[r] + atomicAdd(&cur[r], 1);
    colS[p] = col[i];
    eidx[p] = i;
}

// ---------------- GAT linear layer 0 (in=3), hlin out bf16 -----------------
__global__ __launch_bounds__(256) void k_lin0(
    const float* __restrict__ x, const float* __restrict__ W0,
    const float* __restrict__ asrc, const float* __restrict__ adst,
    unsigned short* __restrict__ hlin, float* __restrict__ hs, float* __restrict__ hd,
    int N) {
    const int wid = threadIdx.x >> 6, lane = threadIdx.x & 63;
    const int n = blockIdx.x * 4 + wid;
    if (n >= N) return;
    float x0 = x[(size_t)n * 3], x1 = x[(size_t)n * 3 + 1], x2 = x[(size_t)n * 3 + 2];
    const int c0 = lane, c1 = lane + 64;
    float h0 = x0 * W0[c0] + x1 * W0[128 + c0] + x2 * W0[256 + c0];
    float h1 = x0 * W0[c1] + x1 * W0[128 + c1] + x2 * W0[256 + c1];
    hlin[(size_t)n * 128 + c0] = f2bf(h0);
    hlin[(size_t)n * 128 + c1] = f2bf(h1);
    float sp = h0 * asrc[c0] + h1 * asrc[c1];
    float dp = h0 * adst[c0] + h1 * adst[c1];
    for (int o = 32; o; o >>= 1) { sp += __shfl_down(sp, o); dp += __shfl_down(dp, o); }
    if (lane == 0) { hs[n] = sp; hd[n] = dp; }
}

// ---------------- GAT W pack (layers 1-2) into MFMA fragment order ---------
// Wg[layer][kb][frag][lane][j] (bf16) = W[layer][k*128+col], with
// k = kb*32 + (j>>2)*16 + (lane>>4)*4 + (j&3), col = frag*16 + (lane&15).
__global__ void k_wpackg(const float* __restrict__ Wcanon,   // [2][128][128] f32
                         unsigned short* __restrict__ Wg) {
    int idx = blockIdx.x * blockDim.x + threadIdx.x;
    if (idx >= 2 * 4 * 8 * 512) return;
    int layer = idx / 16384;
    int r  = idx % 16384;
    int kb = r / 4096;
    int r2 = r % 4096;
    int f  = r2 / 512;
    int q  = r2 % 512;
    int lane = q >> 3, j = q & 7;
    int k   = kb * 32 + ((j >> 2) * 16) + ((lane >> 4) * 4) + (j & 3);
    int col = f * 16 + (lane & 15);
    Wg[idx] = f2bf(Wcanon[(size_t)layer * 16384 + (size_t)k * 128 + col]);
}

// ---------------- GAT linear (MFMA): 64 nodes, 8 waves ---------------------
// Wave f owns col-frag f (cols f*16..f*16+15) across 4 row-frags.
// A-tile staged like the LSTM kernel; h written back to LDS then stored
// coalesced; hs/hd via shfl16 + LDS atomicAdd (LSTM score pattern).
__global__ __launch_bounds__(512) void k_linm(
    const unsigned short* __restrict__ xin,   // [N][128] bf16
    const unsigned short* __restrict__ Wg,    // [4][8][512] bf16 (this layer)
    const float* __restrict__ asrc, const float* __restrict__ adst,
    unsigned short* __restrict__ hlin, float* __restrict__ hs, float* __restrict__ hd,
    int N) {
    __shared__ unsigned short AS[64][136];
    __shared__ float hsS[64], hdS[64];
    const int t = threadIdx.x;
    const int f = t >> 6, lane = t & 63;
    const int n0 = blockIdx.x * 64;
    const int ccol = lane & 15;
    const int klane = lane >> 4;
    const int lrow = klane * 4;
    const int akl = klane * 4;
    const int m = f * 16 + ccol;

    const float asv = asrc[m], adv = adst[m];

    // stage x tile (zero-padded rows >= N)
    for (int i = t; i < 1024; i += 512) {
        int r = i >> 4, kq = (i & 15) * 8;
        u16x8 v = (u16x8)(0);
        if (n0 + r < N) v = *(const u16x8*)(xin + (size_t)(n0 + r) * 128 + kq);
        *(u16x8*)&AS[r][kq] = v;
    }
    if (t < 64) { hsS[t] = 0.f; hdS[t] = 0.f; }
    __syncthreads();

    // MFMA GEMM: acc[rf] over 4 kb
    f32x4 acc[4];
    #pragma unroll
    for (int rf = 0; rf < 4; ++rf) acc[rf] = (f32x4)(0.f);
    #pragma unroll
    for (int kb = 0; kb < 4; ++kb) {
        s16x8 b = *(const s16x8*)(Wg + ((size_t)kb * 8 + f) * 512 + lane * 8);
        const int k0 = kb * 32 + akl;
        #pragma unroll
        for (int rf = 0; rf < 4; ++rf) {
            s16x4 alo = *(const s16x4*)&AS[rf * 16 + ccol][k0];
            s16x4 ahi = *(const s16x4*)&AS[rf * 16 + ccol][k0 + 16];
            s16x8 av = __builtin_shufflevector(alo, ahi, 0, 1, 2, 3, 4, 5, 6, 7);
            acc[rf] = __builtin_amdgcn_mfma_f32_16x16x32_bf16(av, b, acc[rf], 0, 0, 0);
        }
    }
    __syncthreads();   // all A reads done before h overwrite

    // epilogue: write h to LDS + hs/hd partials
    float sp[16], dp[16];
    #pragma unroll
    for (int rf = 0; rf < 4; ++rf) {
        #pragma unroll
        for (int reg = 0; reg < 4; ++reg) {
            float h = acc[rf][reg];
            int ci = rf * 4 + reg;
            AS[rf * 16 + lrow + reg][m] = f2bf(h);
            sp[ci] = h * asv;
            dp[ci] = h * adv;
        }
    }
    #pragma unroll
    for (int o = 1; o < 16; o <<= 1) {
        #pragma unroll
        for (int i = 0; i < 16; ++i) { sp[i] += __shfl_xor(sp[i], o); dp[i] += __shfl_xor(dp[i], o); }
    }
    if (ccol == 0) {
        #pragma unroll
        for (int i = 0; i < 16; ++i) {
            int row = (i >> 2) * 16 + lrow + (i & 3);
            atomicAdd(&hsS[row], sp[i]);
            atomicAdd(&hdS[row], dp[i]);
        }
    }
    __syncthreads();

    // coalesced h store + hs/hd store
    for (int i = t; i < 1024; i += 512) {
        int r = i >> 4, kq = (i & 15) * 8;
        if (n0 + r < N)
            *(u16x8*)(hlin + (size_t)(n0 + r) * 128 + kq) = *(const u16x8*)&AS[r][kq];
    }
    if (t < 64 && n0 + t < N) { hs[n0 + t] = hsS[t]; hd[n0 + t] = hdS[t]; }
}

// ---------------- GAT aggregation: online segment softmax, 8-way unrolled --
__global__ __launch_bounds__(256) void k_aggr(
    const unsigned short* __restrict__ hlin, const float* __restrict__ hs,
    const float* __restrict__ hd,
    const int* __restrict__ indptr, const int* __restrict__ colS,
    const float* __restrict__ b, unsigned short* __restrict__ xout, int N) {
    const int wid = threadIdx.x >> 6, lane = threadIdx.x & 63;
    const int n = blockIdx.x * 4 + wid;
    if (n >= N) return;
    const int s = indptr[n], epos = indptr[n + 1];
    const float hdv = hd[n];
    const int c0 = lane, c1 = lane + 64;
    float m = -1e30f, d = 0.f, a0 = 0.f, a1 = 0.f;
    int idx = s;
    for (; idx + 8 <= epos; idx += 8) {
        int cl[8];
        #pragma unroll
        for (int j = 0; j < 8; ++j) cl[j] = colS[idx + j];
        float e[8];
        #pragma unroll
        for (int j = 0; j < 8; ++j) {
            float ev = hs[cl[j]] + hdv;
            e[j] = (ev > 0.f) ? ev : 0.2f * ev;
        }
        float v0[8], v1[8];
        #pragma unroll
        for (int j = 0; j < 8; ++j) {
            const unsigned short* hp = hlin + (size_t)cl[j] * 128;
            v0[j] = bf2f(hp[c0]);
            v1[j] = bf2f(hp[c1]);
        }
        float m8 = e[0];
        #pragma unroll
        for (int j = 1; j < 8; ++j) m8 = fmaxf(m8, e[j]);
        if (m8 > m) {
            float sc = __expf(m - m8);
            a0 *= sc; a1 *= sc; d *= sc; m = m8;
        }
        #pragma unroll
        for (int j = 0; j < 8; ++j) {
            float w = __expf(e[j] - m);
            a0 += w * v0[j];
            a1 += w * v1[j];
            d  += w;
        }
    }
    for (; idx < epos; ++idx) {
        int col = colS[idx];
        float e = hs[col] + hdv;
        e = (e > 0.f) ? e : 0.2f * e;
        const unsigned short* hr = hlin + (size_t)col * 128;
        float v0 = bf2f(hr[c0]), v1 = bf2f(hr[c1]);
        if (e > m) {
            float sc = __expf(m - e);
            a0 = a0 * sc + v0;
            a1 = a1 * sc + v1;
            d  = d * sc + 1.f;
            m  = e;
        } else {
            float w = __expf(e - m);
            a0 += w * v0;
            a1 += w * v1;
            d  += w;
        }
    }
    float inv = frcp(d + 1e-16f);
    float r0 = a0 * inv + b[c0];
    float r1 = a1 * inv + b[c1];
    xout[(size_t)n * 128 + c0] = f2bf(fmaxf(r0, 0.f));
    xout[(size_t)n * 128 + c1] = f2bf(fmaxf(r1, 0.f));
}

// ---------------- LSTM weight pack into MFMA fragment order ----------------
__global__ void k_wpack(const void* Wihf, const void* Whhf,
                        const void* Wihb, const void* Whhb,
                        const void* bihf, const void* bhhf,
                        const void* bihb, const void* bhhb,
                        const int* __restrict__ flags,
                        unsigned short* __restrict__ Bpack, float* __restrict__ bsum) {
    int idx = blockIdx.x * blockDim.x + threadIdx.x;
    const int TOT = 2 * 10 * 48 * 512;
    if (idx < TOT) {
        int dir = idx / (10 * 48 * 512);
        int r   = idx % (10 * 48 * 512);
        int kb  = r / (48 * 512);
        int r2  = r % (48 * 512);
        int f   = r2 / 512;
        int q   = r2 % 512;
        int lane = q >> 3, j = q & 7;
        int k   = kb * 32 + ((j >> 2) * 16) + ((lane >> 4) * 4) + (j & 3);
        int col = f * 16 + (lane & 15);
        float v;
        if (k < 128)
            v = dir ? rdx(Wihb, (size_t)col * 128 + k, flags[14])
                    : rdx(Wihf, (size_t)col * 128 + k, flags[10]);
        else
            v = dir ? rdx(Whhb, (size_t)col * 192 + (k - 128), flags[15])
                    : rdx(Whhf, (size_t)col * 192 + (k - 128), flags[11]);
        Bpack[idx] = f2bf(v);
    }
    if (idx < 2 * 768) {
        int d = idx / 768, j = idx % 768;
        bsum[idx] = d ? rdx(bihb, j, flags[16]) + rdx(bhhb, j, flags[17])
                      : rdx(bihf, j, flags[12]) + rdx(bhhf, j, flags[13]);
    }
}

// ---------------- fused bidirectional LSTM: 64 rows, 12 waves --------------
__global__ __launch_bounds__(768, 3) void k_lstm_mfma(
    const unsigned short* __restrict__ xsb,  // [3][N][128] bf16
    const unsigned short* __restrict__ Bpack,// [2][10][48][512] bf16
    const float* __restrict__ bsum,          // [2][768]
    const float* __restrict__ attW,          // [384]
    float* __restrict__ scoreP,              // [2][3][N]
    int N) {
    __shared__ unsigned short AS[64][332];   // x:[0,128)  h:[128,320)
    __shared__ float scoreS[64];
    const int t = threadIdx.x;
    const int bf = t >> 6, lane = t & 63;
    const int dir = blockIdx.y;
    const int n0 = blockIdx.x * 64;
    const int ccol = lane & 15;
    const int klane = lane >> 4;
    const int lrow = klane * 4;
    const int akl = klane * 4;
    const int m = bf * 16 + ccol;            // this thread's hidden unit

    const float bI = bsum[dir * 768 + m];
    const float bF = bsum[dir * 768 + 192 + m];
    const float bG = bsum[dir * 768 + 384 + m];
    const float bO = bsum[dir * 768 + 576 + m];
    const float awt = attW[dir * 192 + m];
    float cst[16];
    #pragma unroll
    for (int i = 0; i < 16; ++i) cst[i] = 0.f;

    const unsigned short* Bd = Bpack + (size_t)dir * 10 * 48 * 512;

    for (int s = 0; s < 3; ++s) {
        const int l = dir ? (2 - s) : s;
        // ---- stage x tile: 64x128 bf16 ----
        {
            const unsigned short* xsrc = xsb + ((size_t)l * N + n0) * 128;
            for (int i = t; i < 1024; i += 768) {
                int r = i >> 4, kq = (i & 15) * 8;
                u16x8 v = (u16x8)(0);
                if (n0 + r < N) v = *(const u16x8*)(xsrc + (size_t)r * 128 + kq);
                *(u16x8*)&AS[r][kq] = v;
            }
        }
        if (t < 64) scoreS[t] = 0.f;
        __syncthreads();

        // ---- MFMA GEMM over K, B ping-pong prefetch ----
        const int KB = s ? 10 : 4;               // both even
        f32x4 acc[4][4];
        #pragma unroll
        for (int rf = 0; rf < 4; ++rf)
            #pragma unroll
            for (int g = 0; g < 4; ++g) acc[rf][g] = (f32x4)(0.f);
        s16x8 bA[4], bB[4];
        {
            const unsigned short* bb = Bd + (size_t)bf * 512 + lane * 8;   // kb=0
            #pragma unroll
            for (int g = 0; g < 4; ++g) bA[g] = *(const s16x8*)(bb + (size_t)g * 6144);
        }
        for (int kb = 0; kb < KB; kb += 2) {
            {   // prefetch kb+1
                const unsigned short* bb = Bd + ((size_t)(kb + 1) * 48 + bf) * 512 + lane * 8;
                #pragma unroll
                for (int g = 0; g < 4; ++g) bB[g] = *(const s16x8*)(bb + (size_t)g * 6144);
            }
            {   // compute kb on bA
                const int k0 = kb * 32 + akl;
                s16x8 av[4];
                #pragma unroll
                for (int rf = 0; rf < 4; ++rf) {
                    s16x4 alo = *(const s16x4*)&AS[rf * 16 + ccol][k0];
                    s16x4 ahi = *(const s16x4*)&AS[rf * 16 + ccol][k0 + 16];
                    av[rf] = __builtin_shufflevector(alo, ahi, 0, 1, 2, 3, 4, 5, 6, 7);
                }
                #pragma unroll
                for (int rf = 0; rf < 4; ++rf)
                    #pragma unroll
                    for (int g = 0; g < 4; ++g)
                        acc[rf][g] = __builtin_amdgcn_mfma_f32_16x16x32_bf16(
                            av[rf], bA[g], acc[rf][g], 0, 0, 0);
            }
            if (kb + 2 < KB) {   // prefetch kb+2
                const unsigned short* bb = Bd + ((size_t)(kb + 2) * 48 + bf) * 512 + lane * 8;
                #pragma unroll
                for (int g = 0; g < 4; ++g) bA[g] = *(const s16x8*)(bb + (size_t)g * 6144);
            }
            {   // compute kb+1 on bB
                const int k0 = (kb + 1) * 32 + akl;
                s16x8 av[4];
                #pragma unroll
                for (int rf = 0; rf < 4; ++rf) {
                    s16x4 alo = *(const s16x4*)&AS[rf * 16 + ccol][k0];
                    s16x4 ahi = *(const s16x4*)&AS[rf * 16 + ccol][k0 + 16];
                    av[rf] = __builtin_shufflevector(alo, ahi, 0, 1, 2, 3, 4, 5, 6, 7);
                }
                #pragma unroll
                for (int rf = 0; rf < 4; ++rf)
                    #pragma unroll
                    for (int g = 0; g < 4; ++g)
                        acc[rf][g] = __builtin_amdgcn_mfma_f32_16x16x32_bf16(
                            av[rf], bB[g], acc[rf][g], 0, 0, 0);
            }
        }
        __syncthreads();   // all A reads done before h overwrite

        // ---- cell epilogue: one unit per thread, 16 rows (rcp-based) ----
        float sp[16];
        #pragma unroll
        for (int rf = 0; rf < 4; ++rf) {
            #pragma unroll
            for (int reg = 0; reg < 4; ++reg) {
                float gI = acc[rf][0][reg] + bI;
                float gF = acc[rf][1][reg] + bF;
                float gG = acc[rf][2][reg] + bG;
                float gO = acc[rf][3][reg] + bO;
                float ig = sigm(gI);
                float fg = sigm(gF);
                float gt = fast_tanh(gG);
                float og = sigm(gO);
                int ci = rf * 4 + reg;
                float cn = fg * cst[ci] + ig * gt;
                cst[ci] = cn;
                float hh = og * fast_tanh(cn);
                AS[rf * 16 + lrow + reg][128 + m] = f2bf(hh);
                sp[ci] = hh * awt;
            }
        }
        #pragma unroll
        for (int o = 1; o < 16; o <<= 1) {
            #pragma unroll
            for (int i = 0; i < 16; ++i) sp[i] += __shfl_xor(sp[i], o);
        }
        if (ccol == 0) {
            #pragma unroll
            for (int i = 0; i < 16; ++i)
                atomicAdd(&scoreS[(i >> 2) * 16 + lrow + (i & 3)], sp[i]);
        }
        __syncthreads();
        if (t < 64 && n0 + t < N)
            scoreP[(size_t)(dir * 3 + l) * N + n0 + t] = scoreS[t];
    }
}

// ---------------- fused tail: JK softmax-sum + node MLP + P/Q, 16 nodes ----
__global__ __launch_bounds__(256) void k_tail(
    const unsigned short* __restrict__ xsb, const float* __restrict__ scoreP,
    const float* __restrict__ nW1, const float* __restrict__ nb1,
    const float* __restrict__ nW2, const float* __restrict__ nb2,
    const float* __restrict__ eW1, const float* __restrict__ eb1,
    unsigned short* __restrict__ P, unsigned short* __restrict__ Q,
    float* __restrict__ out, int N) {
    __shared__ float xl[16][128];
    __shared__ float al[16][4];
    const int t = threadIdx.x;
    const int wid = t >> 6, lane = t & 63;
    const int nb = blockIdx.x * 16;
    if (t < 16) {
        int n = nb + t;
        float e0 = 0.f, e1 = 0.f, e2 = 0.f;
        if (n < N) {
            float s0 = scoreP[n]                 + scoreP[(size_t)3 * N + n];
            float s1 = scoreP[(size_t)N + n]     + scoreP[(size_t)4 * N + n];
            float s2 = scoreP[(size_t)2 * N + n] + scoreP[(size_t)5 * N + n];
            float mm = fmaxf(s0, fmaxf(s1, s2));
            e0 = __expf(s0 - mm); e1 = __expf(s1 - mm); e2 = __expf(s2 - mm);
            float inv = frcp(e0 + e1 + e2);
            e0 *= inv; e1 *= inv; e2 *= inv;
        }
        al[t][0] = e0; al[t][1] = e1; al[t][2] = e2;
    }
    __syncthreads();
    const size_t L1o = (size_t)N * 128, L2o = 2 * L1o;
    for (int i = t; i < 2048; i += 256) {
        int r = i >> 7, k = i & 127;
        int n = nb + r;
        float v = 0.f;
        if (n < N) {
            size_t p = (size_t)n * 128 + k;
            v = al[r][0] * bf2f(xsb[p]) + al[r][1] * bf2f(xsb[L1o + p])
              + al[r][2] * bf2f(xsb[L2o + p]);
        }
        xl[r][k] = v;
    }
    __syncthreads();
    const int c0 = lane, c1 = lane + 64;
    const int r0 = wid * 4;
    // ---- node MLP (4 nodes/wave) ----
    {
        float h0[4], h1[4];
        #pragma unroll
        for (int j = 0; j < 4; ++j) { h0[j] = 0.f; h1[j] = 0.f; }
        #pragma unroll 2
        for (int k = 0; k < 128; ++k) {
            float w0 = nW1[k * 128 + c0], w1 = nW1[k * 128 + c1];
            #pragma unroll
            for (int j = 0; j < 4; ++j) {
                float xv = xl[r0 + j][k];
                h0[j] += xv * w0;
                h1[j] += xv * w1;
            }
        }
        float p0[4], p1[4];
        #pragma unroll
        for (int j = 0; j < 4; ++j) {
            float a = fmaxf(h0[j] + nb1[c0], 0.f);
            float bq = fmaxf(h1[j] + nb1[c1], 0.f);
            p0[j] = a * nW2[c0 * 2 + 0] + bq * nW2[c1 * 2 + 0];
            p1[j] = a * nW2[c0 * 2 + 1] + bq * nW2[c1 * 2 + 1];
        }
        #pragma unroll
        for (int o = 32; o; o >>= 1) {
            #pragma unroll
            for (int j = 0; j < 4; ++j) {
                p0[j] += __shfl_down(p0[j], o);
                p1[j] += __shfl_down(p1[j], o);
            }
        }
        if (lane == 0) {
            #pragma unroll
            for (int j = 0; j < 4; ++j) {
                int n = nb + r0 + j;
                if (n < N) {
                    float l0 = p0[j] + nb2[0], l1 = p1[j] + nb2[1];
                    float mm = fmaxf(l0, l1);
                    float e0 = __expf(l0 - mm), e1 = __expf(l1 - mm);
                    float inv = frcp(e0 + e1);
                    out[2 * (size_t)n]     = e0 * inv;
                    out[2 * (size_t)n + 1] = e1 * inv;
                }
            }
        }
    }
    // ---- P/Q precompute (bf16 out, 4 nodes/wave) ----
    {
        float pp0[4], pp1[4], qq0[4], qq1[4];
        #pragma unroll
        for (int j = 0; j < 4; ++j) { pp0[j] = 0.f; pp1[j] = 0.f; qq0[j] = 0.f; qq1[j] = 0.f; }
        for (int k = 0; k < 128; ++k) {
            float wp0 = eW1[k * 128 + c0], wp1 = eW1[k * 128 + c1];
            float wq0 = eW1[(128 + k) * 128 + c0], wq1 = eW1[(128 + k) * 128 + c1];
            #pragma unroll
            for (int j = 0; j < 4; ++j) {
                float xv = xl[r0 + j][k];
                pp0[j] += xv * wp0; pp1[j] += xv * wp1;
                qq0[j] += xv * wq0; qq1[j] += xv * wq1;
            }
        }
        #pragma unroll
        for (int j = 0; j < 4; ++j) {
            int n = nb + r0 + j;
            if (n < N) {
                P[(size_t)n * 128 + c0] = f2bf(pp0[j] + eb1[c0]);
                P[(size_t)n * 128 + c1] = f2bf(pp1[j] + eb1[c1]);
                Q[(size_t)n * 128 + c0] = f2bf(qq0[j]);
                Q[(size_t)n * 128 + c1] = f2bf(qq1[j]);
            }
        }
    }
}

// ---------------- edge MLP finish: CSR order, P amortized per node ---------
__global__ __launch_bounds__(256) void k_edge3(
    const unsigned short* __restrict__ P, const unsigned short* __restrict__ Q,
    const int* __restrict__ indptr, const int* __restrict__ colS,
    const int* __restrict__ eidx,
    const float* __restrict__ W2, const float* __restrict__ b2,
    float* __restrict__ out, int N) {
    const int wid = threadIdx.x >> 6, lane = threadIdx.x & 63;
    const int n = blockIdx.x * 4 + wid;
    if (n >= N) return;
    const int sl = lane & 15, g = lane >> 4;
    const int s = indptr[n], e = indptr[n + 1];
    float pf[8];
    {
        u16x8 pv = *(const u16x8*)(P + (size_t)n * 128 + sl * 8);
        #pragma unroll
        for (int j = 0; j < 8; ++j) pf[j] = bf2f(pv[j]);
    }
    const float* W2f = W2;
    const float b20 = b2[0], b21 = b2[1];
    for (int p = s + g; p < e; p += 8) {
        int p1 = p + 4;
        bool v1 = p1 < e;
        int col0 = colS[p],  eo0 = eidx[p];
        int col1 = v1 ? colS[p1] : col0;
        int eo1  = v1 ? eidx[p1] : 0;
        u16x8 qv0 = *(const u16x8*)(Q + (size_t)col0 * 128 + sl * 8);
        u16x8 qv1 = *(const u16x8*)(Q + (size_t)col1 * 128 + sl * 8);
        float l00 = 0.f, l01 = 0.f, l10 = 0.f, l11 = 0.f;
        #pragma unroll
        for (int j = 0; j < 8; ++j) {
            int ch = sl * 8 + j;
            float wA = W2f[ch * 2], wB = W2f[ch * 2 + 1];
            float h0 = fmaxf(pf[j] + bf2f(qv0[j]), 0.f);
            float h1 = fmaxf(pf[j] + bf2f(qv1[j]), 0.f);
            l00 += h0 * wA; l01 += h0 * wB;
            l10 += h1 * wA; l11 += h1 * wB;
        }
        #pragma unroll
        for (int o = 1; o < 16; o <<= 1) {
            l00 += __shfl_xor(l00, o); l01 += __shfl_xor(l01, o);
            l10 += __shfl_xor(l10, o); l11 += __shfl_xor(l11, o);
        }
        if (sl == 0) {
            {
                float a = l00 + b20, b = l01 + b21;
                float mm = fmaxf(a, b);
                float e0 = __expf(a - mm), e1 = __expf(b - mm);
                float inv = frcp(e0 + e1);
                out[2 * (size_t)N + 2 * (size_t)eo0]     = e0 * inv;
                out[2 * (size_t)N + 2 * (size_t)eo0 + 1] = e1 * inv;
            }
            if (v1) {
                float a = l10 + b20, b = l11 + b21;
                float mm = fmaxf(a, b);
                float e0 = __expf(a - mm), e1 = __expf(b - mm);
                float inv = frcp(e0 + e1);
                out[2 * (size_t)N + 2 * (size_t)eo1]     = e0 * inv;
                out[2 * (size_t)N + 2 * (size_t)eo1 + 1] = e1 * inv;
            }
        }
    }
}

// ---------------------------------------------------------------------------
extern "C" void kernel_launch(void* const* d_in, const int* in_sizes, int n_in,
                              void* d_out, int out_size, void* d_ws, size_t ws_size,
                              hipStream_t stream) {
    if (n_in < NIN) return;
    const int N = in_sizes[0] / 3;
    const int E = in_sizes[1] / 2;

    char* ws = (char*)d_ws;
    size_t off = 0;
    auto alloc = [&](size_t bytes) -> char* {
        char* p = ws + off;
        off = (off + bytes + 255) & ~(size_t)255;
        return p;
    };
    int* flags = (int*)alloc(32 * sizeof(int));
    int* bsums = (int*)alloc(128 * sizeof(int));
    float* canon[NIN];
    for (int i = 0; i < NIN; ++i) canon[i] = nullptr;
    for (int i = 0; i < NIN; ++i) {
        if (i == 1 || (i >= 10 && i <= 17)) continue;   // LSTM weights read raw
        canon[i] = (float*)alloc((size_t)in_sizes[i] * 4);
    }
    int* row32  = (int*)alloc((size_t)E * 4);
    int* col32  = (int*)alloc((size_t)E * 4);
    int* indptr = (int*)alloc((size_t)(N + 1) * 4);
    int* cnt    = (int*)alloc((size_t)N * 4);
    int* colS   = (int*)alloc((size_t)E * 4);
    int* eidx   = (int*)alloc((size_t)E * 4);
    float* hs   = (float*)alloc((size_t)N * 4);
    float* hd   = (float*)alloc((size_t)N * 4);
    // hJK buffer: bf16 hlin during GAT phase; bf16 P/Q after the LSTM
    float* hJK  = (float*)alloc((size_t)N * 128 * 4);
    unsigned short* hlin = (unsigned short*)hJK;
    unsigned short* xsb = (unsigned short*)alloc((size_t)3 * N * 128 * 2);  // bf16 xs
    unsigned short* Bpack = (unsigned short*)alloc((size_t)2 * 10 * 48 * 512 * 2);
    unsigned short* Wg = (unsigned short*)alloc((size_t)2 * 4 * 8 * 512 * 2);
    float* bsum = (float*)alloc((size_t)2 * 768 * 4);
    float* scoreP = (float*)alloc((size_t)6 * N * 4);
    if (off > ws_size) return;
    unsigned short* P = (unsigned short*)hJK;           // bf16, N*128
    unsigned short* Q = (unsigned short*)hJK + (size_t)N * 128;

    InPtrs ip;
    for (int i = 0; i < NIN; ++i) { ip.p[i] = d_in[i]; ip.n[i] = in_sizes[i]; }

    k_sniff<<<NIN, 256, 0, stream>>>(ip, flags);

    // batched canonicalization of all f32/bf16 inputs
    {
        ConvJobs J;
        int nj = 0, blk = 0;
        for (int i = 0; i < NIN; ++i) {
            if (i == 1 || (i >= 10 && i <= 17)) continue;
            J.src[nj] = d_in[i];
            J.dst[nj] = canon[i];
            J.n[nj] = in_sizes[i];
            J.ai[nj] = i;
            J.blk0[nj] = blk;
            blk += (in_sizes[i] + 255) / 256;
            ++nj;
        }
        J.blk0[nj] = blk;
        J.njobs = nj;
        k_convall<<<blk, 256, 0, stream>>>(J, flags);
    }
    // edge decode + histogram (cnt pre-zeroed by memset)
    hipMemsetAsync(cnt, 0, (size_t)N * 4, stream);
    k_conve<<<(E + 255) / 256, 256, 0, stream>>>(d_in[1], row32, col32, cnt, E, flags);
    k_wpack<<<(2 * 10 * 48 * 512 + 255) / 256, 256, 0, stream>>>(
        d_in[10], d_in[11], d_in[14], d_in[15],
        d_in[12], d_in[13], d_in[16], d_in[17], flags, Bpack, bsum);
    k_wpackg<<<(2 * 4 * 8 * 512 + 255) / 256, 256, 0, stream>>>(canon[6], Wg);

    // CSR scan (scan3 also resets cnt for k_fill)
    const int nb1k = (N + 1023) / 1024;
    k_scan1<<<nb1k, 1024, 0, stream>>>(cnt, indptr, bsums, N);
    k_scan2<<<1, 64, 0, stream>>>(bsums, nb1k);
    k_scan3<<<(N + 255) / 256, 256, 0, stream>>>(bsums, indptr, cnt, N, nb1k);
    k_fill<<<(E + 255) / 256, 256, 0, stream>>>(row32, col32, indptr, cnt, colS, eidx, E);

    // GAT layer 0 (in=3)
    k_lin0<<<(N + 3) / 4, 256, 0, stream>>>(canon[0], canon[2], canon[4], canon[5],
                                            hlin, hs, hd, N);
    k_aggr<<<(N + 3) / 4, 256, 0, stream>>>(hlin, hs, hd, indptr, colS, canon[3], xsb, N);
    // GAT layers 1..2 (MFMA linear, bf16 in/out)
    for (int l = 1; l < 3; ++l) {
        const unsigned short* Wgl = Wg + (size_t)(l - 1) * 4 * 8 * 512;
        const float* bb = canon[7] + (size_t)(l - 1) * 128;
        const float* as = canon[8] + (size_t)(l - 1) * 128;
        const float* ad = canon[9] + (size_t)(l - 1) * 128;
        k_linm<<<(N + 63) / 64, 512, 0, stream>>>(xsb + (size_t)(l - 1) * N * 128, Wgl,
                                                  as, ad, hlin, hs, hd, N);
        k_aggr<<<(N + 3) / 4, 256, 0, stream>>>(hlin, hs, hd, indptr, colS, bb,
                                                xsb + (size_t)l * N * 128, N);
    }

    // fused bidirectional LSTM (MFMA, 64-row 12-wave) -> scores
    dim3 lgrid((N + 63) / 64, 2);
    k_lstm_mfma<<<lgrid, 768, 0, stream>>>(xsb, Bpack, bsum, canon[18], scoreP, N);

    float* out = (float*)d_out;
    // fused tail: JK finish + node MLP + P/Q (P/Q overwrite dead hlin buffer)
    k_tail<<<(N + 15) / 16, 256, 0, stream>>>(xsb, scoreP,
                                              canon[20], canon[21], canon[22], canon[23],
                                              canon[24], canon[25], P, Q, out, N);
    // edge MLP in CSR order (P amortized per node; scatter via eidx)
    k_edge3<<<(N + 3) / 4, 256, 0, stream>>>(P, Q, indptr, colS, eidx,
                                             canon[26], canon[27], out, N);
}

// Round 17
// 594.897 us; speedup vs baseline: 1.2047x; 1.1291x over previous
//
#include <hip/hip_runtime.h>
#include <cstdint>
#include <cstddef>

// ---------------------------------------------------------------------------
// ParityGameGATNetwork: 3x GATConv -> JK bidirectional LSTM -> node/edge MLPs
// Round 17: tail GEMMs (node MLP + edge P/Q = 4.9 GF f32 VALU, est ~100us)
// moved to one MFMA kernel k_tailm: A = JK-weighted xsb sum staged bf16 in
// LDS (k_linm layout), 24 col-frags = [nW1 | eW1-top | eW1-bot] packed by
// k_wpackt; node logits via shfl16+LDS-atomic; P/Q stored via LDS coalesced.
// Everything else identical to round 16.
// ---------------------------------------------------------------------------

#define NIN 28
#define MAXJOBS 20

struct InPtrs { const void* p[NIN]; int n[NIN]; };

struct ConvJobs {
    const void* src[MAXJOBS];
    float* dst[MAXJOBS];
    int n[MAXJOBS];
    int ai[MAXJOBS];
    int blk0[MAXJOBS + 1];
    int njobs;
};

typedef short s16x4 __attribute__((ext_vector_type(4)));
typedef short s16x8 __attribute__((ext_vector_type(8)));
typedef float f32x4 __attribute__((ext_vector_type(4)));
typedef unsigned short u16x8 __attribute__((ext_vector_type(8)));

__device__ __forceinline__ float bf2f(unsigned short v) {
    unsigned int u = ((unsigned int)v) << 16;
    return __uint_as_float(u);
}

__device__ __forceinline__ unsigned short f2bf(float x) {
    unsigned int u = __float_as_uint(x);
    unsigned int r = u + 0x7fffu + ((u >> 16) & 1u);
    return (unsigned short)(r >> 16);
}

__device__ __forceinline__ float rdx(const void* p, size_t i, int isf32) {
    return isf32 ? ((const float*)p)[i] : bf2f(((const unsigned short*)p)[i]);
}

__device__ __forceinline__ float frcp(float x) {        // raw v_rcp_f32 (~1ulp)
    return __builtin_amdgcn_rcpf(x);
}

__device__ __forceinline__ float sigm(float x) {
    return frcp(1.f + __expf(-x));
}

__device__ __forceinline__ float fast_tanh(float x) {
    return 1.f - 2.f * frcp(__expf(2.f * x) + 1.f);
}

// ---------------- dtype sniffing -------------------------------------------
__global__ void k_sniff(InPtrs in, int* flags) {
    int ai = blockIdx.x;
    if (ai >= NIN) return;
    __shared__ int cnt;
    if (threadIdx.x == 0) cnt = 0;
    __syncthreads();
    if (ai == 1) {
        const int* w = (const int*)in.p[1];
        int nw = in.n[1] < 512 ? in.n[1] : 512;
        int local = 0;
        for (int i = threadIdx.x; i < nw; i += blockDim.x)
            if ((i & 1) && w[i] != 0) local++;
        atomicAdd(&cnt, local);
        __syncthreads();
        if (threadIdx.x == 0) flags[1] = (cnt < 4) ? 1 : 0;
        return;
    }
    const unsigned short* u = (const unsigned short*)in.p[ai];
    int ns = in.n[ai] < 256 ? in.n[ai] : 256;
    int local = 0;
    for (int i = threadIdx.x; i < ns; i += blockDim.x) {
        if (i & 1) continue;
        unsigned short v = u[i];
        int e = (v >> 7) & 0xff;
        if ((v & 0x7fff) != 0 && (e < 100 || e > 154)) local++;
    }
    atomicAdd(&cnt, local);
    __syncthreads();
    if (threadIdx.x == 0) flags[ai] = (cnt * 4 >= ns) ? 1 : 0;
}

// ---------------- batched canonicalization ---------------------------------
__global__ void k_convall(ConvJobs J, const int* __restrict__ flags) {
    int b = blockIdx.x;
    int j = 0;
    while (j + 1 < J.njobs && b >= J.blk0[j + 1]) ++j;
    int i = (b - J.blk0[j]) * 256 + threadIdx.x;
    if (i >= J.n[j]) return;
    J.dst[j][i] = rdx(J.src[j], i, flags[J.ai[j]]);
}

// edge decode + row histogram fused (cnt pre-zeroed)
__global__ void k_conve(const void* src, int* row, int* col, int* cnt,
                        int E, const int* flags) {
    int i = blockIdx.x * blockDim.x + threadIdx.x;
    if (i >= E) return;
    int r, c;
    if (flags[1]) {
        const long long* s = (const long long*)src;
        r = (int)s[i];
        c = (int)s[(size_t)E + i];
    } else {
        const int* s = (const int*)src;
        r = s[i];
        c = s[(size_t)E + i];
    }
    row[i] = r;
    col[i] = c;
    atomicAdd(&cnt[r], 1);
}

// ---------------- CSR build ------------------------------------------------
__global__ void k_scan1(const int* __restrict__ deg, int* __restrict__ indptr,
                        int* __restrict__ bsums, int N) {
    __shared__ int buf[1024];
    const int t = threadIdx.x;
    const int base = blockIdx.x * 1024;
    int v = (base + t < N) ? deg[base + t] : 0;
    buf[t] = v;
    __syncthreads();
    for (int ofs = 1; ofs < 1024; ofs <<= 1) {
        int add = (t >= ofs) ? buf[t - ofs] : 0;
        __syncthreads();
        buf[t] += add;
        __syncthreads();
    }
    if (base + t < N) indptr[base + t] = buf[t] - v;
    if (t == 1023) bsums[blockIdx.x] = buf[1023];
}

__global__ void k_scan2(int* bsums, int nb) {
    if (threadIdx.x == 0 && blockIdx.x == 0) {
        int acc = 0;
        for (int j = 0; j < nb; ++j) { int v = bsums[j]; bsums[j] = acc; acc += v; }
        bsums[nb] = acc;
    }
}

// adds block offsets AND resets cnt for k_fill
__global__ void k_scan3(const int* __restrict__ bsums, int* __restrict__ indptr,
                        int* __restrict__ cnt, int N, int nb) {
    int i = blockIdx.x * blockDim.x + threadIdx.x;
    if (i < N) {
        indptr[i] += bsums[i >> 10];
        cnt[i] = 0;
    }
    if (i == 0) indptr[N] = bsums[nb];
}

__global__ void k_fill(const int* __restrict__ row, const int* __restrict__ col,
                       const int* __restrict__ indptr, int* __restrict__ cur,
                       int* __restrict__ colS, int* __restrict__ eidx, int E) {
    int i = blockIdx.x * blockDim.x + threadIdx.x;
    if (i >= E) return;
    int r = row[i];
    int p = indptr[r] + atomicAdd(&cur[r], 1);
    colS[p] = col[i];
    eidx[p] = i;
}

// ---------------- GAT linear layer 0 (in=3), hlin out bf16 -----------------
__global__ __launch_bounds__(256) void k_lin0(
    const float* __restrict__ x, const float* __restrict__ W0,
    const float* __restrict__ asrc, const float* __restrict__ adst,
    unsigned short* __restrict__ hlin, float* __restrict__ hs, float* __restrict__ hd,
    int N) {
    const int wid = threadIdx.x >> 6, lane = threadIdx.x & 63;
    const int n = blockIdx.x * 4 + wid;
    if (n >= N) return;
    float x0 = x[(size_t)n * 3], x1 = x[(size_t)n * 3 + 1], x2 = x[(size_t)n * 3 + 2];
    const int c0 = lane, c1 = lane + 64;
    float h0 = x0 * W0[c0] + x1 * W0[128 + c0] + x2 * W0[256 + c0];
    float h1 = x0 * W0[c1] + x1 * W0[128 + c1] + x2 * W0[256 + c1];
    hlin[(size_t)n * 128 + c0] = f2bf(h0);
    hlin[(size_t)n * 128 + c1] = f2bf(h1);
    float sp = h0 * asrc[c0] + h1 * asrc[c1];
    float dp = h0 * adst[c0] + h1 * adst[c1];
    for (int o = 32; o; o >>= 1) { sp += __shfl_down(sp, o); dp += __shfl_down(dp, o); }
    if (lane == 0) { hs[n] = sp; hd[n] = dp; }
}

// ---------------- GAT W pack (layers 1-2) into MFMA fragment order ---------
__global__ void k_wpackg(const float* __restrict__ Wcanon,   // [2][128][128] f32
                         unsigned short* __restrict__ Wg) {
    int idx = blockIdx.x * blockDim.x + threadIdx.x;
    if (idx >= 2 * 4 * 8 * 512) return;
    int layer = idx / 16384;
    int r  = idx % 16384;
    int kb = r / 4096;
    int r2 = r % 4096;
    int f  = r2 / 512;
    int q  = r2 % 512;
    int lane = q >> 3, j = q & 7;
    int k   = kb * 32 + ((j >> 2) * 16) + ((lane >> 4) * 4) + (j & 3);
    int col = f * 16 + (lane & 15);
    Wg[idx] = f2bf(Wcanon[(size_t)layer * 16384 + (size_t)k * 128 + col]);
}

// ---------------- tail W pack: [4 kb][24 fr][512]; fr<8: nW1, 8-15: eW1 top,
// 16-23: eW1 bottom. Same fragment k-map as k_wpackg.
__global__ void k_wpackt(const float* __restrict__ nW1, const float* __restrict__ eW1,
                         unsigned short* __restrict__ Wt) {
    int idx = blockIdx.x * blockDim.x + threadIdx.x;
    if (idx >= 4 * 24 * 512) return;
    int kb = idx / (24 * 512);
    int r  = idx % (24 * 512);
    int fr = r / 512;
    int q  = r % 512;
    int lane = q >> 3, j = q & 7;
    int k   = kb * 32 + ((j >> 2) * 16) + ((lane >> 4) * 4) + (j & 3);
    int grp = fr >> 3;
    int col = (fr & 7) * 16 + (lane & 15);
    float v;
    if (grp == 0)      v = nW1[(size_t)k * 128 + col];
    else if (grp == 1) v = eW1[(size_t)k * 128 + col];
    else               v = eW1[(size_t)(128 + k) * 128 + col];
    Wt[idx] = f2bf(v);
}

// ---------------- GAT linear (MFMA): 64 nodes, 8 waves ---------------------
__global__ __launch_bounds__(512) void k_linm(
    const unsigned short* __restrict__ xin,   // [N][128] bf16
    const unsigned short* __restrict__ Wg,    // [4][8][512] bf16 (this layer)
    const float* __restrict__ asrc, const float* __restrict__ adst,
    unsigned short* __restrict__ hlin, float* __restrict__ hs, float* __restrict__ hd,
    int N) {
    __shared__ unsigned short AS[64][136];
    __shared__ float hsS[64], hdS[64];
    const int t = threadIdx.x;
    const int f = t >> 6, lane = t & 63;
    const int n0 = blockIdx.x * 64;
    const int ccol = lane & 15;
    const int klane = lane >> 4;
    const int lrow = klane * 4;
    const int akl = klane * 4;
    const int m = f * 16 + ccol;

    const float asv = asrc[m], adv = adst[m];

    for (int i = t; i < 1024; i += 512) {
        int r = i >> 4, kq = (i & 15) * 8;
        u16x8 v = (u16x8)(0);
        if (n0 + r < N) v = *(const u16x8*)(xin + (size_t)(n0 + r) * 128 + kq);
        *(u16x8*)&AS[r][kq] = v;
    }
    if (t < 64) { hsS[t] = 0.f; hdS[t] = 0.f; }
    __syncthreads();

    f32x4 acc[4];
    #pragma unroll
    for (int rf = 0; rf < 4; ++rf) acc[rf] = (f32x4)(0.f);
    #pragma unroll
    for (int kb = 0; kb < 4; ++kb) {
        s16x8 b = *(const s16x8*)(Wg + ((size_t)kb * 8 + f) * 512 + lane * 8);
        const int k0 = kb * 32 + akl;
        #pragma unroll
        for (int rf = 0; rf < 4; ++rf) {
            s16x4 alo = *(const s16x4*)&AS[rf * 16 + ccol][k0];
            s16x4 ahi = *(const s16x4*)&AS[rf * 16 + ccol][k0 + 16];
            s16x8 av = __builtin_shufflevector(alo, ahi, 0, 1, 2, 3, 4, 5, 6, 7);
            acc[rf] = __builtin_amdgcn_mfma_f32_16x16x32_bf16(av, b, acc[rf], 0, 0, 0);
        }
    }
    __syncthreads();   // all A reads done before h overwrite

    float sp[16], dp[16];
    #pragma unroll
    for (int rf = 0; rf < 4; ++rf) {
        #pragma unroll
        for (int reg = 0; reg < 4; ++reg) {
            float h = acc[rf][reg];
            int ci = rf * 4 + reg;
            AS[rf * 16 + lrow + reg][m] = f2bf(h);
            sp[ci] = h * asv;
            dp[ci] = h * adv;
        }
    }
    #pragma unroll
    for (int o = 1; o < 16; o <<= 1) {
        #pragma unroll
        for (int i = 0; i < 16; ++i) { sp[i] += __shfl_xor(sp[i], o); dp[i] += __shfl_xor(dp[i], o); }
    }
    if (ccol == 0) {
        #pragma unroll
        for (int i = 0; i < 16; ++i) {
            int row = (i >> 2) * 16 + lrow + (i & 3);
            atomicAdd(&hsS[row], sp[i]);
            atomicAdd(&hdS[row], dp[i]);
        }
    }
    __syncthreads();

    for (int i = t; i < 1024; i += 512) {
        int r = i >> 4, kq = (i & 15) * 8;
        if (n0 + r < N)
            *(u16x8*)(hlin + (size_t)(n0 + r) * 128 + kq) = *(const u16x8*)&AS[r][kq];
    }
    if (t < 64 && n0 + t < N) { hs[n0 + t] = hsS[t]; hd[n0 + t] = hdS[t]; }
}

// ---------------- GAT aggregation: online segment softmax, 8-way unrolled --
__global__ __launch_bounds__(256) void k_aggr(
    const unsigned short* __restrict__ hlin, const float* __restrict__ hs,
    const float* __restrict__ hd,
    const int* __restrict__ indptr, const int* __restrict__ colS,
    const float* __restrict__ b, unsigned short* __restrict__ xout, int N) {
    const int wid = threadIdx.x >> 6, lane = threadIdx.x & 63;
    const int n = blockIdx.x * 4 + wid;
    if (n >= N) return;
    const int s = indptr[n], epos = indptr[n + 1];
    const float hdv = hd[n];
    const int c0 = lane, c1 = lane + 64;
    float m = -1e30f, d = 0.f, a0 = 0.f, a1 = 0.f;
    int idx = s;
    for (; idx + 8 <= epos; idx += 8) {
        int cl[8];
        #pragma unroll
        for (int j = 0; j < 8; ++j) cl[j] = colS[idx + j];
        float e[8];
        #pragma unroll
        for (int j = 0; j < 8; ++j) {
            float ev = hs[cl[j]] + hdv;
            e[j] = (ev > 0.f) ? ev : 0.2f * ev;
        }
        float v0[8], v1[8];
        #pragma unroll
        for (int j = 0; j < 8; ++j) {
            const unsigned short* hp = hlin + (size_t)cl[j] * 128;
            v0[j] = bf2f(hp[c0]);
            v1[j] = bf2f(hp[c1]);
        }
        float m8 = e[0];
        #pragma unroll
        for (int j = 1; j < 8; ++j) m8 = fmaxf(m8, e[j]);
        if (m8 > m) {
            float sc = __expf(m - m8);
            a0 *= sc; a1 *= sc; d *= sc; m = m8;
        }
        #pragma unroll
        for (int j = 0; j < 8; ++j) {
            float w = __expf(e[j] - m);
            a0 += w * v0[j];
            a1 += w * v1[j];
            d  += w;
        }
    }
    for (; idx < epos; ++idx) {
        int col = colS[idx];
        float e = hs[col] + hdv;
        e = (e > 0.f) ? e : 0.2f * e;
        const unsigned short* hr = hlin + (size_t)col * 128;
        float v0 = bf2f(hr[c0]), v1 = bf2f(hr[c1]);
        if (e > m) {
            float sc = __expf(m - e);
            a0 = a0 * sc + v0;
            a1 = a1 * sc + v1;
            d  = d * sc + 1.f;
            m  = e;
        } else {
            float w = __expf(e - m);
            a0 += w * v0;
            a1 += w * v1;
            d  += w;
        }
    }
    float inv = frcp(d + 1e-16f);
    float r0 = a0 * inv + b[c0];
    float r1 = a1 * inv + b[c1];
    xout[(size_t)n * 128 + c0] = f2bf(fmaxf(r0, 0.f));
    xout[(size_t)n * 128 + c1] = f2bf(fmaxf(r1, 0.f));
}

// ---------------- LSTM weight pack into MFMA fragment order ----------------
__global__ void k_wpack(const void* Wihf, const void* Whhf,
                        const void* Wihb, const void* Whhb,
                        const void* bihf, const void* bhhf,
                        const void* bihb, const void* bhhb,
                        const int* __restrict__ flags,
                        unsigned short* __restrict__ Bpack, float* __restrict__ bsum) {
    int idx = blockIdx.x * blockDim.x + threadIdx.x;
    const int TOT = 2 * 10 * 48 * 512;
    if (idx < TOT) {
        int dir = idx / (10 * 48 * 512);
        int r   = idx % (10 * 48 * 512);
        int kb  = r / (48 * 512);
        int r2  = r % (48 * 512);
        int f   = r2 / 512;
        int q   = r2 % 512;
        int lane = q >> 3, j = q & 7;
        int k   = kb * 32 + ((j >> 2) * 16) + ((lane >> 4) * 4) + (j & 3);
        int col = f * 16 + (lane & 15);
        float v;
        if (k < 128)
            v = dir ? rdx(Wihb, (size_t)col * 128 + k, flags[14])
                    : rdx(Wihf, (size_t)col * 128 + k, flags[10]);
        else
            v = dir ? rdx(Whhb, (size_t)col * 192 + (k - 128), flags[15])
                    : rdx(Whhf, (size_t)col * 192 + (k - 128), flags[11]);
        Bpack[idx] = f2bf(v);
    }
    if (idx < 2 * 768) {
        int d = idx / 768, j = idx % 768;
        bsum[idx] = d ? rdx(bihb, j, flags[16]) + rdx(bhhb, j, flags[17])
                      : rdx(bihf, j, flags[12]) + rdx(bhhf, j, flags[13]);
    }
}

// ---------------- fused bidirectional LSTM: 64 rows, 12 waves --------------
__global__ __launch_bounds__(768, 3) void k_lstm_mfma(
    const unsigned short* __restrict__ xsb,  // [3][N][128] bf16
    const unsigned short* __restrict__ Bpack,// [2][10][48][512] bf16
    const float* __restrict__ bsum,          // [2][768]
    const float* __restrict__ attW,          // [384]
    float* __restrict__ scoreP,              // [2][3][N]
    int N) {
    __shared__ unsigned short AS[64][332];   // x:[0,128)  h:[128,320)
    __shared__ float scoreS[64];
    const int t = threadIdx.x;
    const int bf = t >> 6, lane = t & 63;
    const int dir = blockIdx.y;
    const int n0 = blockIdx.x * 64;
    const int ccol = lane & 15;
    const int klane = lane >> 4;
    const int lrow = klane * 4;
    const int akl = klane * 4;
    const int m = bf * 16 + ccol;            // this thread's hidden unit

    const float bI = bsum[dir * 768 + m];
    const float bF = bsum[dir * 768 + 192 + m];
    const float bG = bsum[dir * 768 + 384 + m];
    const float bO = bsum[dir * 768 + 576 + m];
    const float awt = attW[dir * 192 + m];
    float cst[16];
    #pragma unroll
    for (int i = 0; i < 16; ++i) cst[i] = 0.f;

    const unsigned short* Bd = Bpack + (size_t)dir * 10 * 48 * 512;

    for (int s = 0; s < 3; ++s) {
        const int l = dir ? (2 - s) : s;
        // ---- stage x tile: 64x128 bf16 ----
        {
            const unsigned short* xsrc = xsb + ((size_t)l * N + n0) * 128;
            for (int i = t; i < 1024; i += 768) {
                int r = i >> 4, kq = (i & 15) * 8;
                u16x8 v = (u16x8)(0);
                if (n0 + r < N) v = *(const u16x8*)(xsrc + (size_t)r * 128 + kq);
                *(u16x8*)&AS[r][kq] = v;
            }
        }
        if (t < 64) scoreS[t] = 0.f;
        __syncthreads();

        // ---- MFMA GEMM over K, B ping-pong prefetch ----
        const int KB = s ? 10 : 4;               // both even
        f32x4 acc[4][4];
        #pragma unroll
        for (int rf = 0; rf < 4; ++rf)
            #pragma unroll
            for (int g = 0; g < 4; ++g) acc[rf][g] = (f32x4)(0.f);
        s16x8 bA[4], bB[4];
        {
            const unsigned short* bb = Bd + (size_t)bf * 512 + lane * 8;   // kb=0
            #pragma unroll
            for (int g = 0; g < 4; ++g) bA[g] = *(const s16x8*)(bb + (size_t)g * 6144);
        }
        for (int kb = 0; kb < KB; kb += 2) {
            {   // prefetch kb+1
                const unsigned short* bb = Bd + ((size_t)(kb + 1) * 48 + bf) * 512 + lane * 8;
                #pragma unroll
                for (int g = 0; g < 4; ++g) bB[g] = *(const s16x8*)(bb + (size_t)g * 6144);
            }
            {   // compute kb on bA
                const int k0 = kb * 32 + akl;
                s16x8 av[4];
                #pragma unroll
                for (int rf = 0; rf < 4; ++rf) {
                    s16x4 alo = *(const s16x4*)&AS[rf * 16 + ccol][k0];
                    s16x4 ahi = *(const s16x4*)&AS[rf * 16 + ccol][k0 + 16];
                    av[rf] = __builtin_shufflevector(alo, ahi, 0, 1, 2, 3, 4, 5, 6, 7);
                }
                #pragma unroll
                for (int rf = 0; rf < 4; ++rf)
                    #pragma unroll
                    for (int g = 0; g < 4; ++g)
                        acc[rf][g] = __builtin_amdgcn_mfma_f32_16x16x32_bf16(
                            av[rf], bA[g], acc[rf][g], 0, 0, 0);
            }
            if (kb + 2 < KB) {   // prefetch kb+2
                const unsigned short* bb = Bd + ((size_t)(kb + 2) * 48 + bf) * 512 + lane * 8;
                #pragma unroll
                for (int g = 0; g < 4; ++g) bA[g] = *(const s16x8*)(bb + (size_t)g * 6144);
            }
            {   // compute kb+1 on bB
                const int k0 = (kb + 1) * 32 + akl;
                s16x8 av[4];
                #pragma unroll
                for (int rf = 0; rf < 4; ++rf) {
                    s16x4 alo = *(const s16x4*)&AS[rf * 16 + ccol][k0];
                    s16x4 ahi = *(const s16x4*)&AS[rf * 16 + ccol][k0 + 16];
                    av[rf] = __builtin_shufflevector(alo, ahi, 0, 1, 2, 3, 4, 5, 6, 7);
                }
                #pragma unroll
                for (int rf = 0; rf < 4; ++rf)
                    #pragma unroll
                    for (int g = 0; g < 4; ++g)
                        acc[rf][g] = __builtin_amdgcn_mfma_f32_16x16x32_bf16(
                            av[rf], bB[g], acc[rf][g], 0, 0, 0);
            }
        }
        __syncthreads();   // all A reads done before h overwrite

        // ---- cell epilogue: one unit per thread, 16 rows (rcp-based) ----
        float sp[16];
        #pragma unroll
        for (int rf = 0; rf < 4; ++rf) {
            #pragma unroll
            for (int reg = 0; reg < 4; ++reg) {
                float gI = acc[rf][0][reg] + bI;
                float gF = acc[rf][1][reg] + bF;
                float gG = acc[rf][2][reg] + bG;
                float gO = acc[rf][3][reg] + bO;
                float ig = sigm(gI);
                float fg = sigm(gF);
                float gt = fast_tanh(gG);
                float og = sigm(gO);
                int ci = rf * 4 + reg;
                float cn = fg * cst[ci] + ig * gt;
                cst[ci] = cn;
                float hh = og * fast_tanh(cn);
                AS[rf * 16 + lrow + reg][128 + m] = f2bf(hh);
                sp[ci] = hh * awt;
            }
        }
        #pragma unroll
        for (int o = 1; o < 16; o <<= 1) {
            #pragma unroll
            for (int i = 0; i < 16; ++i) sp[i] += __shfl_xor(sp[i], o);
        }
        if (ccol == 0) {
            #pragma unroll
            for (int i = 0; i < 16; ++i)
                atomicAdd(&scoreS[(i >> 2) * 16 + lrow + (i & 3)], sp[i]);
        }
        __syncthreads();
        if (t < 64 && n0 + t < N)
            scoreP[(size_t)(dir * 3 + l) * N + n0 + t] = scoreS[t];
    }
}

// ---------------- fused MFMA tail: JK sum + node MLP + P/Q, 64 nodes -------
// 8 waves; wave f owns col-frags {f (nW1), 8+f (P), 16+f (Q)}. A-tile = JK
// weighted xsb sum in bf16 LDS. Node logits via shfl16 + LDS atomics.
__global__ __launch_bounds__(512) void k_tailm(
    const unsigned short* __restrict__ xsb, const float* __restrict__ scoreP,
    const unsigned short* __restrict__ Wt,   // [4][24][512] bf16
    const float* __restrict__ nb1, const float* __restrict__ nW2,
    const float* __restrict__ nb2, const float* __restrict__ eb1,
    unsigned short* __restrict__ P, unsigned short* __restrict__ Q,
    float* __restrict__ out, int N) {
    __shared__ unsigned short AS[64][136];
    __shared__ float al[64][4];
    __shared__ float lgt[64][2];
    const int t = threadIdx.x;
    const int f = t >> 6, lane = t & 63;
    const int n0 = blockIdx.x * 64;
    const int ccol = lane & 15;
    const int klane = lane >> 4;
    const int lrow = klane * 4;
    const int akl = klane * 4;
    const int m = f * 16 + ccol;                 // output col in [0,128)

    if (t < 64) {
        int n = n0 + t;
        float e0 = 0.f, e1 = 0.f, e2 = 0.f;
        if (n < N) {
            float s0 = scoreP[n]                 + scoreP[(size_t)3 * N + n];
            float s1 = scoreP[(size_t)N + n]     + scoreP[(size_t)4 * N + n];
            float s2 = scoreP[(size_t)2 * N + n] + scoreP[(size_t)5 * N + n];
            float mm = fmaxf(s0, fmaxf(s1, s2));
            e0 = __expf(s0 - mm); e1 = __expf(s1 - mm); e2 = __expf(s2 - mm);
            float inv = frcp(e0 + e1 + e2);
            e0 *= inv; e1 *= inv; e2 *= inv;
        }
        al[t][0] = e0; al[t][1] = e1; al[t][2] = e2;
        lgt[t][0] = 0.f; lgt[t][1] = 0.f;
    }
    __syncthreads();

    // stage A = sum_l al[l] * xsb_l (bf16)
    const size_t L1o = (size_t)N * 128, L2o = 2 * L1o;
    for (int i = t; i < 1024; i += 512) {
        int r = i >> 4, kq = (i & 15) * 8;
        u16x8 o8 = (u16x8)(0);
        if (n0 + r < N) {
            size_t base = (size_t)(n0 + r) * 128 + kq;
            u16x8 a = *(const u16x8*)(xsb + base);
            u16x8 b = *(const u16x8*)(xsb + L1o + base);
            u16x8 c = *(const u16x8*)(xsb + L2o + base);
            float w0 = al[r][0], w1 = al[r][1], w2 = al[r][2];
            #pragma unroll
            for (int j = 0; j < 8; ++j)
                o8[j] = f2bf(w0 * bf2f(a[j]) + w1 * bf2f(b[j]) + w2 * bf2f(c[j]));
        }
        *(u16x8*)&AS[r][kq] = o8;
    }
    __syncthreads();

    // MFMA: 3 frag-groups x 4 row-frags
    f32x4 accN[4], accP[4], accQ[4];
    #pragma unroll
    for (int rf = 0; rf < 4; ++rf) { accN[rf] = (f32x4)(0.f); accP[rf] = (f32x4)(0.f); accQ[rf] = (f32x4)(0.f); }
    #pragma unroll
    for (int kb = 0; kb < 4; ++kb) {
        s16x8 bN = *(const s16x8*)(Wt + ((size_t)kb * 24 + f) * 512 + lane * 8);
        s16x8 bP = *(const s16x8*)(Wt + ((size_t)kb * 24 + 8 + f) * 512 + lane * 8);
        s16x8 bQ = *(const s16x8*)(Wt + ((size_t)kb * 24 + 16 + f) * 512 + lane * 8);
        const int k0 = kb * 32 + akl;
        #pragma unroll
        for (int rf = 0; rf < 4; ++rf) {
            s16x4 alo = *(const s16x4*)&AS[rf * 16 + ccol][k0];
            s16x4 ahi = *(const s16x4*)&AS[rf * 16 + ccol][k0 + 16];
            s16x8 av = __builtin_shufflevector(alo, ahi, 0, 1, 2, 3, 4, 5, 6, 7);
            accN[rf] = __builtin_amdgcn_mfma_f32_16x16x32_bf16(av, bN, accN[rf], 0, 0, 0);
            accP[rf] = __builtin_amdgcn_mfma_f32_16x16x32_bf16(av, bP, accP[rf], 0, 0, 0);
            accQ[rf] = __builtin_amdgcn_mfma_f32_16x16x32_bf16(av, bQ, accQ[rf], 0, 0, 0);
        }
    }
    __syncthreads();   // all A reads done before overwrite

    // node logits: relu(accN + nb1) . nW2
    {
        const float nb1v = nb1[m];
        const float w20 = nW2[2 * m], w21 = nW2[2 * m + 1];
        float s0[16], s1[16];
        #pragma unroll
        for (int rf = 0; rf < 4; ++rf) {
            #pragma unroll
            for (int reg = 0; reg < 4; ++reg) {
                float h = fmaxf(accN[rf][reg] + nb1v, 0.f);
                int ci = rf * 4 + reg;
                s0[ci] = h * w20;
                s1[ci] = h * w21;
            }
        }
        #pragma unroll
        for (int o = 1; o < 16; o <<= 1) {
            #pragma unroll
            for (int i = 0; i < 16; ++i) { s0[i] += __shfl_xor(s0[i], o); s1[i] += __shfl_xor(s1[i], o); }
        }
        if (ccol == 0) {
            #pragma unroll
            for (int i = 0; i < 16; ++i) {
                int row = (i >> 2) * 16 + lrow + (i & 3);
                atomicAdd(&lgt[row][0], s0[i]);
                atomicAdd(&lgt[row][1], s1[i]);
            }
        }
    }
    // P into AS
    {
        const float eb1v = eb1[m];
        #pragma unroll
        for (int rf = 0; rf < 4; ++rf)
            #pragma unroll
            for (int reg = 0; reg < 4; ++reg)
                AS[rf * 16 + lrow + reg][m] = f2bf(accP[rf][reg] + eb1v);
    }
    __syncthreads();
    // finish node softmax + store P
    if (t < 64 && n0 + t < N) {
        float l0 = lgt[t][0] + nb2[0], l1 = lgt[t][1] + nb2[1];
        float mm = fmaxf(l0, l1);
        float e0 = __expf(l0 - mm), e1 = __expf(l1 - mm);
        float inv = frcp(e0 + e1);
        out[2 * (size_t)(n0 + t)]     = e0 * inv;
        out[2 * (size_t)(n0 + t) + 1] = e1 * inv;
    }
    for (int i = t; i < 1024; i += 512) {
        int r = i >> 4, kq = (i & 15) * 8;
        if (n0 + r < N)
            *(u16x8*)(P + (size_t)(n0 + r) * 128 + kq) = *(const u16x8*)&AS[r][kq];
    }
    __syncthreads();
    // Q into AS, then store
    #pragma unroll
    for (int rf = 0; rf < 4; ++rf)
        #pragma unroll
        for (int reg = 0; reg < 4; ++reg)
            AS[rf * 16 + lrow + reg][m] = f2bf(accQ[rf][reg]);
    __syncthreads();
    for (int i = t; i < 1024; i += 512) {
        int r = i >> 4, kq = (i & 15) * 8;
        if (n0 + r < N)
            *(u16x8*)(Q + (size_t)(n0 + r) * 128 + kq) = *(const u16x8*)&AS[r][kq];
    }
}

// ---------------- edge MLP finish: CSR order, P amortized per node ---------
__global__ __launch_bounds__(256) void k_edge3(
    const unsigned short* __restrict__ P, const unsigned short* __restrict__ Q,
    const int* __restrict__ indptr, const int* __restrict__ colS,
    const int* __restrict__ eidx,
    const float* __restrict__ W2, const float* __restrict__ b2,
    float* __restrict__ out, int N) {
    const int wid = threadIdx.x >> 6, lane = threadIdx.x & 63;
    const int n = blockIdx.x * 4 + wid;
    if (n >= N) return;
    const int sl = lane & 15, g = lane >> 4;
    const int s = indptr[n], e = indptr[n + 1];
    float pf[8];
    {
        u16x8 pv = *(const u16x8*)(P + (size_t)n * 128 + sl * 8);
        #pragma unroll
        for (int j = 0; j < 8; ++j) pf[j] = bf2f(pv[j]);
    }
    const float* W2f = W2;
    const float b20 = b2[0], b21 = b2[1];
    for (int p = s + g; p < e; p += 8) {
        int p1 = p + 4;
        bool v1 = p1 < e;
        int col0 = colS[p],  eo0 = eidx[p];
        int col1 = v1 ? colS[p1] : col0;
        int eo1  = v1 ? eidx[p1] : 0;
        u16x8 qv0 = *(const u16x8*)(Q + (size_t)col0 * 128 + sl * 8);
        u16x8 qv1 = *(const u16x8*)(Q + (size_t)col1 * 128 + sl * 8);
        float l00 = 0.f, l01 = 0.f, l10 = 0.f, l11 = 0.f;
        #pragma unroll
        for (int j = 0; j < 8; ++j) {
            int ch = sl * 8 + j;
            float wA = W2f[ch * 2], wB = W2f[ch * 2 + 1];
            float h0 = fmaxf(pf[j] + bf2f(qv0[j]), 0.f);
            float h1 = fmaxf(pf[j] + bf2f(qv1[j]), 0.f);
            l00 += h0 * wA; l01 += h0 * wB;
            l10 += h1 * wA; l11 += h1 * wB;
        }
        #pragma unroll
        for (int o = 1; o < 16; o <<= 1) {
            l00 += __shfl_xor(l00, o); l01 += __shfl_xor(l01, o);
            l10 += __shfl_xor(l10, o); l11 += __shfl_xor(l11, o);
        }
        if (sl == 0) {
            {
                float a = l00 + b20, b = l01 + b21;
                float mm = fmaxf(a, b);
                float e0 = __expf(a - mm), e1 = __expf(b - mm);
                float inv = frcp(e0 + e1);
                out[2 * (size_t)N + 2 * (size_t)eo0]     = e0 * inv;
                out[2 * (size_t)N + 2 * (size_t)eo0 + 1] = e1 * inv;
            }
            if (v1) {
                float a = l10 + b20, b = l11 + b21;
                float mm = fmaxf(a, b);
                float e0 = __expf(a - mm), e1 = __expf(b - mm);
                float inv = frcp(e0 + e1);
                out[2 * (size_t)N + 2 * (size_t)eo1]     = e0 * inv;
                out[2 * (size_t)N + 2 * (size_t)eo1 + 1] = e1 * inv;
            }
        }
    }
}

// ---------------------------------------------------------------------------
extern "C" void kernel_launch(void* const* d_in, const int* in_sizes, int n_in,
                              void* d_out, int out_size, void* d_ws, size_t ws_size,
                              hipStream_t stream) {
    if (n_in < NIN) return;
    const int N = in_sizes[0] / 3;
    const int E = in_sizes[1] / 2;

    char* ws = (char*)d_ws;
    size_t off = 0;
    auto alloc = [&](size_t bytes) -> char* {
        char* p = ws + off;
        off = (off + bytes + 255) & ~(size_t)255;
        return p;
    };
    int* flags = (int*)alloc(32 * sizeof(int));
    int* bsums = (int*)alloc(128 * sizeof(int));
    float* canon[NIN];
    for (int i = 0; i < NIN; ++i) canon[i] = nullptr;
    for (int i = 0; i < NIN; ++i) {
        if (i == 1 || (i >= 10 && i <= 17)) continue;   // LSTM weights read raw
        canon[i] = (float*)alloc((size_t)in_sizes[i] * 4);
    }
    int* row32  = (int*)alloc((size_t)E * 4);
    int* col32  = (int*)alloc((size_t)E * 4);
    int* indptr = (int*)alloc((size_t)(N + 1) * 4);
    int* cnt    = (int*)alloc((size_t)N * 4);
    int* colS   = (int*)alloc((size_t)E * 4);
    int* eidx   = (int*)alloc((size_t)E * 4);
    float* hs   = (float*)alloc((size_t)N * 4);
    float* hd   = (float*)alloc((size_t)N * 4);
    // hJK buffer: bf16 hlin during GAT phase; bf16 P/Q after the LSTM
    float* hJK  = (float*)alloc((size_t)N * 128 * 4);
    unsigned short* hlin = (unsigned short*)hJK;
    unsigned short* xsb = (unsigned short*)alloc((size_t)3 * N * 128 * 2);  // bf16 xs
    unsigned short* Bpack = (unsigned short*)alloc((size_t)2 * 10 * 48 * 512 * 2);
    unsigned short* Wg = (unsigned short*)alloc((size_t)2 * 4 * 8 * 512 * 2);
    unsigned short* Wt = (unsigned short*)alloc((size_t)4 * 24 * 512 * 2);
    float* bsum = (float*)alloc((size_t)2 * 768 * 4);
    float* scoreP = (float*)alloc((size_t)6 * N * 4);
    if (off > ws_size) return;
    unsigned short* P = (unsigned short*)hJK;           // bf16, N*128
    unsigned short* Q = (unsigned short*)hJK + (size_t)N * 128;

    InPtrs ip;
    for (int i = 0; i < NIN; ++i) { ip.p[i] = d_in[i]; ip.n[i] = in_sizes[i]; }

    k_sniff<<<NIN, 256, 0, stream>>>(ip, flags);

    // batched canonicalization of all f32/bf16 inputs
    {
        ConvJobs J;
        int nj = 0, blk = 0;
        for (int i = 0; i < NIN; ++i) {
            if (i == 1 || (i >= 10 && i <= 17)) continue;
            J.src[nj] = d_in[i];
            J.dst[nj] = canon[i];
            J.n[nj] = in_sizes[i];
            J.ai[nj] = i;
            J.blk0[nj] = blk;
            blk += (in_sizes[i] + 255) / 256;
            ++nj;
        }
        J.blk0[nj] = blk;
        J.njobs = nj;
        k_convall<<<blk, 256, 0, stream>>>(J, flags);
    }
    // edge decode + histogram (cnt pre-zeroed by memset)
    hipMemsetAsync(cnt, 0, (size_t)N * 4, stream);
    k_conve<<<(E + 255) / 256, 256, 0, stream>>>(d_in[1], row32, col32, cnt, E, flags);
    k_wpack<<<(2 * 10 * 48 * 512 + 255) / 256, 256, 0, stream>>>(
        d_in[10], d_in[11], d_in[14], d_in[15],
        d_in[12], d_in[13], d_in[16], d_in[17], flags, Bpack, bsum);
    k_wpackg<<<(2 * 4 * 8 * 512 + 255) / 256, 256, 0, stream>>>(canon[6], Wg);
    k_wpackt<<<(4 * 24 * 512 + 255) / 256, 256, 0, stream>>>(canon[20], canon[24], Wt);

    // CSR scan (scan3 also resets cnt for k_fill)
    const int nb1k = (N + 1023) / 1024;
    k_scan1<<<nb1k, 1024, 0, stream>>>(cnt, indptr, bsums, N);
    k_scan2<<<1, 64, 0, stream>>>(bsums, nb1k);
    k_scan3<<<(N + 255) / 256, 256, 0, stream>>>(bsums, indptr, cnt, N, nb1k);
    k_fill<<<(E + 255) / 256, 256, 0, stream>>>(row32, col32, indptr, cnt, colS, eidx, E);

    // GAT layer 0 (in=3)
    k_lin0<<<(N + 3) / 4, 256, 0, stream>>>(canon[0], canon[2], canon[4], canon[5],
                                            hlin, hs, hd, N);
    k_aggr<<<(N + 3) / 4, 256, 0, stream>>>(hlin, hs, hd, indptr, colS, canon[3], xsb, N);
    // GAT layers 1..2 (MFMA linear, bf16 in/out)
    for (int l = 1; l < 3; ++l) {
        const unsigned short* Wgl = Wg + (size_t)(l - 1) * 4 * 8 * 512;
        const float* bb = canon[7] + (size_t)(l - 1) * 128;
        const float* as = canon[8] + (size_t)(l - 1) * 128;
        const float* ad = canon[9] + (size_t)(l - 1) * 128;
        k_linm<<<(N + 63) / 64, 512, 0, stream>>>(xsb + (size_t)(l - 1) * N * 128, Wgl,
                                                  as, ad, hlin, hs, hd, N);
        k_aggr<<<(N + 3) / 4, 256, 0, stream>>>(hlin, hs, hd, indptr, colS, bb,
                                                xsb + (size_t)l * N * 128, N);
    }

    // fused bidirectional LSTM (MFMA, 64-row 12-wave) -> scores
    dim3 lgrid((N + 63) / 64, 2);
    k_lstm_mfma<<<lgrid, 768, 0, stream>>>(xsb, Bpack, bsum, canon[18], scoreP, N);

    float* out = (float*)d_out;
    // fused MFMA tail: JK finish + node MLP + P/Q
    k_tailm<<<(N + 63) / 64, 512, 0, stream>>>(xsb, scoreP, Wt,
                                               canon[21], canon[22], canon[23], canon[25],
                                               P, Q, out, N);
    // edge MLP in CSR order (P amortized per node; scatter via eidx)
    k_edge3<<<(N + 3) / 4, 256, 0, stream>>>(P, Q, indptr, colS, eidx,
                                             canon[26], canon[27], out, N);
}

// Round 18
// 584.684 us; speedup vs baseline: 1.2258x; 1.0175x over previous
//
#include <hip/hip_runtime.h>
#include <cstdint>
#include <cstddef>

// ---------------------------------------------------------------------------
// ParityGameGATNetwork: 3x GATConv -> JK bidirectional LSTM -> node/edge MLPs
// Round 18: (a) LSTM schedule: 2 barriers/step (was 3); next-layer x loads
// issued into registers before the cell epilogue (latency hidden under the
// ~600cy VALU/trans chain), written to LDS after; (b) mega-prep kernel fuses
// convall+conve+wpack+wpackg+wpackt (pack kernels read raw inputs via flags),
// 20 -> 16 launches. Everything else identical to round 17.
// ---------------------------------------------------------------------------

#define NIN 28
#define MAXJOBS 20

struct InPtrs { const void* p[NIN]; int n[NIN]; };

struct PrepCfg {
    const void* src[MAXJOBS];
    float* dst[MAXJOBS];
    int n[MAXJOBS];
    int ai[MAXJOBS];
    int blk0[MAXJOBS + 1];
    int njobs;
    int cvB, wB, gB, tB;                 // block range starts for fixed jobs
    // conve
    const void* esrc; int* row; int* col; int* cnt; int E;
    // wpack (lstm)
    const void *Wihf, *Whhf, *Wihb, *Whhb, *bihf, *bhhf, *bihb, *bhhb;
    unsigned short* Bpack; float* bsum;
    // wpackg (gat W, raw input 6)
    const void* Wgsrc; unsigned short* Wg;
    // wpackt (nW1 input 20, eW1 input 24, raw)
    const void* nW1src; const void* eW1src; unsigned short* Wt;
};

typedef short s16x4 __attribute__((ext_vector_type(4)));
typedef short s16x8 __attribute__((ext_vector_type(8)));
typedef float f32x4 __attribute__((ext_vector_type(4)));
typedef unsigned short u16x8 __attribute__((ext_vector_type(8)));

__device__ __forceinline__ float bf2f(unsigned short v) {
    unsigned int u = ((unsigned int)v) << 16;
    return __uint_as_float(u);
}

__device__ __forceinline__ unsigned short f2bf(float x) {
    unsigned int u = __float_as_uint(x);
    unsigned int r = u + 0x7fffu + ((u >> 16) & 1u);
    return (unsigned short)(r >> 16);
}

__device__ __forceinline__ float rdx(const void* p, size_t i, int isf32) {
    return isf32 ? ((const float*)p)[i] : bf2f(((const unsigned short*)p)[i]);
}

__device__ __forceinline__ float frcp(float x) {        // raw v_rcp_f32 (~1ulp)
    return __builtin_amdgcn_rcpf(x);
}

__device__ __forceinline__ float sigm(float x) {
    return frcp(1.f + __expf(-x));
}

__device__ __forceinline__ float fast_tanh(float x) {
    return 1.f - 2.f * frcp(__expf(2.f * x) + 1.f);
}

// ---------------- dtype sniffing -------------------------------------------
__global__ void k_sniff(InPtrs in, int* flags) {
    int ai = blockIdx.x;
    if (ai >= NIN) return;
    __shared__ int cnt;
    if (threadIdx.x == 0) cnt = 0;
    __syncthreads();
    if (ai == 1) {
        const int* w = (const int*)in.p[1];
        int nw = in.n[1] < 512 ? in.n[1] : 512;
        int local = 0;
        for (int i = threadIdx.x; i < nw; i += blockDim.x)
            if ((i & 1) && w[i] != 0) local++;
        atomicAdd(&cnt, local);
        __syncthreads();
        if (threadIdx.x == 0) flags[1] = (cnt < 4) ? 1 : 0;
        return;
    }
    const unsigned short* u = (const unsigned short*)in.p[ai];
    int ns = in.n[ai] < 256 ? in.n[ai] : 256;
    int local = 0;
    for (int i = threadIdx.x; i < ns; i += blockDim.x) {
        if (i & 1) continue;
        unsigned short v = u[i];
        int e = (v >> 7) & 0xff;
        if ((v & 0x7fff) != 0 && (e < 100 || e > 154)) local++;
    }
    atomicAdd(&cnt, local);
    __syncthreads();
    if (threadIdx.x == 0) flags[ai] = (cnt * 4 >= ns) ? 1 : 0;
}

// ---------------- mega prep: conv + edge decode/hist + all weight packs ----
__global__ void k_prep(PrepCfg C, const int* __restrict__ flags) {
    const int b = blockIdx.x;
    const int tid = threadIdx.x;
    if (b < C.cvB) {                     // canonicalization jobs
        int j = 0;
        while (j + 1 < C.njobs && b >= C.blk0[j + 1]) ++j;
        int i = (b - C.blk0[j]) * 256 + tid;
        if (i < C.n[j]) C.dst[j][i] = rdx(C.src[j], i, flags[C.ai[j]]);
        return;
    }
    if (b < C.wB) {                      // edge decode + histogram
        int i = (b - C.cvB) * 256 + tid;
        if (i >= C.E) return;
        int r, c;
        if (flags[1]) {
            const long long* s = (const long long*)C.esrc;
            r = (int)s[i];
            c = (int)s[(size_t)C.E + i];
        } else {
            const int* s = (const int*)C.esrc;
            r = s[i];
            c = s[(size_t)C.E + i];
        }
        C.row[i] = r;
        C.col[i] = c;
        atomicAdd(&C.cnt[r], 1);
        return;
    }
    if (b < C.gB) {                      // LSTM weight pack
        int idx = (b - C.wB) * 256 + tid;
        const int TOT = 2 * 10 * 48 * 512;
        if (idx < TOT) {
            int dir = idx / (10 * 48 * 512);
            int r   = idx % (10 * 48 * 512);
            int kb  = r / (48 * 512);
            int r2  = r % (48 * 512);
            int f   = r2 / 512;
            int q   = r2 % 512;
            int lane = q >> 3, j = q & 7;
            int k   = kb * 32 + ((j >> 2) * 16) + ((lane >> 4) * 4) + (j & 3);
            int col = f * 16 + (lane & 15);
            float v;
            if (k < 128)
                v = dir ? rdx(C.Wihb, (size_t)col * 128 + k, flags[14])
                        : rdx(C.Wihf, (size_t)col * 128 + k, flags[10]);
            else
                v = dir ? rdx(C.Whhb, (size_t)col * 192 + (k - 128), flags[15])
                        : rdx(C.Whhf, (size_t)col * 192 + (k - 128), flags[11]);
            C.Bpack[idx] = f2bf(v);
        }
        if (idx < 2 * 768) {
            int d = idx / 768, j = idx % 768;
            C.bsum[idx] = d ? rdx(C.bihb, j, flags[16]) + rdx(C.bhhb, j, flags[17])
                            : rdx(C.bihf, j, flags[12]) + rdx(C.bhhf, j, flags[13]);
        }
        return;
    }
    if (b < C.tB) {                      // GAT W pack (layers 1-2, raw input 6)
        int idx = (b - C.gB) * 256 + tid;
        if (idx >= 2 * 4 * 8 * 512) return;
        int layer = idx / 16384;
        int r  = idx % 16384;
        int kb = r / 4096;
        int r2 = r % 4096;
        int f  = r2 / 512;
        int q  = r2 % 512;
        int lane = q >> 3, j = q & 7;
        int k   = kb * 32 + ((j >> 2) * 16) + ((lane >> 4) * 4) + (j & 3);
        int col = f * 16 + (lane & 15);
        C.Wg[idx] = f2bf(rdx(C.Wgsrc, (size_t)layer * 16384 + (size_t)k * 128 + col,
                             flags[6]));
        return;
    }
    {                                    // tail W pack (raw inputs 20/24)
        int idx = (b - C.tB) * 256 + tid;
        if (idx >= 4 * 24 * 512) return;
        int kb = idx / (24 * 512);
        int r  = idx % (24 * 512);
        int fr = r / 512;
        int q  = r % 512;
        int lane = q >> 3, j = q & 7;
        int k   = kb * 32 + ((j >> 2) * 16) + ((lane >> 4) * 4) + (j & 3);
        int grp = fr >> 3;
        int col = (fr & 7) * 16 + (lane & 15);
        float v;
        if (grp == 0)      v = rdx(C.nW1src, (size_t)k * 128 + col, flags[20]);
        else if (grp == 1) v = rdx(C.eW1src, (size_t)k * 128 + col, flags[24]);
        else               v = rdx(C.eW1src, (size_t)(128 + k) * 128 + col, flags[24]);
        C.Wt[idx] = f2bf(v);
    }
}

// ---------------- CSR build ------------------------------------------------
__global__ void k_scan1(const int* __restrict__ deg, int* __restrict__ indptr,
                        int* __restrict__ bsums, int N) {
    __shared__ int buf[1024];
    const int t = threadIdx.x;
    const int base = blockIdx.x * 1024;
    int v = (base + t < N) ? deg[base + t] : 0;
    buf[t] = v;
    __syncthreads();
    for (int ofs = 1; ofs < 1024; ofs <<= 1) {
        int add = (t >= ofs) ? buf[t - ofs] : 0;
        __syncthreads();
        buf[t] += add;
        __syncthreads();
    }
    if (base + t < N) indptr[base + t] = buf[t] - v;
    if (t == 1023) bsums[blockIdx.x] = buf[1023];
}

__global__ void k_scan2(int* bsums, int nb) {
    if (threadIdx.x == 0 && blockIdx.x == 0) {
        int acc = 0;
        for (int j = 0; j < nb; ++j) { int v = bsums[j]; bsums[j] = acc; acc += v; }
        bsums[nb] = acc;
    }
}

__global__ void k_scan3(const int* __restrict__ bsums, int* __restrict__ indptr,
                        int* __restrict__ cnt, int N, int nb) {
    int i = blockIdx.x * blockDim.x + threadIdx.x;
    if (i < N) {
        indptr[i] += bsums[i >> 10];
        cnt[i] = 0;
    }
    if (i == 0) indptr[N] = bsums[nb];
}

__global__ void k_fill(const int* __restrict__ row, const int* __restrict__ col,
                       const int* __restrict__ indptr, int* __restrict__ cur,
                       int* __restrict__ colS, int* __restrict__ eidx, int E) {
    int i = blockIdx.x * blockDim.x + threadIdx.x;
    if (i >= E) return;
    int r = row[i];
    int p = indptr[r] + atomicAdd(&cur[r], 1);
    colS[p] = col[i];
    eidx[p] = i;
}

// ---------------- GAT linear layer 0 (in=3), hlin out bf16 -----------------
__global__ __launch_bounds__(256) void k_lin0(
    const float* __restrict__ x, const float* __restrict__ W0,
    const float* __restrict__ asrc, const float* __restrict__ adst,
    unsigned short* __restrict__ hlin, float* __restrict__ hs, float* __restrict__ hd,
    int N) {
    const int wid = threadIdx.x >> 6, lane = threadIdx.x & 63;
    const int n = blockIdx.x * 4 + wid;
    if (n >= N) return;
    float x0 = x[(size_t)n * 3], x1 = x[(size_t)n * 3 + 1], x2 = x[(size_t)n * 3 + 2];
    const int c0 = lane, c1 = lane + 64;
    float h0 = x0 * W0[c0] + x1 * W0[128 + c0] + x2 * W0[256 + c0];
    float h1 = x0 * W0[c1] + x1 * W0[128 + c1] + x2 * W0[256 + c1];
    hlin[(size_t)n * 128 + c0] = f2bf(h0);
    hlin[(size_t)n * 128 + c1] = f2bf(h1);
    float sp = h0 * asrc[c0] + h1 * asrc[c1];
    float dp = h0 * adst[c0] + h1 * adst[c1];
    for (int o = 32; o; o >>= 1) { sp += __shfl_down(sp, o); dp += __shfl_down(dp, o); }
    if (lane == 0) { hs[n] = sp; hd[n] = dp; }
}

// ---------------- GAT linear (MFMA): 64 nodes, 8 waves ---------------------
__global__ __launch_bounds__(512) void k_linm(
    const unsigned short* __restrict__ xin,   // [N][128] bf16
    const unsigned short* __restrict__ Wg,    // [4][8][512] bf16 (this layer)
    const float* __restrict__ asrc, const float* __restrict__ adst,
    unsigned short* __restrict__ hlin, float* __restrict__ hs, float* __restrict__ hd,
    int N) {
    __shared__ unsigned short AS[64][136];
    __shared__ float hsS[64], hdS[64];
    const int t = threadIdx.x;
    const int f = t >> 6, lane = t & 63;
    const int n0 = blockIdx.x * 64;
    const int ccol = lane & 15;
    const int klane = lane >> 4;
    const int lrow = klane * 4;
    const int akl = klane * 4;
    const int m = f * 16 + ccol;

    const float asv = asrc[m], adv = adst[m];

    for (int i = t; i < 1024; i += 512) {
        int r = i >> 4, kq = (i & 15) * 8;
        u16x8 v = (u16x8)(0);
        if (n0 + r < N) v = *(const u16x8*)(xin + (size_t)(n0 + r) * 128 + kq);
        *(u16x8*)&AS[r][kq] = v;
    }
    if (t < 64) { hsS[t] = 0.f; hdS[t] = 0.f; }
    __syncthreads();

    f32x4 acc[4];
    #pragma unroll
    for (int rf = 0; rf < 4; ++rf) acc[rf] = (f32x4)(0.f);
    #pragma unroll
    for (int kb = 0; kb < 4; ++kb) {
        s16x8 b = *(const s16x8*)(Wg + ((size_t)kb * 8 + f) * 512 + lane * 8);
        const int k0 = kb * 32 + akl;
        #pragma unroll
        for (int rf = 0; rf < 4; ++rf) {
            s16x4 alo = *(const s16x4*)&AS[rf * 16 + ccol][k0];
            s16x4 ahi = *(const s16x4*)&AS[rf * 16 + ccol][k0 + 16];
            s16x8 av = __builtin_shufflevector(alo, ahi, 0, 1, 2, 3, 4, 5, 6, 7);
            acc[rf] = __builtin_amdgcn_mfma_f32_16x16x32_bf16(av, b, acc[rf], 0, 0, 0);
        }
    }
    __syncthreads();   // all A reads done before h overwrite

    float sp[16], dp[16];
    #pragma unroll
    for (int rf = 0; rf < 4; ++rf) {
        #pragma unroll
        for (int reg = 0; reg < 4; ++reg) {
            float h = acc[rf][reg];
            int ci = rf * 4 + reg;
            AS[rf * 16 + lrow + reg][m] = f2bf(h);
            sp[ci] = h * asv;
            dp[ci] = h * adv;
        }
    }
    #pragma unroll
    for (int o = 1; o < 16; o <<= 1) {
        #pragma unroll
        for (int i = 0; i < 16; ++i) { sp[i] += __shfl_xor(sp[i], o); dp[i] += __shfl_xor(dp[i], o); }
    }
    if (ccol == 0) {
        #pragma unroll
        for (int i = 0; i < 16; ++i) {
            int row = (i >> 2) * 16 + lrow + (i & 3);
            atomicAdd(&hsS[row], sp[i]);
            atomicAdd(&hdS[row], dp[i]);
        }
    }
    __syncthreads();

    for (int i = t; i < 1024; i += 512) {
        int r = i >> 4, kq = (i & 15) * 8;
        if (n0 + r < N)
            *(u16x8*)(hlin + (size_t)(n0 + r) * 128 + kq) = *(const u16x8*)&AS[r][kq];
    }
    if (t < 64 && n0 + t < N) { hs[n0 + t] = hsS[t]; hd[n0 + t] = hdS[t]; }
}

// ---------------- GAT aggregation: online segment softmax, 8-way unrolled --
__global__ __launch_bounds__(256) void k_aggr(
    const unsigned short* __restrict__ hlin, const float* __restrict__ hs,
    const float* __restrict__ hd,
    const int* __restrict__ indptr, const int* __restrict__ colS,
    const float* __restrict__ b, unsigned short* __restrict__ xout, int N) {
    const int wid = threadIdx.x >> 6, lane = threadIdx.x & 63;
    const int n = blockIdx.x * 4 + wid;
    if (n >= N) return;
    const int s = indptr[n], epos = indptr[n + 1];
    const float hdv = hd[n];
    const int c0 = lane, c1 = lane + 64;
    float m = -1e30f, d = 0.f, a0 = 0.f, a1 = 0.f;
    int idx = s;
    for (; idx + 8 <= epos; idx += 8) {
        int cl[8];
        #pragma unroll
        for (int j = 0; j < 8; ++j) cl[j] = colS[idx + j];
        float e[8];
        #pragma unroll
        for (int j = 0; j < 8; ++j) {
            float ev = hs[cl[j]] + hdv;
            e[j] = (ev > 0.f) ? ev : 0.2f * ev;
        }
        float v0[8], v1[8];
        #pragma unroll
        for (int j = 0; j < 8; ++j) {
            const unsigned short* hp = hlin + (size_t)cl[j] * 128;
            v0[j] = bf2f(hp[c0]);
            v1[j] = bf2f(hp[c1]);
        }
        float m8 = e[0];
        #pragma unroll
        for (int j = 1; j < 8; ++j) m8 = fmaxf(m8, e[j]);
        if (m8 > m) {
            float sc = __expf(m - m8);
            a0 *= sc; a1 *= sc; d *= sc; m = m8;
        }
        #pragma unroll
        for (int j = 0; j < 8; ++j) {
            float w = __expf(e[j] - m);
            a0 += w * v0[j];
            a1 += w * v1[j];
            d  += w;
        }
    }
    for (; idx < epos; ++idx) {
        int col = colS[idx];
        float e = hs[col] + hdv;
        e = (e > 0.f) ? e : 0.2f * e;
        const unsigned short* hr = hlin + (size_t)col * 128;
        float v0 = bf2f(hr[c0]), v1 = bf2f(hr[c1]);
        if (e > m) {
            float sc = __expf(m - e);
            a0 = a0 * sc + v0;
            a1 = a1 * sc + v1;
            d  = d * sc + 1.f;
            m  = e;
        } else {
            float w = __expf(e - m);
            a0 += w * v0;
            a1 += w * v1;
            d  += w;
        }
    }
    float inv = frcp(d + 1e-16f);
    float r0 = a0 * inv + b[c0];
    float r1 = a1 * inv + b[c1];
    xout[(size_t)n * 128 + c0] = f2bf(fmaxf(r0, 0.f));
    xout[(size_t)n * 128 + c1] = f2bf(fmaxf(r1, 0.f));
}

// ---------------- fused bidirectional LSTM: 64 rows, 12 waves --------------
// Round-18 schedule: 2 barriers/step; next-x loads issued before the cell
// epilogue (latency hidden), written to LDS after, covered by one barrier.
__global__ __launch_bounds__(768, 3) void k_lstm_mfma(
    const unsigned short* __restrict__ xsb,  // [3][N][128] bf16
    const unsigned short* __restrict__ Bpack,// [2][10][48][512] bf16
    const float* __restrict__ bsum,          // [2][768]
    const float* __restrict__ attW,          // [384]
    float* __restrict__ scoreP,              // [2][3][N]
    int N) {
    __shared__ unsigned short AS[64][332];   // x:[0,128)  h:[128,320)
    __shared__ float scoreS[64];
    const int t = threadIdx.x;
    const int bf = t >> 6, lane = t & 63;
    const int dir = blockIdx.y;
    const int n0 = blockIdx.x * 64;
    const int ccol = lane & 15;
    const int klane = lane >> 4;
    const int lrow = klane * 4;
    const int akl = klane * 4;
    const int m = bf * 16 + ccol;            // this thread's hidden unit

    const float bI = bsum[dir * 768 + m];
    const float bF = bsum[dir * 768 + 192 + m];
    const float bG = bsum[dir * 768 + 384 + m];
    const float bO = bsum[dir * 768 + 576 + m];
    const float awt = attW[dir * 192 + m];
    float cst[16];
    #pragma unroll
    for (int i = 0; i < 16; ++i) cst[i] = 0.f;

    const unsigned short* Bd = Bpack + (size_t)dir * 10 * 48 * 512;

    // ---- prologue: stage x for s=0 ----
    {
        const int l0 = dir ? 2 : 0;
        const unsigned short* xsrc = xsb + ((size_t)l0 * N + n0) * 128;
        for (int i = t; i < 1024; i += 768) {
            int r = i >> 4, kq = (i & 15) * 8;
            u16x8 v = (u16x8)(0);
            if (n0 + r < N) v = *(const u16x8*)(xsrc + (size_t)r * 128 + kq);
            *(u16x8*)&AS[r][kq] = v;
        }
    }
    if (t < 64) scoreS[t] = 0.f;
    __syncthreads();

    for (int s = 0; s < 3; ++s) {
        const int l = dir ? (2 - s) : s;

        // ---- MFMA GEMM over K, B ping-pong prefetch ----
        const int KB = s ? 10 : 4;               // both even
        f32x4 acc[4][4];
        #pragma unroll
        for (int rf = 0; rf < 4; ++rf)
            #pragma unroll
            for (int g = 0; g < 4; ++g) acc[rf][g] = (f32x4)(0.f);
        s16x8 bA[4], bB[4];
        {
            const unsigned short* bb = Bd + (size_t)bf * 512 + lane * 8;   // kb=0
            #pragma unroll
            for (int g = 0; g < 4; ++g) bA[g] = *(const s16x8*)(bb + (size_t)g * 6144);
        }
        for (int kb = 0; kb < KB; kb += 2) {
            {   // prefetch kb+1
                const unsigned short* bb = Bd + ((size_t)(kb + 1) * 48 + bf) * 512 + lane * 8;
                #pragma unroll
                for (int g = 0; g < 4; ++g) bB[g] = *(const s16x8*)(bb + (size_t)g * 6144);
            }
            {   // compute kb on bA
                const int k0 = kb * 32 + akl;
                s16x8 av[4];
                #pragma unroll
                for (int rf = 0; rf < 4; ++rf) {
                    s16x4 alo = *(const s16x4*)&AS[rf * 16 + ccol][k0];
                    s16x4 ahi = *(const s16x4*)&AS[rf * 16 + ccol][k0 + 16];
                    av[rf] = __builtin_shufflevector(alo, ahi, 0, 1, 2, 3, 4, 5, 6, 7);
                }
                #pragma unroll
                for (int rf = 0; rf < 4; ++rf)
                    #pragma unroll
                    for (int g = 0; g < 4; ++g)
                        acc[rf][g] = __builtin_amdgcn_mfma_f32_16x16x32_bf16(
                            av[rf], bA[g], acc[rf][g], 0, 0, 0);
            }
            if (kb + 2 < KB) {   // prefetch kb+2
                const unsigned short* bb = Bd + ((size_t)(kb + 2) * 48 + bf) * 512 + lane * 8;
                #pragma unroll
                for (int g = 0; g < 4; ++g) bA[g] = *(const s16x8*)(bb + (size_t)g * 6144);
            }
            {   // compute kb+1 on bB
                const int k0 = (kb + 1) * 32 + akl;
                s16x8 av[4];
                #pragma unroll
                for (int rf = 0; rf < 4; ++rf) {
                    s16x4 alo = *(const s16x4*)&AS[rf * 16 + ccol][k0];
                    s16x4 ahi = *(const s16x4*)&AS[rf * 16 + ccol][k0 + 16];
                    av[rf] = __builtin_shufflevector(alo, ahi, 0, 1, 2, 3, 4, 5, 6, 7);
                }
                #pragma unroll
                for (int rf = 0; rf < 4; ++rf)
                    #pragma unroll
                    for (int g = 0; g < 4; ++g)
                        acc[rf][g] = __builtin_amdgcn_mfma_f32_16x16x32_bf16(
                            av[rf], bB[g], acc[rf][g], 0, 0, 0);
            }
        }
        __syncthreads();   // SYNC2: all A reads done (x region now dead)

        // ---- issue next-layer x loads into registers (hidden under epilogue)
        u16x8 nx0 = (u16x8)(0), nx1 = (u16x8)(0);
        if (s < 2) {
            const int ln = dir ? (1 - s) : (s + 1);
            const unsigned short* xsrc = xsb + ((size_t)ln * N + n0) * 128;
            {
                int r = t >> 4, kq = (t & 15) * 8;
                if (n0 + r < N) nx0 = *(const u16x8*)(xsrc + (size_t)r * 128 + kq);
            }
            if (t < 256) {
                int i = t + 768, r = i >> 4, kq = (i & 15) * 8;
                if (n0 + r < N) nx1 = *(const u16x8*)(xsrc + (size_t)r * 128 + kq);
            }
        }

        // ---- cell epilogue: one unit per thread, 16 rows (rcp-based) ----
        float sp[16];
        #pragma unroll
        for (int rf = 0; rf < 4; ++rf) {
            #pragma unroll
            for (int reg = 0; reg < 4; ++reg) {
                float gI = acc[rf][0][reg] + bI;
                float gF = acc[rf][1][reg] + bF;
                float gG = acc[rf][2][reg] + bG;
                float gO = acc[rf][3][reg] + bO;
                float ig = sigm(gI);
                float fg = sigm(gF);
                float gt = fast_tanh(gG);
                float og = sigm(gO);
                int ci = rf * 4 + reg;
                float cn = fg * cst[ci] + ig * gt;
                cst[ci] = cn;
                float hh = og * fast_tanh(cn);
                AS[rf * 16 + lrow + reg][128 + m] = f2bf(hh);
                sp[ci] = hh * awt;
            }
        }
        #pragma unroll
        for (int o = 1; o < 16; o <<= 1) {
            #pragma unroll
            for (int i = 0; i < 16; ++i) sp[i] += __shfl_xor(sp[i], o);
        }
        if (ccol == 0) {
            #pragma unroll
            for (int i = 0; i < 16; ++i)
                atomicAdd(&scoreS[(i >> 2) * 16 + lrow + (i & 3)], sp[i]);
        }

        // ---- write staged next-x into LDS x region ----
        if (s < 2) {
            {
                int r = t >> 4, kq = (t & 15) * 8;
                *(u16x8*)&AS[r][kq] = nx0;
            }
            if (t < 256) {
                int i = t + 768, r = i >> 4, kq = (i & 15) * 8;
                *(u16x8*)&AS[r][kq] = nx1;
            }
        }
        __syncthreads();   // SYNC3: h writes + score atomics + x staging

        if (t < 64) {
            if (n0 + t < N)
                scoreP[(size_t)(dir * 3 + l) * N + n0 + t] = scoreS[t];
            scoreS[t] = 0.f;   // reset; visible before next epilogue (SYNC2)
        }
    }
}

// ---------------- fused MFMA tail: JK sum + node MLP + P/Q, 64 nodes -------
__global__ __launch_bounds__(512) void k_tailm(
    const unsigned short* __restrict__ xsb, const float* __restrict__ scoreP,
    const unsigned short* __restrict__ Wt,   // [4][24][512] bf16
    const float* __restrict__ nb1, const float* __restrict__ nW2,
    const float* __restrict__ nb2, const float* __restrict__ eb1,
    unsigned short* __restrict__ P, unsigned short* __restrict__ Q,
    float* __restrict__ out, int N) {
    __shared__ unsigned short AS[64][136];
    __shared__ float al[64][4];
    __shared__ float lgt[64][2];
    const int t = threadIdx.x;
    const int f = t >> 6, lane = t & 63;
    const int n0 = blockIdx.x * 64;
    const int ccol = lane & 15;
    const int klane = lane >> 4;
    const int lrow = klane * 4;
    const int akl = klane * 4;
    const int m = f * 16 + ccol;                 // output col in [0,128)

    if (t < 64) {
        int n = n0 + t;
        float e0 = 0.f, e1 = 0.f, e2 = 0.f;
        if (n < N) {
            float s0 = scoreP[n]                 + scoreP[(size_t)3 * N + n];
            float s1 = scoreP[(size_t)N + n]     + scoreP[(size_t)4 * N + n];
            float s2 = scoreP[(size_t)2 * N + n] + scoreP[(size_t)5 * N + n];
            float mm = fmaxf(s0, fmaxf(s1, s2));
            e0 = __expf(s0 - mm); e1 = __expf(s1 - mm); e2 = __expf(s2 - mm);
            float inv = frcp(e0 + e1 + e2);
            e0 *= inv; e1 *= inv; e2 *= inv;
        }
        al[t][0] = e0; al[t][1] = e1; al[t][2] = e2;
        lgt[t][0] = 0.f; lgt[t][1] = 0.f;
    }
    __syncthreads();

    const size_t L1o = (size_t)N * 128, L2o = 2 * L1o;
    for (int i = t; i < 1024; i += 512) {
        int r = i >> 4, kq = (i & 15) * 8;
        u16x8 o8 = (u16x8)(0);
        if (n0 + r < N) {
            size_t base = (size_t)(n0 + r) * 128 + kq;
            u16x8 a = *(const u16x8*)(xsb + base);
            u16x8 b = *(const u16x8*)(xsb + L1o + base);
            u16x8 c = *(const u16x8*)(xsb + L2o + base);
            float w0 = al[r][0], w1 = al[r][1], w2 = al[r][2];
            #pragma unroll
            for (int j = 0; j < 8; ++j)
                o8[j] = f2bf(w0 * bf2f(a[j]) + w1 * bf2f(b[j]) + w2 * bf2f(c[j]));
        }
        *(u16x8*)&AS[r][kq] = o8;
    }
    __syncthreads();

    f32x4 accN[4], accP[4], accQ[4];
    #pragma unroll
    for (int rf = 0; rf < 4; ++rf) { accN[rf] = (f32x4)(0.f); accP[rf] = (f32x4)(0.f); accQ[rf] = (f32x4)(0.f); }
    #pragma unroll
    for (int kb = 0; kb < 4; ++kb) {
        s16x8 bN = *(const s16x8*)(Wt + ((size_t)kb * 24 + f) * 512 + lane * 8);
        s16x8 bP = *(const s16x8*)(Wt + ((size_t)kb * 24 + 8 + f) * 512 + lane * 8);
        s16x8 bQ = *(const s16x8*)(Wt + ((size_t)kb * 24 + 16 + f) * 512 + lane * 8);
        const int k0 = kb * 32 + akl;
        #pragma unroll
        for (int rf = 0; rf < 4; ++rf) {
            s16x4 alo = *(const s16x4*)&AS[rf * 16 + ccol][k0];
            s16x4 ahi = *(const s16x4*)&AS[rf * 16 + ccol][k0 + 16];
            s16x8 av = __builtin_shufflevector(alo, ahi, 0, 1, 2, 3, 4, 5, 6, 7);
            accN[rf] = __builtin_amdgcn_mfma_f32_16x16x32_bf16(av, bN, accN[rf], 0, 0, 0);
            accP[rf] = __builtin_amdgcn_mfma_f32_16x16x32_bf16(av, bP, accP[rf], 0, 0, 0);
            accQ[rf] = __builtin_amdgcn_mfma_f32_16x16x32_bf16(av, bQ, accQ[rf], 0, 0, 0);
        }
    }
    __syncthreads();   // all A reads done before overwrite

    {
        const float nb1v = nb1[m];
        const float w20 = nW2[2 * m], w21 = nW2[2 * m + 1];
        float s0[16], s1[16];
        #pragma unroll
        for (int rf = 0; rf < 4; ++rf) {
            #pragma unroll
            for (int reg = 0; reg < 4; ++reg) {
                float h = fmaxf(accN[rf][reg] + nb1v, 0.f);
                int ci = rf * 4 + reg;
                s0[ci] = h * w20;
                s1[ci] = h * w21;
            }
        }
        #pragma unroll
        for (int o = 1; o < 16; o <<= 1) {
            #pragma unroll
            for (int i = 0; i < 16; ++i) { s0[i] += __shfl_xor(s0[i], o); s1[i] += __shfl_xor(s1[i], o); }
        }
        if (ccol == 0) {
            #pragma unroll
            for (int i = 0; i < 16; ++i) {
                int row = (i >> 2) * 16 + lrow + (i & 3);
                atomicAdd(&lgt[row][0], s0[i]);
                atomicAdd(&lgt[row][1], s1[i]);
            }
        }
    }
    {
        const float eb1v = eb1[m];
        #pragma unroll
        for (int rf = 0; rf < 4; ++rf)
            #pragma unroll
            for (int reg = 0; reg < 4; ++reg)
                AS[rf * 16 + lrow + reg][m] = f2bf(accP[rf][reg] + eb1v);
    }
    __syncthreads();
    if (t < 64 && n0 + t < N) {
        float l0 = lgt[t][0] + nb2[0], l1 = lgt[t][1] + nb2[1];
        float mm = fmaxf(l0, l1);
        float e0 = __expf(l0 - mm), e1 = __expf(l1 - mm);
        float inv = frcp(e0 + e1);
        out[2 * (size_t)(n0 + t)]     = e0 * inv;
        out[2 * (size_t)(n0 + t) + 1] = e1 * inv;
    }
    for (int i = t; i < 1024; i += 512) {
        int r = i >> 4, kq = (i & 15) * 8;
        if (n0 + r < N)
            *(u16x8*)(P + (size_t)(n0 + r) * 128 + kq) = *(const u16x8*)&AS[r][kq];
    }
    __syncthreads();
    #pragma unroll
    for (int rf = 0; rf < 4; ++rf)
        #pragma unroll
        for (int reg = 0; reg < 4; ++reg)
            AS[rf * 16 + lrow + reg][m] = f2bf(accQ[rf][reg]);
    __syncthreads();
    for (int i = t; i < 1024; i += 512) {
        int r = i >> 4, kq = (i & 15) * 8;
        if (n0 + r < N)
            *(u16x8*)(Q + (size_t)(n0 + r) * 128 + kq) = *(const u16x8*)&AS[r][kq];
    }
}

// ---------------- edge MLP finish: CSR order, P amortized per node ---------
__global__ __launch_bounds__(256) void k_edge3(
    const unsigned short* __restrict__ P, const unsigned short* __restrict__ Q,
    const int* __restrict__ indptr, const int* __restrict__ colS,
    const int* __restrict__ eidx,
    const float* __restrict__ W2, const float* __restrict__ b2,
    float* __restrict__ out, int N) {
    const int wid = threadIdx.x >> 6, lane = threadIdx.x & 63;
    const int n = blockIdx.x * 4 + wid;
    if (n >= N) return;
    const int sl = lane & 15, g = lane >> 4;
    const int s = indptr[n], e = indptr[n + 1];
    float pf[8];
    {
        u16x8 pv = *(const u16x8*)(P + (size_t)n * 128 + sl * 8);
        #pragma unroll
        for (int j = 0; j < 8; ++j) pf[j] = bf2f(pv[j]);
    }
    const float* W2f = W2;
    const float b20 = b2[0], b21 = b2[1];
    for (int p = s + g; p < e; p += 8) {
        int p1 = p + 4;
        bool v1 = p1 < e;
        int col0 = colS[p],  eo0 = eidx[p];
        int col1 = v1 ? colS[p1] : col0;
        int eo1  = v1 ? eidx[p1] : 0;
        u16x8 qv0 = *(const u16x8*)(Q + (size_t)col0 * 128 + sl * 8);
        u16x8 qv1 = *(const u16x8*)(Q + (size_t)col1 * 128 + sl * 8);
        float l00 = 0.f, l01 = 0.f, l10 = 0.f, l11 = 0.f;
        #pragma unroll
        for (int j = 0; j < 8; ++j) {
            int ch = sl * 8 + j;
            float wA = W2f[ch * 2], wB = W2f[ch * 2 + 1];
            float h0 = fmaxf(pf[j] + bf2f(qv0[j]), 0.f);
            float h1 = fmaxf(pf[j] + bf2f(qv1[j]), 0.f);
            l00 += h0 * wA; l01 += h0 * wB;
            l10 += h1 * wA; l11 += h1 * wB;
        }
        #pragma unroll
        for (int o = 1; o < 16; o <<= 1) {
            l00 += __shfl_xor(l00, o); l01 += __shfl_xor(l01, o);
            l10 += __shfl_xor(l10, o); l11 += __shfl_xor(l11, o);
        }
        if (sl == 0) {
            {
                float a = l00 + b20, b = l01 + b21;
                float mm = fmaxf(a, b);
                float e0 = __expf(a - mm), e1 = __expf(b - mm);
                float inv = frcp(e0 + e1);
                out[2 * (size_t)N + 2 * (size_t)eo0]     = e0 * inv;
                out[2 * (size_t)N + 2 * (size_t)eo0 + 1] = e1 * inv;
            }
            if (v1) {
                float a = l10 + b20, b = l11 + b21;
                float mm = fmaxf(a, b);
                float e0 = __expf(a - mm), e1 = __expf(b - mm);
                float inv = frcp(e0 + e1);
                out[2 * (size_t)N + 2 * (size_t)eo1]     = e0 * inv;
                out[2 * (size_t)N + 2 * (size_t)eo1 + 1] = e1 * inv;
            }
        }
    }
}

// ---------------------------------------------------------------------------
extern "C" void kernel_launch(void* const* d_in, const int* in_sizes, int n_in,
                              void* d_out, int out_size, void* d_ws, size_t ws_size,
                              hipStream_t stream) {
    if (n_in < NIN) return;
    const int N = in_sizes[0] / 3;
    const int E = in_sizes[1] / 2;

    char* ws = (char*)d_ws;
    size_t off = 0;
    auto alloc = [&](size_t bytes) -> char* {
        char* p = ws + off;
        off = (off + bytes + 255) & ~(size_t)255;
        return p;
    };
    auto skipCanon = [](int i) {
        return i == 1 || (i >= 10 && i <= 17) || i == 6 || i == 20 || i == 24;
    };
    int* flags = (int*)alloc(32 * sizeof(int));
    int* bsums = (int*)alloc(128 * sizeof(int));
    float* canon[NIN];
    for (int i = 0; i < NIN; ++i) canon[i] = nullptr;
    for (int i = 0; i < NIN; ++i) {
        if (skipCanon(i)) continue;      // these are read raw by k_prep
        canon[i] = (float*)alloc((size_t)in_sizes[i] * 4);
    }
    int* row32  = (int*)alloc((size_t)E * 4);
    int* col32  = (int*)alloc((size_t)E * 4);
    int* indptr = (int*)alloc((size_t)(N + 1) * 4);
    int* cnt    = (int*)alloc((size_t)N * 4);
    int* colS   = (int*)alloc((size_t)E * 4);
    int* eidx   = (int*)alloc((size_t)E * 4);
    float* hs   = (float*)alloc((size_t)N * 4);
    float* hd   = (float*)alloc((size_t)N * 4);
    // hJK buffer: bf16 hlin during GAT phase; bf16 P/Q after the LSTM
    float* hJK  = (float*)alloc((size_t)N * 128 * 4);
    unsigned short* hlin = (unsigned short*)hJK;
    unsigned short* xsb = (unsigned short*)alloc((size_t)3 * N * 128 * 2);  // bf16 xs
    unsigned short* Bpack = (unsigned short*)alloc((size_t)2 * 10 * 48 * 512 * 2);
    unsigned short* Wg = (unsigned short*)alloc((size_t)2 * 4 * 8 * 512 * 2);
    unsigned short* Wt = (unsigned short*)alloc((size_t)4 * 24 * 512 * 2);
    float* bsum = (float*)alloc((size_t)2 * 768 * 4);
    float* scoreP = (float*)alloc((size_t)6 * N * 4);
    if (off > ws_size) return;
    unsigned short* P = (unsigned short*)hJK;           // bf16, N*128
    unsigned short* Q = (unsigned short*)hJK + (size_t)N * 128;

    InPtrs ip;
    for (int i = 0; i < NIN; ++i) { ip.p[i] = d_in[i]; ip.n[i] = in_sizes[i]; }

    k_sniff<<<NIN, 256, 0, stream>>>(ip, flags);

    // mega-prep: conv + edge decode/hist + all weight packs, one launch
    hipMemsetAsync(cnt, 0, (size_t)N * 4, stream);
    {
        PrepCfg C;
        int nj = 0, blk = 0;
        for (int i = 0; i < NIN; ++i) {
            if (skipCanon(i)) continue;
            C.src[nj] = d_in[i];
            C.dst[nj] = canon[i];
            C.n[nj] = in_sizes[i];
            C.ai[nj] = i;
            C.blk0[nj] = blk;
            blk += (in_sizes[i] + 255) / 256;
            ++nj;
        }
        C.blk0[nj] = blk;
        C.njobs = nj;
        C.cvB = blk;
        blk += (E + 255) / 256;                      C.wB = blk;
        blk += (2 * 10 * 48 * 512 + 255) / 256;      C.gB = blk;
        blk += (2 * 4 * 8 * 512 + 255) / 256;        C.tB = blk;
        blk += (4 * 24 * 512 + 255) / 256;
        C.esrc = d_in[1]; C.row = row32; C.col = col32; C.cnt = cnt; C.E = E;
        C.Wihf = d_in[10]; C.Whhf = d_in[11]; C.Wihb = d_in[14]; C.Whhb = d_in[15];
        C.bihf = d_in[12]; C.bhhf = d_in[13]; C.bihb = d_in[16]; C.bhhb = d_in[17];
        C.Bpack = Bpack; C.bsum = bsum;
        C.Wgsrc = d_in[6]; C.Wg = Wg;
        C.nW1src = d_in[20]; C.eW1src = d_in[24]; C.Wt = Wt;
        k_prep<<<blk, 256, 0, stream>>>(C, flags);
    }

    // CSR scan (scan3 also resets cnt for k_fill)
    const int nb1k = (N + 1023) / 1024;
    k_scan1<<<nb1k, 1024, 0, stream>>>(cnt, indptr, bsums, N);
    k_scan2<<<1, 64, 0, stream>>>(bsums, nb1k);
    k_scan3<<<(N + 255) / 256, 256, 0, stream>>>(bsums, indptr, cnt, N, nb1k);
    k_fill<<<(E + 255) / 256, 256, 0, stream>>>(row32, col32, indptr, cnt, colS, eidx, E);

    // GAT layer 0 (in=3)
    k_lin0<<<(N + 3) / 4, 256, 0, stream>>>(canon[0], canon[2], canon[4], canon[5],
                                            hlin, hs, hd, N);
    k_aggr<<<(N + 3) / 4, 256, 0, stream>>>(hlin, hs, hd, indptr, colS, canon[3], xsb, N);
    // GAT layers 1..2 (MFMA linear, bf16 in/out)
    for (int l = 1; l < 3; ++l) {
        const unsigned short* Wgl = Wg + (size_t)(l - 1) * 4 * 8 * 512;
        const float* bb = canon[7] + (size_t)(l - 1) * 128;
        const float* as = canon[8] + (size_t)(l - 1) * 128;
        const float* ad = canon[9] + (size_t)(l - 1) * 128;
        k_linm<<<(N + 63) / 64, 512, 0, stream>>>(xsb + (size_t)(l - 1) * N * 128, Wgl,
                                                  as, ad, hlin, hs, hd, N);
        k_aggr<<<(N + 3) / 4, 256, 0, stream>>>(hlin, hs, hd, indptr, colS, bb,
                                                xsb + (size_t)l * N * 128, N);
    }

    // fused bidirectional LSTM (MFMA, 64-row 12-wave) -> scores
    dim3 lgrid((N + 63) / 64, 2);
    k_lstm_mfma<<<lgrid, 768, 0, stream>>>(xsb, Bpack, bsum, canon[18], scoreP, N);

    float* out = (float*)d_out;
    // fused MFMA tail: JK finish + node MLP + P/Q
    k_tailm<<<(N + 63) / 64, 512, 0, stream>>>(xsb, scoreP, Wt,
                                               canon[21], canon[22], canon[23], canon[25],
                                               P, Q, out, N);
    // edge MLP in CSR order (P amortized per node; scatter via eidx)
    k_edge3<<<(N + 3) / 4, 256, 0, stream>>>(P, Q, indptr, colS, eidx,
                                             canon[26], canon[27], out, N);
}

// Round 19
// 583.692 us; speedup vs baseline: 1.2279x; 1.0017x over previous
//
#include <hip/hip_runtime.h>
#include <cstdint>
#include <cstddef>

// ---------------------------------------------------------------------------
// ParityGameGATNetwork: 3x GATConv -> JK bidirectional LSTM -> node/edge MLPs
// Round 19: k_aggr lane->channel remap (2l,2l+1): the per-edge hlin gather
// becomes one 4B load instead of two 2B loads 128B apart (24 -> 16 VMEM per
// 8-edge group; the loop is gather-issue-bound). Store likewise one 4B word.
// Everything else identical to round 18.
// ---------------------------------------------------------------------------

#define NIN 28
#define MAXJOBS 20

struct InPtrs { const void* p[NIN]; int n[NIN]; };

struct PrepCfg {
    const void* src[MAXJOBS];
    float* dst[MAXJOBS];
    int n[MAXJOBS];
    int ai[MAXJOBS];
    int blk0[MAXJOBS + 1];
    int njobs;
    int cvB, wB, gB, tB;                 // block range starts for fixed jobs
    // conve
    const void* esrc; int* row; int* col; int* cnt; int E;
    // wpack (lstm)
    const void *Wihf, *Whhf, *Wihb, *Whhb, *bihf, *bhhf, *bihb, *bhhb;
    unsigned short* Bpack; float* bsum;
    // wpackg (gat W, raw input 6)
    const void* Wgsrc; unsigned short* Wg;
    // wpackt (nW1 input 20, eW1 input 24, raw)
    const void* nW1src; const void* eW1src; unsigned short* Wt;
};

typedef short s16x4 __attribute__((ext_vector_type(4)));
typedef short s16x8 __attribute__((ext_vector_type(8)));
typedef float f32x4 __attribute__((ext_vector_type(4)));
typedef unsigned short u16x8 __attribute__((ext_vector_type(8)));

__device__ __forceinline__ float bf2f(unsigned short v) {
    unsigned int u = ((unsigned int)v) << 16;
    return __uint_as_float(u);
}

__device__ __forceinline__ unsigned short f2bf(float x) {
    unsigned int u = __float_as_uint(x);
    unsigned int r = u + 0x7fffu + ((u >> 16) & 1u);
    return (unsigned short)(r >> 16);
}

__device__ __forceinline__ float rdx(const void* p, size_t i, int isf32) {
    return isf32 ? ((const float*)p)[i] : bf2f(((const unsigned short*)p)[i]);
}

__device__ __forceinline__ float frcp(float x) {        // raw v_rcp_f32 (~1ulp)
    return __builtin_amdgcn_rcpf(x);
}

__device__ __forceinline__ float sigm(float x) {
    return frcp(1.f + __expf(-x));
}

__device__ __forceinline__ float fast_tanh(float x) {
    return 1.f - 2.f * frcp(__expf(2.f * x) + 1.f);
}

// ---------------- dtype sniffing -------------------------------------------
__global__ void k_sniff(InPtrs in, int* flags) {
    int ai = blockIdx.x;
    if (ai >= NIN) return;
    __shared__ int cnt;
    if (threadIdx.x == 0) cnt = 0;
    __syncthreads();
    if (ai == 1) {
        const int* w = (const int*)in.p[1];
        int nw = in.n[1] < 512 ? in.n[1] : 512;
        int local = 0;
        for (int i = threadIdx.x; i < nw; i += blockDim.x)
            if ((i & 1) && w[i] != 0) local++;
        atomicAdd(&cnt, local);
        __syncthreads();
        if (threadIdx.x == 0) flags[1] = (cnt < 4) ? 1 : 0;
        return;
    }
    const unsigned short* u = (const unsigned short*)in.p[ai];
    int ns = in.n[ai] < 256 ? in.n[ai] : 256;
    int local = 0;
    for (int i = threadIdx.x; i < ns; i += blockDim.x) {
        if (i & 1) continue;
        unsigned short v = u[i];
        int e = (v >> 7) & 0xff;
        if ((v & 0x7fff) != 0 && (e < 100 || e > 154)) local++;
    }
    atomicAdd(&cnt, local);
    __syncthreads();
    if (threadIdx.x == 0) flags[ai] = (cnt * 4 >= ns) ? 1 : 0;
}

// ---------------- mega prep: conv + edge decode/hist + all weight packs ----
__global__ void k_prep(PrepCfg C, const int* __restrict__ flags) {
    const int b = blockIdx.x;
    const int tid = threadIdx.x;
    if (b < C.cvB) {                     // canonicalization jobs
        int j = 0;
        while (j + 1 < C.njobs && b >= C.blk0[j + 1]) ++j;
        int i = (b - C.blk0[j]) * 256 + tid;
        if (i < C.n[j]) C.dst[j][i] = rdx(C.src[j], i, flags[C.ai[j]]);
        return;
    }
    if (b < C.wB) {                      // edge decode + histogram
        int i = (b - C.cvB) * 256 + tid;
        if (i >= C.E) return;
        int r, c;
        if (flags[1]) {
            const long long* s = (const long long*)C.esrc;
            r = (int)s[i];
            c = (int)s[(size_t)C.E + i];
        } else {
            const int* s = (const int*)C.esrc;
            r = s[i];
            c = s[(size_t)C.E + i];
        }
        C.row[i] = r;
        C.col[i] = c;
        atomicAdd(&C.cnt[r], 1);
        return;
    }
    if (b < C.gB) {                      // LSTM weight pack
        int idx = (b - C.wB) * 256 + tid;
        const int TOT = 2 * 10 * 48 * 512;
        if (idx < TOT) {
            int dir = idx / (10 * 48 * 512);
            int r   = idx % (10 * 48 * 512);
            int kb  = r / (48 * 512);
            int r2  = r % (48 * 512);
            int f   = r2 / 512;
            int q   = r2 % 512;
            int lane = q >> 3, j = q & 7;
            int k   = kb * 32 + ((j >> 2) * 16) + ((lane >> 4) * 4) + (j & 3);
            int col = f * 16 + (lane & 15);
            float v;
            if (k < 128)
                v = dir ? rdx(C.Wihb, (size_t)col * 128 + k, flags[14])
                        : rdx(C.Wihf, (size_t)col * 128 + k, flags[10]);
            else
                v = dir ? rdx(C.Whhb, (size_t)col * 192 + (k - 128), flags[15])
                        : rdx(C.Whhf, (size_t)col * 192 + (k - 128), flags[11]);
            C.Bpack[idx] = f2bf(v);
        }
        if (idx < 2 * 768) {
            int d = idx / 768, j = idx % 768;
            C.bsum[idx] = d ? rdx(C.bihb, j, flags[16]) + rdx(C.bhhb, j, flags[17])
                            : rdx(C.bihf, j, flags[12]) + rdx(C.bhhf, j, flags[13]);
        }
        return;
    }
    if (b < C.tB) {                      // GAT W pack (layers 1-2, raw input 6)
        int idx = (b - C.gB) * 256 + tid;
        if (idx >= 2 * 4 * 8 * 512) return;
        int layer = idx / 16384;
        int r  = idx % 16384;
        int kb = r / 4096;
        int r2 = r % 4096;
        int f  = r2 / 512;
        int q  = r2 % 512;
        int lane = q >> 3, j = q & 7;
        int k   = kb * 32 + ((j >> 2) * 16) + ((lane >> 4) * 4) + (j & 3);
        int col = f * 16 + (lane & 15);
        C.Wg[idx] = f2bf(rdx(C.Wgsrc, (size_t)layer * 16384 + (size_t)k * 128 + col,
                             flags[6]));
        return;
    }
    {                                    // tail W pack (raw inputs 20/24)
        int idx = (b - C.tB) * 256 + tid;
        if (idx >= 4 * 24 * 512) return;
        int kb = idx / (24 * 512);
        int r  = idx % (24 * 512);
        int fr = r / 512;
        int q  = r % 512;
        int lane = q >> 3, j = q & 7;
        int k   = kb * 32 + ((j >> 2) * 16) + ((lane >> 4) * 4) + (j & 3);
        int grp = fr >> 3;
        int col = (fr & 7) * 16 + (lane & 15);
        float v;
        if (grp == 0)      v = rdx(C.nW1src, (size_t)k * 128 + col, flags[20]);
        else if (grp == 1) v = rdx(C.eW1src, (size_t)k * 128 + col, flags[24]);
        else               v = rdx(C.eW1src, (size_t)(128 + k) * 128 + col, flags[24]);
        C.Wt[idx] = f2bf(v);
    }
}

// ---------------- CSR build ------------------------------------------------
__global__ void k_scan1(const int* __restrict__ deg, int* __restrict__ indptr,
                        int* __restrict__ bsums, int N) {
    __shared__ int buf[1024];
    const int t = threadIdx.x;
    const int base = blockIdx.x * 1024;
    int v = (base + t < N) ? deg[base + t] : 0;
    buf[t] = v;
    __syncthreads();
    for (int ofs = 1; ofs < 1024; ofs <<= 1) {
        int add = (t >= ofs) ? buf[t - ofs] : 0;
        __syncthreads();
        buf[t] += add;
        __syncthreads();
    }
    if (base + t < N) indptr[base + t] = buf[t] - v;
    if (t == 1023) bsums[blockIdx.x] = buf[1023];
}

__global__ void k_scan2(int* bsums, int nb) {
    if (threadIdx.x == 0 && blockIdx.x == 0) {
        int acc = 0;
        for (int j = 0; j < nb; ++j) { int v = bsums[j]; bsums[j] = acc; acc += v; }
        bsums[nb] = acc;
    }
}

__global__ void k_scan3(const int* __restrict__ bsums, int* __restrict__ indptr,
                        int* __restrict__ cnt, int N, int nb) {
    int i = blockIdx.x * blockDim.x + threadIdx.x;
    if (i < N) {
        indptr[i] += bsums[i >> 10];
        cnt[i] = 0;
    }
    if (i == 0) indptr[N] = bsums[nb];
}

__global__ void k_fill(const int* __restrict__ row, const int* __restrict__ col,
                       const int* __restrict__ indptr, int* __restrict__ cur,
                       int* __restrict__ colS, int* __restrict__ eidx, int E) {
    int i = blockIdx.x * blockDim.x + threadIdx.x;
    if (i >= E) return;
    int r = row[i];
    int p = indptr[r] + atomicAdd(&cur[r], 1);
    colS[p] = col[i];
    eidx[p] = i;
}

// ---------------- GAT linear layer 0 (in=3), hlin out bf16 -----------------
__global__ __launch_bounds__(256) void k_lin0(
    const float* __restrict__ x, const float* __restrict__ W0,
    const float* __restrict__ asrc, const float* __restrict__ adst,
    unsigned short* __restrict__ hlin, float* __restrict__ hs, float* __restrict__ hd,
    int N) {
    const int wid = threadIdx.x >> 6, lane = threadIdx.x & 63;
    const int n = blockIdx.x * 4 + wid;
    if (n >= N) return;
    float x0 = x[(size_t)n * 3], x1 = x[(size_t)n * 3 + 1], x2 = x[(size_t)n * 3 + 2];
    const int c0 = lane, c1 = lane + 64;
    float h0 = x0 * W0[c0] + x1 * W0[128 + c0] + x2 * W0[256 + c0];
    float h1 = x0 * W0[c1] + x1 * W0[128 + c1] + x2 * W0[256 + c1];
    hlin[(size_t)n * 128 + c0] = f2bf(h0);
    hlin[(size_t)n * 128 + c1] = f2bf(h1);
    float sp = h0 * asrc[c0] + h1 * asrc[c1];
    float dp = h0 * adst[c0] + h1 * adst[c1];
    for (int o = 32; o; o >>= 1) { sp += __shfl_down(sp, o); dp += __shfl_down(dp, o); }
    if (lane == 0) { hs[n] = sp; hd[n] = dp; }
}

// ---------------- GAT linear (MFMA): 64 nodes, 8 waves ---------------------
__global__ __launch_bounds__(512) void k_linm(
    const unsigned short* __restrict__ xin,   // [N][128] bf16
    const unsigned short* __restrict__ Wg,    // [4][8][512] bf16 (this layer)
    const float* __restrict__ asrc, const float* __restrict__ adst,
    unsigned short* __restrict__ hlin, float* __restrict__ hs, float* __restrict__ hd,
    int N) {
    __shared__ unsigned short AS[64][136];
    __shared__ float hsS[64], hdS[64];
    const int t = threadIdx.x;
    const int f = t >> 6, lane = t & 63;
    const int n0 = blockIdx.x * 64;
    const int ccol = lane & 15;
    const int klane = lane >> 4;
    const int lrow = klane * 4;
    const int akl = klane * 4;
    const int m = f * 16 + ccol;

    const float asv = asrc[m], adv = adst[m];

    for (int i = t; i < 1024; i += 512) {
        int r = i >> 4, kq = (i & 15) * 8;
        u16x8 v = (u16x8)(0);
        if (n0 + r < N) v = *(const u16x8*)(xin + (size_t)(n0 + r) * 128 + kq);
        *(u16x8*)&AS[r][kq] = v;
    }
    if (t < 64) { hsS[t] = 0.f; hdS[t] = 0.f; }
    __syncthreads();

    f32x4 acc[4];
    #pragma unroll
    for (int rf = 0; rf < 4; ++rf) acc[rf] = (f32x4)(0.f);
    #pragma unroll
    for (int kb = 0; kb < 4; ++kb) {
        s16x8 b = *(const s16x8*)(Wg + ((size_t)kb * 8 + f) * 512 + lane * 8);
        const int k0 = kb * 32 + akl;
        #pragma unroll
        for (int rf = 0; rf < 4; ++rf) {
            s16x4 alo = *(const s16x4*)&AS[rf * 16 + ccol][k0];
            s16x4 ahi = *(const s16x4*)&AS[rf * 16 + ccol][k0 + 16];
            s16x8 av = __builtin_shufflevector(alo, ahi, 0, 1, 2, 3, 4, 5, 6, 7);
            acc[rf] = __builtin_amdgcn_mfma_f32_16x16x32_bf16(av, b, acc[rf], 0, 0, 0);
        }
    }
    __syncthreads();   // all A reads done before h overwrite

    float sp[16], dp[16];
    #pragma unroll
    for (int rf = 0; rf < 4; ++rf) {
        #pragma unroll
        for (int reg = 0; reg < 4; ++reg) {
            float h = acc[rf][reg];
            int ci = rf * 4 + reg;
            AS[rf * 16 + lrow + reg][m] = f2bf(h);
            sp[ci] = h * asv;
            dp[ci] = h * adv;
        }
    }
    #pragma unroll
    for (int o = 1; o < 16; o <<= 1) {
        #pragma unroll
        for (int i = 0; i < 16; ++i) { sp[i] += __shfl_xor(sp[i], o); dp[i] += __shfl_xor(dp[i], o); }
    }
    if (ccol == 0) {
        #pragma unroll
        for (int i = 0; i < 16; ++i) {
            int row = (i >> 2) * 16 + lrow + (i & 3);
            atomicAdd(&hsS[row], sp[i]);
            atomicAdd(&hdS[row], dp[i]);
        }
    }
    __syncthreads();

    for (int i = t; i < 1024; i += 512) {
        int r = i >> 4, kq = (i & 15) * 8;
        if (n0 + r < N)
            *(u16x8*)(hlin + (size_t)(n0 + r) * 128 + kq) = *(const u16x8*)&AS[r][kq];
    }
    if (t < 64 && n0 + t < N) { hs[n0 + t] = hsS[t]; hd[n0 + t] = hdS[t]; }
}

// ---------------- GAT aggregation: online segment softmax ------------------
// Lane owns channels (2*lane, 2*lane+1): one 4B gather per edge per lane.
__global__ __launch_bounds__(256) void k_aggr(
    const unsigned short* __restrict__ hlin, const float* __restrict__ hs,
    const float* __restrict__ hd,
    const int* __restrict__ indptr, const int* __restrict__ colS,
    const float* __restrict__ b, unsigned short* __restrict__ xout, int N) {
    const int wid = threadIdx.x >> 6, lane = threadIdx.x & 63;
    const int n = blockIdx.x * 4 + wid;
    if (n >= N) return;
    const int s = indptr[n], epos = indptr[n + 1];
    const float hdv = hd[n];
    const int c0 = lane * 2, c1 = lane * 2 + 1;
    float m = -1e30f, d = 0.f, a0 = 0.f, a1 = 0.f;
    int idx = s;
    for (; idx + 8 <= epos; idx += 8) {
        int cl[8];
        #pragma unroll
        for (int j = 0; j < 8; ++j) cl[j] = colS[idx + j];
        float e[8];
        #pragma unroll
        for (int j = 0; j < 8; ++j) {
            float ev = hs[cl[j]] + hdv;
            e[j] = (ev > 0.f) ? ev : 0.2f * ev;
        }
        unsigned int hw[8];
        #pragma unroll
        for (int j = 0; j < 8; ++j)
            hw[j] = *(const unsigned int*)(hlin + (size_t)cl[j] * 128 + c0);
        float m8 = e[0];
        #pragma unroll
        for (int j = 1; j < 8; ++j) m8 = fmaxf(m8, e[j]);
        if (m8 > m) {
            float sc = __expf(m - m8);
            a0 *= sc; a1 *= sc; d *= sc; m = m8;
        }
        #pragma unroll
        for (int j = 0; j < 8; ++j) {
            float w = __expf(e[j] - m);
            a0 += w * bf2f((unsigned short)(hw[j] & 0xffffu));
            a1 += w * bf2f((unsigned short)(hw[j] >> 16));
            d  += w;
        }
    }
    for (; idx < epos; ++idx) {
        int col = colS[idx];
        float e = hs[col] + hdv;
        e = (e > 0.f) ? e : 0.2f * e;
        unsigned int hw = *(const unsigned int*)(hlin + (size_t)col * 128 + c0);
        float v0 = bf2f((unsigned short)(hw & 0xffffu));
        float v1 = bf2f((unsigned short)(hw >> 16));
        if (e > m) {
            float sc = __expf(m - e);
            a0 = a0 * sc + v0;
            a1 = a1 * sc + v1;
            d  = d * sc + 1.f;
            m  = e;
        } else {
            float w = __expf(e - m);
            a0 += w * v0;
            a1 += w * v1;
            d  += w;
        }
    }
    float inv = frcp(d + 1e-16f);
    float r0 = a0 * inv + b[c0];
    float r1 = a1 * inv + b[c1];
    unsigned int ow = (unsigned int)f2bf(fmaxf(r0, 0.f))
                    | ((unsigned int)f2bf(fmaxf(r1, 0.f)) << 16);
    *(unsigned int*)(xout + (size_t)n * 128 + c0) = ow;
}

// ---------------- fused bidirectional LSTM: 64 rows, 12 waves --------------
__global__ __launch_bounds__(768, 3) void k_lstm_mfma(
    const unsigned short* __restrict__ xsb,  // [3][N][128] bf16
    const unsigned short* __restrict__ Bpack,// [2][10][48][512] bf16
    const float* __restrict__ bsum,          // [2][768]
    const float* __restrict__ attW,          // [384]
    float* __restrict__ scoreP,              // [2][3][N]
    int N) {
    __shared__ unsigned short AS[64][332];   // x:[0,128)  h:[128,320)
    __shared__ float scoreS[64];
    const int t = threadIdx.x;
    const int bf = t >> 6, lane = t & 63;
    const int dir = blockIdx.y;
    const int n0 = blockIdx.x * 64;
    const int ccol = lane & 15;
    const int klane = lane >> 4;
    const int lrow = klane * 4;
    const int akl = klane * 4;
    const int m = bf * 16 + ccol;            // this thread's hidden unit

    const float bI = bsum[dir * 768 + m];
    const float bF = bsum[dir * 768 + 192 + m];
    const float bG = bsum[dir * 768 + 384 + m];
    const float bO = bsum[dir * 768 + 576 + m];
    const float awt = attW[dir * 192 + m];
    float cst[16];
    #pragma unroll
    for (int i = 0; i < 16; ++i) cst[i] = 0.f;

    const unsigned short* Bd = Bpack + (size_t)dir * 10 * 48 * 512;

    // ---- prologue: stage x for s=0 ----
    {
        const int l0 = dir ? 2 : 0;
        const unsigned short* xsrc = xsb + ((size_t)l0 * N + n0) * 128;
        for (int i = t; i < 1024; i += 768) {
            int r = i >> 4, kq = (i & 15) * 8;
            u16x8 v = (u16x8)(0);
            if (n0 + r < N) v = *(const u16x8*)(xsrc + (size_t)r * 128 + kq);
            *(u16x8*)&AS[r][kq] = v;
        }
    }
    if (t < 64) scoreS[t] = 0.f;
    __syncthreads();

    for (int s = 0; s < 3; ++s) {
        const int l = dir ? (2 - s) : s;

        // ---- MFMA GEMM over K, B ping-pong prefetch ----
        const int KB = s ? 10 : 4;               // both even
        f32x4 acc[4][4];
        #pragma unroll
        for (int rf = 0; rf < 4; ++rf)
            #pragma unroll
            for (int g = 0; g < 4; ++g) acc[rf][g] = (f32x4)(0.f);
        s16x8 bA[4], bB[4];
        {
            const unsigned short* bb = Bd + (size_t)bf * 512 + lane * 8;   // kb=0
            #pragma unroll
            for (int g = 0; g < 4; ++g) bA[g] = *(const s16x8*)(bb + (size_t)g * 6144);
        }
        for (int kb = 0; kb < KB; kb += 2) {
            {   // prefetch kb+1
                const unsigned short* bb = Bd + ((size_t)(kb + 1) * 48 + bf) * 512 + lane * 8;
                #pragma unroll
                for (int g = 0; g < 4; ++g) bB[g] = *(const s16x8*)(bb + (size_t)g * 6144);
            }
            {   // compute kb on bA
                const int k0 = kb * 32 + akl;
                s16x8 av[4];
                #pragma unroll
                for (int rf = 0; rf < 4; ++rf) {
                    s16x4 alo = *(const s16x4*)&AS[rf * 16 + ccol][k0];
                    s16x4 ahi = *(const s16x4*)&AS[rf * 16 + ccol][k0 + 16];
                    av[rf] = __builtin_shufflevector(alo, ahi, 0, 1, 2, 3, 4, 5, 6, 7);
                }
                #pragma unroll
                for (int rf = 0; rf < 4; ++rf)
                    #pragma unroll
                    for (int g = 0; g < 4; ++g)
                        acc[rf][g] = __builtin_amdgcn_mfma_f32_16x16x32_bf16(
                            av[rf], bA[g], acc[rf][g], 0, 0, 0);
            }
            if (kb + 2 < KB) {   // prefetch kb+2
                const unsigned short* bb = Bd + ((size_t)(kb + 2) * 48 + bf) * 512 + lane * 8;
                #pragma unroll
                for (int g = 0; g < 4; ++g) bA[g] = *(const s16x8*)(bb + (size_t)g * 6144);
            }
            {   // compute kb+1 on bB
                const int k0 = (kb + 1) * 32 + akl;
                s16x8 av[4];
                #pragma unroll
                for (int rf = 0; rf < 4; ++rf) {
                    s16x4 alo = *(const s16x4*)&AS[rf * 16 + ccol][k0];
                    s16x4 ahi = *(const s16x4*)&AS[rf * 16 + ccol][k0 + 16];
                    av[rf] = __builtin_shufflevector(alo, ahi, 0, 1, 2, 3, 4, 5, 6, 7);
                }
                #pragma unroll
                for (int rf = 0; rf < 4; ++rf)
                    #pragma unroll
                    for (int g = 0; g < 4; ++g)
                        acc[rf][g] = __builtin_amdgcn_mfma_f32_16x16x32_bf16(
                            av[rf], bB[g], acc[rf][g], 0, 0, 0);
            }
        }
        __syncthreads();   // SYNC2: all A reads done (x region now dead)

        // ---- issue next-layer x loads into registers (hidden under epilogue)
        u16x8 nx0 = (u16x8)(0), nx1 = (u16x8)(0);
        if (s < 2) {
            const int ln = dir ? (1 - s) : (s + 1);
            const unsigned short* xsrc = xsb + ((size_t)ln * N + n0) * 128;
            {
                int r = t >> 4, kq = (t & 15) * 8;
                if (n0 + r < N) nx0 = *(const u16x8*)(xsrc + (size_t)r * 128 + kq);
            }
            if (t < 256) {
                int i = t + 768, r = i >> 4, kq = (i & 15) * 8;
                if (n0 + r < N) nx1 = *(const u16x8*)(xsrc + (size_t)r * 128 + kq);
            }
        }

        // ---- cell epilogue: one unit per thread, 16 rows (rcp-based) ----
        float sp[16];
        #pragma unroll
        for (int rf = 0; rf < 4; ++rf) {
            #pragma unroll
            for (int reg = 0; reg < 4; ++reg) {
                float gI = acc[rf][0][reg] + bI;
                float gF = acc[rf][1][reg] + bF;
                float gG = acc[rf][2][reg] + bG;
                float gO = acc[rf][3][reg] + bO;
                float ig = sigm(gI);
                float fg = sigm(gF);
                float gt = fast_tanh(gG);
                float og = sigm(gO);
                int ci = rf * 4 + reg;
                float cn = fg * cst[ci] + ig * gt;
                cst[ci] = cn;
                float hh = og * fast_tanh(cn);
                AS[rf * 16 + lrow + reg][128 + m] = f2bf(hh);
                sp[ci] = hh * awt;
            }
        }
        #pragma unroll
        for (int o = 1; o < 16; o <<= 1) {
            #pragma unroll
            for (int i = 0; i < 16; ++i) sp[i] += __shfl_xor(sp[i], o);
        }
        if (ccol == 0) {
            #pragma unroll
            for (int i = 0; i < 16; ++i)
                atomicAdd(&scoreS[(i >> 2) * 16 + lrow + (i & 3)], sp[i]);
        }

        // ---- write staged next-x into LDS x region ----
        if (s < 2) {
            {
                int r = t >> 4, kq = (t & 15) * 8;
                *(u16x8*)&AS[r][kq] = nx0;
            }
            if (t < 256) {
                int i = t + 768, r = i >> 4, kq = (i & 15) * 8;
                *(u16x8*)&AS[r][kq] = nx1;
            }
        }
        __syncthreads();   // SYNC3: h writes + score atomics + x staging

        if (t < 64) {
            if (n0 + t < N)
                scoreP[(size_t)(dir * 3 + l) * N + n0 + t] = scoreS[t];
            scoreS[t] = 0.f;   // reset; visible before next epilogue (SYNC2)
        }
    }
}

// ---------------- fused MFMA tail: JK sum + node MLP + P/Q, 64 nodes -------
__global__ __launch_bounds__(512) void k_tailm(
    const unsigned short* __restrict__ xsb, const float* __restrict__ scoreP,
    const unsigned short* __restrict__ Wt,   // [4][24][512] bf16
    const float* __restrict__ nb1, const float* __restrict__ nW2,
    const float* __restrict__ nb2, const float* __restrict__ eb1,
    unsigned short* __restrict__ P, unsigned short* __restrict__ Q,
    float* __restrict__ out, int N) {
    __shared__ unsigned short AS[64][136];
    __shared__ float al[64][4];
    __shared__ float lgt[64][2];
    const int t = threadIdx.x;
    const int f = t >> 6, lane = t & 63;
    const int n0 = blockIdx.x * 64;
    const int ccol = lane & 15;
    const int klane = lane >> 4;
    const int lrow = klane * 4;
    const int akl = klane * 4;
    const int m = f * 16 + ccol;                 // output col in [0,128)

    if (t < 64) {
        int n = n0 + t;
        float e0 = 0.f, e1 = 0.f, e2 = 0.f;
        if (n < N) {
            float s0 = scoreP[n]                 + scoreP[(size_t)3 * N + n];
            float s1 = scoreP[(size_t)N + n]     + scoreP[(size_t)4 * N + n];
            float s2 = scoreP[(size_t)2 * N + n] + scoreP[(size_t)5 * N + n];
            float mm = fmaxf(s0, fmaxf(s1, s2));
            e0 = __expf(s0 - mm); e1 = __expf(s1 - mm); e2 = __expf(s2 - mm);
            float inv = frcp(e0 + e1 + e2);
            e0 *= inv; e1 *= inv; e2 *= inv;
        }
        al[t][0] = e0; al[t][1] = e1; al[t][2] = e2;
        lgt[t][0] = 0.f; lgt[t][1] = 0.f;
    }
    __syncthreads();

    const size_t L1o = (size_t)N * 128, L2o = 2 * L1o;
    for (int i = t; i < 1024; i += 512) {
        int r = i >> 4, kq = (i & 15) * 8;
        u16x8 o8 = (u16x8)(0);
        if (n0 + r < N) {
            size_t base = (size_t)(n0 + r) * 128 + kq;
            u16x8 a = *(const u16x8*)(xsb + base);
            u16x8 b = *(const u16x8*)(xsb + L1o + base);
            u16x8 c = *(const u16x8*)(xsb + L2o + base);
            float w0 = al[r][0], w1 = al[r][1], w2 = al[r][2];
            #pragma unroll
            for (int j = 0; j < 8; ++j)
                o8[j] = f2bf(w0 * bf2f(a[j]) + w1 * bf2f(b[j]) + w2 * bf2f(c[j]));
        }
        *(u16x8*)&AS[r][kq] = o8;
    }
    __syncthreads();

    f32x4 accN[4], accP[4], accQ[4];
    #pragma unroll
    for (int rf = 0; rf < 4; ++rf) { accN[rf] = (f32x4)(0.f); accP[rf] = (f32x4)(0.f); accQ[rf] = (f32x4)(0.f); }
    #pragma unroll
    for (int kb = 0; kb < 4; ++kb) {
        s16x8 bN = *(const s16x8*)(Wt + ((size_t)kb * 24 + f) * 512 + lane * 8);
        s16x8 bP = *(const s16x8*)(Wt + ((size_t)kb * 24 + 8 + f) * 512 + lane * 8);
        s16x8 bQ = *(const s16x8*)(Wt + ((size_t)kb * 24 + 16 + f) * 512 + lane * 8);
        const int k0 = kb * 32 + akl;
        #pragma unroll
        for (int rf = 0; rf < 4; ++rf) {
            s16x4 alo = *(const s16x4*)&AS[rf * 16 + ccol][k0];
            s16x4 ahi = *(const s16x4*)&AS[rf * 16 + ccol][k0 + 16];
            s16x8 av = __builtin_shufflevector(alo, ahi, 0, 1, 2, 3, 4, 5, 6, 7);
            accN[rf] = __builtin_amdgcn_mfma_f32_16x16x32_bf16(av, bN, accN[rf], 0, 0, 0);
            accP[rf] = __builtin_amdgcn_mfma_f32_16x16x32_bf16(av, bP, accP[rf], 0, 0, 0);
            accQ[rf] = __builtin_amdgcn_mfma_f32_16x16x32_bf16(av, bQ, accQ[rf], 0, 0, 0);
        }
    }
    __syncthreads();   // all A reads done before overwrite

    {
        const float nb1v = nb1[m];
        const float w20 = nW2[2 * m], w21 = nW2[2 * m + 1];
        float s0[16], s1[16];
        #pragma unroll
        for (int rf = 0; rf < 4; ++rf) {
            #pragma unroll
            for (int reg = 0; reg < 4; ++reg) {
                float h = fmaxf(accN[rf][reg] + nb1v, 0.f);
                int ci = rf * 4 + reg;
                s0[ci] = h * w20;
                s1[ci] = h * w21;
            }
        }
        #pragma unroll
        for (int o = 1; o < 16; o <<= 1) {
            #pragma unroll
            for (int i = 0; i < 16; ++i) { s0[i] += __shfl_xor(s0[i], o); s1[i] += __shfl_xor(s1[i], o); }
        }
        if (ccol == 0) {
            #pragma unroll
            for (int i = 0; i < 16; ++i) {
                int row = (i >> 2) * 16 + lrow + (i & 3);
                atomicAdd(&lgt[row][0], s0[i]);
                atomicAdd(&lgt[row][1], s1[i]);
            }
        }
    }
    {
        const float eb1v = eb1[m];
        #pragma unroll
        for (int rf = 0; rf < 4; ++rf)
            #pragma unroll
            for (int reg = 0; reg < 4; ++reg)
                AS[rf * 16 + lrow + reg][m] = f2bf(accP[rf][reg] + eb1v);
    }
    __syncthreads();
    if (t < 64 && n0 + t < N) {
        float l0 = lgt[t][0] + nb2[0], l1 = lgt[t][1] + nb2[1];
        float mm = fmaxf(l0, l1);
        float e0 = __expf(l0 - mm), e1 = __expf(l1 - mm);
        float inv = frcp(e0 + e1);
        out[2 * (size_t)(n0 + t)]     = e0 * inv;
        out[2 * (size_t)(n0 + t) + 1] = e1 * inv;
    }
    for (int i = t; i < 1024; i += 512) {
        int r = i >> 4, kq = (i & 15) * 8;
        if (n0 + r < N)
            *(u16x8*)(P + (size_t)(n0 + r) * 128 + kq) = *(const u16x8*)&AS[r][kq];
    }
    __syncthreads();
    #pragma unroll
    for (int rf = 0; rf < 4; ++rf)
        #pragma unroll
        for (int reg = 0; reg < 4; ++reg)
            AS[rf * 16 + lrow + reg][m] = f2bf(accQ[rf][reg]);
    __syncthreads();
    for (int i = t; i < 1024; i += 512) {
        int r = i >> 4, kq = (i & 15) * 8;
        if (n0 + r < N)
            *(u16x8*)(Q + (size_t)(n0 + r) * 128 + kq) = *(const u16x8*)&AS[r][kq];
    }
}

// ---------------- edge MLP finish: CSR order, P amortized per node ---------
__global__ __launch_bounds__(256) void k_edge3(
    const unsigned short* __restrict__ P, const unsigned short* __restrict__ Q,
    const int* __restrict__ indptr, const int* __restrict__ colS,
    const int* __restrict__ eidx,
    const float* __restrict__ W2, const float* __restrict__ b2,
    float* __restrict__ out, int N) {
    const int wid = threadIdx.x >> 6, lane = threadIdx.x & 63;
    const int n = blockIdx.x * 4 + wid;
    if (n >= N) return;
    const int sl = lane & 15, g = lane >> 4;
    const int s = indptr[n], e = indptr[n + 1];
    float pf[8];
    {
        u16x8 pv = *(const u16x8*)(P + (size_t)n * 128 + sl * 8);
        #pragma unroll
        for (int j = 0; j < 8; ++j) pf[j] = bf2f(pv[j]);
    }
    const float* W2f = W2;
    const float b20 = b2[0], b21 = b2[1];
    for (int p = s + g; p < e; p += 8) {
        int p1 = p + 4;
        bool v1 = p1 < e;
        int col0 = colS[p],  eo0 = eidx[p];
        int col1 = v1 ? colS[p1] : col0;
        int eo1  = v1 ? eidx[p1] : 0;
        u16x8 qv0 = *(const u16x8*)(Q + (size_t)col0 * 128 + sl * 8);
        u16x8 qv1 = *(const u16x8*)(Q + (size_t)col1 * 128 + sl * 8);
        float l00 = 0.f, l01 = 0.f, l10 = 0.f, l11 = 0.f;
        #pragma unroll
        for (int j = 0; j < 8; ++j) {
            int ch = sl * 8 + j;
            float wA = W2f[ch * 2], wB = W2f[ch * 2 + 1];
            float h0 = fmaxf(pf[j] + bf2f(qv0[j]), 0.f);
            float h1 = fmaxf(pf[j] + bf2f(qv1[j]), 0.f);
            l00 += h0 * wA; l01 += h0 * wB;
            l10 += h1 * wA; l11 += h1 * wB;
        }
        #pragma unroll
        for (int o = 1; o < 16; o <<= 1) {
            l00 += __shfl_xor(l00, o); l01 += __shfl_xor(l01, o);
            l10 += __shfl_xor(l10, o); l11 += __shfl_xor(l11, o);
        }
        if (sl == 0) {
            {
                float a = l00 + b20, b = l01 + b21;
                float mm = fmaxf(a, b);
                float e0 = __expf(a - mm), e1 = __expf(b - mm);
                float inv = frcp(e0 + e1);
                out[2 * (size_t)N + 2 * (size_t)eo0]     = e0 * inv;
                out[2 * (size_t)N + 2 * (size_t)eo0 + 1] = e1 * inv;
            }
            if (v1) {
                float a = l10 + b20, b = l11 + b21;
                float mm = fmaxf(a, b);
                float e0 = __expf(a - mm), e1 = __expf(b - mm);
                float inv = frcp(e0 + e1);
                out[2 * (size_t)N + 2 * (size_t)eo1]     = e0 * inv;
                out[2 * (size_t)N + 2 * (size_t)eo1 + 1] = e1 * inv;
            }
        }
    }
}

// ---------------------------------------------------------------------------
extern "C" void kernel_launch(void* const* d_in, const int* in_sizes, int n_in,
                              void* d_out, int out_size, void* d_ws, size_t ws_size,
                              hipStream_t stream) {
    if (n_in < NIN) return;
    const int N = in_sizes[0] / 3;
    const int E = in_sizes[1] / 2;

    char* ws = (char*)d_ws;
    size_t off = 0;
    auto alloc = [&](size_t bytes) -> char* {
        char* p = ws + off;
        off = (off + bytes + 255) & ~(size_t)255;
        return p;
    };
    auto skipCanon = [](int i) {
        return i == 1 || (i >= 10 && i <= 17) || i == 6 || i == 20 || i == 24;
    };
    int* flags = (int*)alloc(32 * sizeof(int));
    int* bsums = (int*)alloc(128 * sizeof(int));
    float* canon[NIN];
    for (int i = 0; i < NIN; ++i) canon[i] = nullptr;
    for (int i = 0; i < NIN; ++i) {
        if (skipCanon(i)) continue;      // these are read raw by k_prep
        canon[i] = (float*)alloc((size_t)in_sizes[i] * 4);
    }
    int* row32  = (int*)alloc((size_t)E * 4);
    int* col32  = (int*)alloc((size_t)E * 4);
    int* indptr = (int*)alloc((size_t)(N + 1) * 4);
    int* cnt    = (int*)alloc((size_t)N * 4);
    int* colS   = (int*)alloc((size_t)E * 4);
    int* eidx   = (int*)alloc((size_t)E * 4);
    float* hs   = (float*)alloc((size_t)N * 4);
    float* hd   = (float*)alloc((size_t)N * 4);
    // hJK buffer: bf16 hlin during GAT phase; bf16 P/Q after the LSTM
    float* hJK  = (float*)alloc((size_t)N * 128 * 4);
    unsigned short* hlin = (unsigned short*)hJK;
    unsigned short* xsb = (unsigned short*)alloc((size_t)3 * N * 128 * 2);  // bf16 xs
    unsigned short* Bpack = (unsigned short*)alloc((size_t)2 * 10 * 48 * 512 * 2);
    unsigned short* Wg = (unsigned short*)alloc((size_t)2 * 4 * 8 * 512 * 2);
    unsigned short* Wt = (unsigned short*)alloc((size_t)4 * 24 * 512 * 2);
    float* bsum = (float*)alloc((size_t)2 * 768 * 4);
    float* scoreP = (float*)alloc((size_t)6 * N * 4);
    if (off > ws_size) return;
    unsigned short* P = (unsigned short*)hJK;           // bf16, N*128
    unsigned short* Q = (unsigned short*)hJK + (size_t)N * 128;

    InPtrs ip;
    for (int i = 0; i < NIN; ++i) { ip.p[i] = d_in[i]; ip.n[i] = in_sizes[i]; }

    k_sniff<<<NIN, 256, 0, stream>>>(ip, flags);

    // mega-prep: conv + edge decode/hist + all weight packs, one launch
    hipMemsetAsync(cnt, 0, (size_t)N * 4, stream);
    {
        PrepCfg C;
        int nj = 0, blk = 0;
        for (int i = 0; i < NIN; ++i) {
            if (skipCanon(i)) continue;
            C.src[nj] = d_in[i];
            C.dst[nj] = canon[i];
            C.n[nj] = in_sizes[i];
            C.ai[nj] = i;
            C.blk0[nj] = blk;
            blk += (in_sizes[i] + 255) / 256;
            ++nj;
        }
        C.blk0[nj] = blk;
        C.njobs = nj;
        C.cvB = blk;
        blk += (E + 255) / 256;                      C.wB = blk;
        blk += (2 * 10 * 48 * 512 + 255) / 256;      C.gB = blk;
        blk += (2 * 4 * 8 * 512 + 255) / 256;        C.tB = blk;
        blk += (4 * 24 * 512 + 255) / 256;
        C.esrc = d_in[1]; C.row = row32; C.col = col32; C.cnt = cnt; C.E = E;
        C.Wihf = d_in[10]; C.Whhf = d_in[11]; C.Wihb = d_in[14]; C.Whhb = d_in[15];
        C.bihf = d_in[12]; C.bhhf = d_in[13]; C.bihb = d_in[16]; C.bhhb = d_in[17];
        C.Bpack = Bpack; C.bsum = bsum;
        C.Wgsrc = d_in[6]; C.Wg = Wg;
        C.nW1src = d_in[20]; C.eW1src = d_in[24]; C.Wt = Wt;
        k_prep<<<blk, 256, 0, stream>>>(C, flags);
    }

    // CSR scan (scan3 also resets cnt for k_fill)
    const int nb1k = (N + 1023) / 1024;
    k_scan1<<<nb1k, 1024, 0, stream>>>(cnt, indptr, bsums, N);
    k_scan2<<<1, 64, 0, stream>>>(bsums, nb1k);
    k_scan3<<<(N + 255) / 256, 256, 0, stream>>>(bsums, indptr, cnt, N, nb1k);
    k_fill<<<(E + 255) / 256, 256, 0, stream>>>(row32, col32, indptr, cnt, colS, eidx, E);

    // GAT layer 0 (in=3)
    k_lin0<<<(N + 3) / 4, 256, 0, stream>>>(canon[0], canon[2], canon[4], canon[5],
                                            hlin, hs, hd, N);
    k_aggr<<<(N + 3) / 4, 256, 0, stream>>>(hlin, hs, hd, indptr, colS, canon[3], xsb, N);
    // GAT layers 1..2 (MFMA linear, bf16 in/out)
    for (int l = 1; l < 3; ++l) {
        const unsigned short* Wgl = Wg + (size_t)(l - 1) * 4 * 8 * 512;
        const float* bb = canon[7] + (size_t)(l - 1) * 128;
        const float* as = canon[8] + (size_t)(l - 1) * 128;
        const float* ad = canon[9] + (size_t)(l - 1) * 128;
        k_linm<<<(N + 63) / 64, 512, 0, stream>>>(xsb + (size_t)(l - 1) * N * 128, Wgl,
                                                  as, ad, hlin, hs, hd, N);
        k_aggr<<<(N + 3) / 4, 256, 0, stream>>>(hlin, hs, hd, indptr, colS, bb,
                                                xsb + (size_t)l * N * 128, N);
    }

    // fused bidirectional LSTM (MFMA, 64-row 12-wave) -> scores
    dim3 lgrid((N + 63) / 64, 2);
    k_lstm_mfma<<<lgrid, 768, 0, stream>>>(xsb, Bpack, bsum, canon[18], scoreP, N);

    float* out = (float*)d_out;
    // fused MFMA tail: JK finish + node MLP + P/Q
    k_tailm<<<(N + 63) / 64, 512, 0, stream>>>(xsb, scoreP, Wt,
                                               canon[21], canon[22], canon[23], canon[25],
                                               P, Q, out, N);
    // edge MLP in CSR order (P amortized per node; scatter via eidx)
    k_edge3<<<(N + 3) / 4, 256, 0, stream>>>(P, Q, indptr, colS, eidx,
                                             canon[26], canon[27], out, N);
}

// Round 20
// 577.425 us; speedup vs baseline: 1.2412x; 1.0109x over previous
//
#include <hip/hip_runtime.h>
#include <cstdint>
#include <cstddef>

// ---------------------------------------------------------------------------
// ParityGameGATNetwork: 3x GATConv -> JK bidirectional LSTM -> node/edge MLPs
// Round 20: launch-count attack (per-launch graph overhead ~5us measured):
// (a) k_lin0 folded into k_prep (reads raw inputs via flags); (b) cnt-zeroing
// folded into k_sniff; (c) k_scan2 folded into k_scan3 (redundant 256-wide
// LDS scan of block sums per block); (d) k_edge3 4-deep edge pipelining
// (avg degree 16 -> one latency chain per node). 16 -> 13 launches.
// ---------------------------------------------------------------------------

#define NIN 28
#define MAXJOBS 20

struct InPtrs { const void* p[NIN]; int n[NIN]; };

struct PrepCfg {
    const void* src[MAXJOBS];
    float* dst[MAXJOBS];
    int n[MAXJOBS];
    int ai[MAXJOBS];
    int blk0[MAXJOBS + 1];
    int njobs;
    int cvB, wB, gB, tB, l0B;            // block range starts for fixed jobs
    // conve
    const void* esrc; int* row; int* col; int* cnt; int E;
    // wpack (lstm)
    const void *Wihf, *Whhf, *Wihb, *Whhb, *bihf, *bhhf, *bihb, *bhhb;
    unsigned short* Bpack; float* bsum;
    // wpackg (gat W, raw input 6)
    const void* Wgsrc; unsigned short* Wg;
    // wpackt (nW1 input 20, eW1 input 24, raw)
    const void* nW1src; const void* eW1src; unsigned short* Wt;
    // lin0 (raw inputs 0,2,4,5)
    const void *xsrc0, *W0src, *as0src, *ad0src;
    unsigned short* hlin; float* hs; float* hd; int N;
};

typedef short s16x4 __attribute__((ext_vector_type(4)));
typedef short s16x8 __attribute__((ext_vector_type(8)));
typedef float f32x4 __attribute__((ext_vector_type(4)));
typedef unsigned short u16x8 __attribute__((ext_vector_type(8)));

__device__ __forceinline__ float bf2f(unsigned short v) {
    unsigned int u = ((unsigned int)v) << 16;
    return __uint_as_float(u);
}

__device__ __forceinline__ unsigned short f2bf(float x) {
    unsigned int u = __float_as_uint(x);
    unsigned int r = u + 0x7fffu + ((u >> 16) & 1u);
    return (unsigned short)(r >> 16);
}

__device__ __forceinline__ float rdx(const void* p, size_t i, int isf32) {
    return isf32 ? ((const float*)p)[i] : bf2f(((const unsigned short*)p)[i]);
}

__device__ __forceinline__ float frcp(float x) {        // raw v_rcp_f32 (~1ulp)
    return __builtin_amdgcn_rcpf(x);
}

__device__ __forceinline__ float sigm(float x) {
    return frcp(1.f + __expf(-x));
}

__device__ __forceinline__ float fast_tanh(float x) {
    return 1.f - 2.f * frcp(__expf(2.f * x) + 1.f);
}

// ---------------- dtype sniffing + cnt zeroing ------------------------------
__global__ void k_sniff(InPtrs in, int* flags, int* cntz, int N) {
    int ai = blockIdx.x;
    if (ai >= NIN) {                      // extra blocks: zero cnt
        int i = (ai - NIN) * 256 + threadIdx.x;
        if (i < N) cntz[i] = 0;
        return;
    }
    __shared__ int cnt;
    if (threadIdx.x == 0) cnt = 0;
    __syncthreads();
    if (ai == 1) {
        const int* w = (const int*)in.p[1];
        int nw = in.n[1] < 512 ? in.n[1] : 512;
        int local = 0;
        for (int i = threadIdx.x; i < nw; i += blockDim.x)
            if ((i & 1) && w[i] != 0) local++;
        atomicAdd(&cnt, local);
        __syncthreads();
        if (threadIdx.x == 0) flags[1] = (cnt < 4) ? 1 : 0;
        return;
    }
    const unsigned short* u = (const unsigned short*)in.p[ai];
    int ns = in.n[ai] < 256 ? in.n[ai] : 256;
    int local = 0;
    for (int i = threadIdx.x; i < ns; i += blockDim.x) {
        if (i & 1) continue;
        unsigned short v = u[i];
        int e = (v >> 7) & 0xff;
        if ((v & 0x7fff) != 0 && (e < 100 || e > 154)) local++;
    }
    atomicAdd(&cnt, local);
    __syncthreads();
    if (threadIdx.x == 0) flags[ai] = (cnt * 4 >= ns) ? 1 : 0;
}

// ---------------- mega prep: conv + edge decode/hist + packs + lin0 --------
__global__ void k_prep(PrepCfg C, const int* __restrict__ flags) {
    const int b = blockIdx.x;
    const int tid = threadIdx.x;
    if (b < C.cvB) {                     // canonicalization jobs
        int j = 0;
        while (j + 1 < C.njobs && b >= C.blk0[j + 1]) ++j;
        int i = (b - C.blk0[j]) * 256 + tid;
        if (i < C.n[j]) C.dst[j][i] = rdx(C.src[j], i, flags[C.ai[j]]);
        return;
    }
    if (b < C.wB) {                      // edge decode + histogram
        int i = (b - C.cvB) * 256 + tid;
        if (i >= C.E) return;
        int r, c;
        if (flags[1]) {
            const long long* s = (const long long*)C.esrc;
            r = (int)s[i];
            c = (int)s[(size_t)C.E + i];
        } else {
            const int* s = (const int*)C.esrc;
            r = s[i];
            c = s[(size_t)C.E + i];
        }
        C.row[i] = r;
        C.col[i] = c;
        atomicAdd(&C.cnt[r], 1);
        return;
    }
    if (b < C.gB) {                      // LSTM weight pack
        int idx = (b - C.wB) * 256 + tid;
        const int TOT = 2 * 10 * 48 * 512;
        if (idx < TOT) {
            int dir = idx / (10 * 48 * 512);
            int r   = idx % (10 * 48 * 512);
            int kb  = r / (48 * 512);
            int r2  = r % (48 * 512);
            int f   = r2 / 512;
            int q   = r2 % 512;
            int lane = q >> 3, j = q & 7;
            int k   = kb * 32 + ((j >> 2) * 16) + ((lane >> 4) * 4) + (j & 3);
            int col = f * 16 + (lane & 15);
            float v;
            if (k < 128)
                v = dir ? rdx(C.Wihb, (size_t)col * 128 + k, flags[14])
                        : rdx(C.Wihf, (size_t)col * 128 + k, flags[10]);
            else
                v = dir ? rdx(C.Whhb, (size_t)col * 192 + (k - 128), flags[15])
                        : rdx(C.Whhf, (size_t)col * 192 + (k - 128), flags[11]);
            C.Bpack[idx] = f2bf(v);
        }
        if (idx < 2 * 768) {
            int d = idx / 768, j = idx % 768;
            C.bsum[idx] = d ? rdx(C.bihb, j, flags[16]) + rdx(C.bhhb, j, flags[17])
                            : rdx(C.bihf, j, flags[12]) + rdx(C.bhhf, j, flags[13]);
        }
        return;
    }
    if (b < C.tB) {                      // GAT W pack (layers 1-2, raw input 6)
        int idx = (b - C.gB) * 256 + tid;
        if (idx >= 2 * 4 * 8 * 512) return;
        int layer = idx / 16384;
        int r  = idx % 16384;
        int kb = r / 4096;
        int r2 = r % 4096;
        int f  = r2 / 512;
        int q  = r2 % 512;
        int lane = q >> 3, j = q & 7;
        int k   = kb * 32 + ((j >> 2) * 16) + ((lane >> 4) * 4) + (j & 3);
        int col = f * 16 + (lane & 15);
        C.Wg[idx] = f2bf(rdx(C.Wgsrc, (size_t)layer * 16384 + (size_t)k * 128 + col,
                             flags[6]));
        return;
    }
    if (b < C.l0B) {                     // tail W pack (raw inputs 20/24)
        int idx = (b - C.tB) * 256 + tid;
        if (idx >= 4 * 24 * 512) return;
        int kb = idx / (24 * 512);
        int r  = idx % (24 * 512);
        int fr = r / 512;
        int q  = r % 512;
        int lane = q >> 3, j = q & 7;
        int k   = kb * 32 + ((j >> 2) * 16) + ((lane >> 4) * 4) + (j & 3);
        int grp = fr >> 3;
        int col = (fr & 7) * 16 + (lane & 15);
        float v;
        if (grp == 0)      v = rdx(C.nW1src, (size_t)k * 128 + col, flags[20]);
        else if (grp == 1) v = rdx(C.eW1src, (size_t)k * 128 + col, flags[24]);
        else               v = rdx(C.eW1src, (size_t)(128 + k) * 128 + col, flags[24]);
        C.Wt[idx] = f2bf(v);
        return;
    }
    {                                    // GAT layer-0 linear (raw inputs)
        const int wid = tid >> 6, lane = tid & 63;
        const int n = (b - C.l0B) * 4 + wid;
        if (n >= C.N) return;
        const int f32x = flags[0], f32w = flags[2];
        float x0 = rdx(C.xsrc0, (size_t)n * 3 + 0, f32x);
        float x1 = rdx(C.xsrc0, (size_t)n * 3 + 1, f32x);
        float x2 = rdx(C.xsrc0, (size_t)n * 3 + 2, f32x);
        const int c0 = lane, c1 = lane + 64;
        float h0 = x0 * rdx(C.W0src, c0, f32w) + x1 * rdx(C.W0src, 128 + c0, f32w)
                 + x2 * rdx(C.W0src, 256 + c0, f32w);
        float h1 = x0 * rdx(C.W0src, c1, f32w) + x1 * rdx(C.W0src, 128 + c1, f32w)
                 + x2 * rdx(C.W0src, 256 + c1, f32w);
        C.hlin[(size_t)n * 128 + c0] = f2bf(h0);
        C.hlin[(size_t)n * 128 + c1] = f2bf(h1);
        float sp = h0 * rdx(C.as0src, c0, flags[4]) + h1 * rdx(C.as0src, c1, flags[4]);
        float dp = h0 * rdx(C.ad0src, c0, flags[5]) + h1 * rdx(C.ad0src, c1, flags[5]);
        for (int o = 32; o; o >>= 1) { sp += __shfl_down(sp, o); dp += __shfl_down(dp, o); }
        if (lane == 0) { C.hs[n] = sp; C.hd[n] = dp; }
    }
}

// ---------------- CSR build ------------------------------------------------
__global__ void k_scan1(const int* __restrict__ deg, int* __restrict__ indptr,
                        int* __restrict__ bsums, int N) {
    __shared__ int buf[1024];
    const int t = threadIdx.x;
    const int base = blockIdx.x * 1024;
    int v = (base + t < N) ? deg[base + t] : 0;
    buf[t] = v;
    __syncthreads();
    for (int ofs = 1; ofs < 1024; ofs <<= 1) {
        int add = (t >= ofs) ? buf[t - ofs] : 0;
        __syncthreads();
        buf[t] += add;
        __syncthreads();
    }
    if (base + t < N) indptr[base + t] = buf[t] - v;
    if (t == 1023) bsums[blockIdx.x] = buf[1023];
}

// scan3: per-block redundant LDS scan of block sums (nb<=256) + apply + cnt
__global__ void k_scan3(const int* __restrict__ bsums, int* __restrict__ indptr,
                        int* __restrict__ cnt, int N, int nb) {
    __shared__ int buf[256];
    __shared__ int sh[258];
    const int t = threadIdx.x;
    if (nb <= 256) {
        int v = (t < nb) ? bsums[t] : 0;
        buf[t] = v;
        __syncthreads();
        for (int ofs = 1; ofs < 256; ofs <<= 1) {
            int add = (t >= ofs) ? buf[t - ofs] : 0;
            __syncthreads();
            buf[t] += add;
            __syncthreads();
        }
        if (t < nb) sh[t] = buf[t] - v;          // exclusive prefix
        if (t == 0) sh[nb] = buf[255];           // total
    } else {
        if (t == 0) {                            // robust fallback (unused here)
            int acc = 0;
            for (int j = 0; j < nb && j < 257; ++j) { sh[j] = acc; acc += bsums[j]; }
            sh[nb < 257 ? nb : 257] = acc;
        }
    }
    __syncthreads();
    int i = blockIdx.x * blockDim.x + t;
    if (i < N) {
        indptr[i] += sh[i >> 10];
        cnt[i] = 0;
    }
    if (i == 0) indptr[N] = sh[nb];
}

__global__ void k_fill(const int* __restrict__ row, const int* __restrict__ col,
                       const int* __restrict__ indptr, int* __restrict__ cur,
                       int* __restrict__ colS, int* __restrict__ eidx, int E) {
    int i = blockIdx.x * blockDim.x + threadIdx.x;
    if (i >= E) return;
    int r = row[i];
    int p = indptr[r] + atomicAdd(&cur[r], 1);
    colS[p] = col[i];
    eidx[p] = i;
}

// ---------------- GAT linear (MFMA): 64 nodes, 8 waves ---------------------
__global__ __launch_bounds__(512) void k_linm(
    const unsigned short* __restrict__ xin,   // [N][128] bf16
    const unsigned short* __restrict__ Wg,    // [4][8][512] bf16 (this layer)
    const float* __restrict__ asrc, const float* __restrict__ adst,
    unsigned short* __restrict__ hlin, float* __restrict__ hs, float* __restrict__ hd,
    int N) {
    __shared__ unsigned short AS[64][136];
    __shared__ float hsS[64], hdS[64];
    const int t = threadIdx.x;
    const int f = t >> 6, lane = t & 63;
    const int n0 = blockIdx.x * 64;
    const int ccol = lane & 15;
    const int klane = lane >> 4;
    const int lrow = klane * 4;
    const int akl = klane * 4;
    const int m = f * 16 + ccol;

    const float asv = asrc[m], adv = adst[m];

    for (int i = t; i < 1024; i += 512) {
        int r = i >> 4, kq = (i & 15) * 8;
        u16x8 v = (u16x8)(0);
        if (n0 + r < N) v = *(const u16x8*)(xin + (size_t)(n0 + r) * 128 + kq);
        *(u16x8*)&AS[r][kq] = v;
    }
    if (t < 64) { hsS[t] = 0.f; hdS[t] = 0.f; }
    __syncthreads();

    f32x4 acc[4];
    #pragma unroll
    for (int rf = 0; rf < 4; ++rf) acc[rf] = (f32x4)(0.f);
    #pragma unroll
    for (int kb = 0; kb < 4; ++kb) {
        s16x8 b = *(const s16x8*)(Wg + ((size_t)kb * 8 + f) * 512 + lane * 8);
        const int k0 = kb * 32 + akl;
        #pragma unroll
        for (int rf = 0; rf < 4; ++rf) {
            s16x4 alo = *(const s16x4*)&AS[rf * 16 + ccol][k0];
            s16x4 ahi = *(const s16x4*)&AS[rf * 16 + ccol][k0 + 16];
            s16x8 av = __builtin_shufflevector(alo, ahi, 0, 1, 2, 3, 4, 5, 6, 7);
            acc[rf] = __builtin_amdgcn_mfma_f32_16x16x32_bf16(av, b, acc[rf], 0, 0, 0);
        }
    }
    __syncthreads();   // all A reads done before h overwrite

    float sp[16], dp[16];
    #pragma unroll
    for (int rf = 0; rf < 4; ++rf) {
        #pragma unroll
        for (int reg = 0; reg < 4; ++reg) {
            float h = acc[rf][reg];
            int ci = rf * 4 + reg;
            AS[rf * 16 + lrow + reg][m] = f2bf(h);
            sp[ci] = h * asv;
            dp[ci] = h * adv;
        }
    }
    #pragma unroll
    for (int o = 1; o < 16; o <<= 1) {
        #pragma unroll
        for (int i = 0; i < 16; ++i) { sp[i] += __shfl_xor(sp[i], o); dp[i] += __shfl_xor(dp[i], o); }
    }
    if (ccol == 0) {
        #pragma unroll
        for (int i = 0; i < 16; ++i) {
            int row = (i >> 2) * 16 + lrow + (i & 3);
            atomicAdd(&hsS[row], sp[i]);
            atomicAdd(&hdS[row], dp[i]);
        }
    }
    __syncthreads();

    for (int i = t; i < 1024; i += 512) {
        int r = i >> 4, kq = (i & 15) * 8;
        if (n0 + r < N)
            *(u16x8*)(hlin + (size_t)(n0 + r) * 128 + kq) = *(const u16x8*)&AS[r][kq];
    }
    if (t < 64 && n0 + t < N) { hs[n0 + t] = hsS[t]; hd[n0 + t] = hdS[t]; }
}

// ---------------- GAT aggregation: online segment softmax ------------------
// Lane owns channels (2*lane, 2*lane+1): one 4B gather per edge per lane.
__global__ __launch_bounds__(256) void k_aggr(
    const unsigned short* __restrict__ hlin, const float* __restrict__ hs,
    const float* __restrict__ hd,
    const int* __restrict__ indptr, const int* __restrict__ colS,
    const float* __restrict__ b, unsigned short* __restrict__ xout, int N) {
    const int wid = threadIdx.x >> 6, lane = threadIdx.x & 63;
    const int n = blockIdx.x * 4 + wid;
    if (n >= N) return;
    const int s = indptr[n], epos = indptr[n + 1];
    const float hdv = hd[n];
    const int c0 = lane * 2, c1 = lane * 2 + 1;
    float m = -1e30f, d = 0.f, a0 = 0.f, a1 = 0.f;
    int idx = s;
    for (; idx + 8 <= epos; idx += 8) {
        int cl[8];
        #pragma unroll
        for (int j = 0; j < 8; ++j) cl[j] = colS[idx + j];
        float e[8];
        #pragma unroll
        for (int j = 0; j < 8; ++j) {
            float ev = hs[cl[j]] + hdv;
            e[j] = (ev > 0.f) ? ev : 0.2f * ev;
        }
        unsigned int hw[8];
        #pragma unroll
        for (int j = 0; j < 8; ++j)
            hw[j] = *(const unsigned int*)(hlin + (size_t)cl[j] * 128 + c0);
        float m8 = e[0];
        #pragma unroll
        for (int j = 1; j < 8; ++j) m8 = fmaxf(m8, e[j]);
        if (m8 > m) {
            float sc = __expf(m - m8);
            a0 *= sc; a1 *= sc; d *= sc; m = m8;
        }
        #pragma unroll
        for (int j = 0; j < 8; ++j) {
            float w = __expf(e[j] - m);
            a0 += w * bf2f((unsigned short)(hw[j] & 0xffffu));
            a1 += w * bf2f((unsigned short)(hw[j] >> 16));
            d  += w;
        }
    }
    for (; idx < epos; ++idx) {
        int col = colS[idx];
        float e = hs[col] + hdv;
        e = (e > 0.f) ? e : 0.2f * e;
        unsigned int hw = *(const unsigned int*)(hlin + (size_t)col * 128 + c0);
        float v0 = bf2f((unsigned short)(hw & 0xffffu));
        float v1 = bf2f((unsigned short)(hw >> 16));
        if (e > m) {
            float sc = __expf(m - e);
            a0 = a0 * sc + v0;
            a1 = a1 * sc + v1;
            d  = d * sc + 1.f;
            m  = e;
        } else {
            float w = __expf(e - m);
            a0 += w * v0;
            a1 += w * v1;
            d  += w;
        }
    }
    float inv = frcp(d + 1e-16f);
    float r0 = a0 * inv + b[c0];
    float r1 = a1 * inv + b[c1];
    unsigned int ow = (unsigned int)f2bf(fmaxf(r0, 0.f))
                    | ((unsigned int)f2bf(fmaxf(r1, 0.f)) << 16);
    *(unsigned int*)(xout + (size_t)n * 128 + c0) = ow;
}

// ---------------- fused bidirectional LSTM: 64 rows, 12 waves --------------
__global__ __launch_bounds__(768, 3) void k_lstm_mfma(
    const unsigned short* __restrict__ xsb,  // [3][N][128] bf16
    const unsigned short* __restrict__ Bpack,// [2][10][48][512] bf16
    const float* __restrict__ bsum,          // [2][768]
    const float* __restrict__ attW,          // [384]
    float* __restrict__ scoreP,              // [2][3][N]
    int N) {
    __shared__ unsigned short AS[64][332];   // x:[0,128)  h:[128,320)
    __shared__ float scoreS[64];
    const int t = threadIdx.x;
    const int bf = t >> 6, lane = t & 63;
    const int dir = blockIdx.y;
    const int n0 = blockIdx.x * 64;
    const int ccol = lane & 15;
    const int klane = lane >> 4;
    const int lrow = klane * 4;
    const int akl = klane * 4;
    const int m = bf * 16 + ccol;            // this thread's hidden unit

    const float bI = bsum[dir * 768 + m];
    const float bF = bsum[dir * 768 + 192 + m];
    const float bG = bsum[dir * 768 + 384 + m];
    const float bO = bsum[dir * 768 + 576 + m];
    const float awt = attW[dir * 192 + m];
    float cst[16];
    #pragma unroll
    for (int i = 0; i < 16; ++i) cst[i] = 0.f;

    const unsigned short* Bd = Bpack + (size_t)dir * 10 * 48 * 512;

    // ---- prologue: stage x for s=0 ----
    {
        const int l0 = dir ? 2 : 0;
        const unsigned short* xsrc = xsb + ((size_t)l0 * N + n0) * 128;
        for (int i = t; i < 1024; i += 768) {
            int r = i >> 4, kq = (i & 15) * 8;
            u16x8 v = (u16x8)(0);
            if (n0 + r < N) v = *(const u16x8*)(xsrc + (size_t)r * 128 + kq);
            *(u16x8*)&AS[r][kq] = v;
        }
    }
    if (t < 64) scoreS[t] = 0.f;
    __syncthreads();

    for (int s = 0; s < 3; ++s) {
        const int l = dir ? (2 - s) : s;

        // ---- MFMA GEMM over K, B ping-pong prefetch ----
        const int KB = s ? 10 : 4;               // both even
        f32x4 acc[4][4];
        #pragma unroll
        for (int rf = 0; rf < 4; ++rf)
            #pragma unroll
            for (int g = 0; g < 4; ++g) acc[rf][g] = (f32x4)(0.f);
        s16x8 bA[4], bB[4];
        {
            const unsigned short* bb = Bd + (size_t)bf * 512 + lane * 8;   // kb=0
            #pragma unroll
            for (int g = 0; g < 4; ++g) bA[g] = *(const s16x8*)(bb + (size_t)g * 6144);
        }
        for (int kb = 0; kb < KB; kb += 2) {
            {   // prefetch kb+1
                const unsigned short* bb = Bd + ((size_t)(kb + 1) * 48 + bf) * 512 + lane * 8;
                #pragma unroll
                for (int g = 0; g < 4; ++g) bB[g] = *(const s16x8*)(bb + (size_t)g * 6144);
            }
            {   // compute kb on bA
                const int k0 = kb * 32 + akl;
                s16x8 av[4];
                #pragma unroll
                for (int rf = 0; rf < 4; ++rf) {
                    s16x4 alo = *(const s16x4*)&AS[rf * 16 + ccol][k0];
                    s16x4 ahi = *(const s16x4*)&AS[rf * 16 + ccol][k0 + 16];
                    av[rf] = __builtin_shufflevector(alo, ahi, 0, 1, 2, 3, 4, 5, 6, 7);
                }
                #pragma unroll
                for (int rf = 0; rf < 4; ++rf)
                    #pragma unroll
                    for (int g = 0; g < 4; ++g)
                        acc[rf][g] = __builtin_amdgcn_mfma_f32_16x16x32_bf16(
                            av[rf], bA[g], acc[rf][g], 0, 0, 0);
            }
            if (kb + 2 < KB) {   // prefetch kb+2
                const unsigned short* bb = Bd + ((size_t)(kb + 2) * 48 + bf) * 512 + lane * 8;
                #pragma unroll
                for (int g = 0; g < 4; ++g) bA[g] = *(const s16x8*)(bb + (size_t)g * 6144);
            }
            {   // compute kb+1 on bB
                const int k0 = (kb + 1) * 32 + akl;
                s16x8 av[4];
                #pragma unroll
                for (int rf = 0; rf < 4; ++rf) {
                    s16x4 alo = *(const s16x4*)&AS[rf * 16 + ccol][k0];
                    s16x4 ahi = *(const s16x4*)&AS[rf * 16 + ccol][k0 + 16];
                    av[rf] = __builtin_shufflevector(alo, ahi, 0, 1, 2, 3, 4, 5, 6, 7);
                }
                #pragma unroll
                for (int rf = 0; rf < 4; ++rf)
                    #pragma unroll
                    for (int g = 0; g < 4; ++g)
                        acc[rf][g] = __builtin_amdgcn_mfma_f32_16x16x32_bf16(
                            av[rf], bB[g], acc[rf][g], 0, 0, 0);
            }
        }
        __syncthreads();   // SYNC2: all A reads done (x region now dead)

        // ---- issue next-layer x loads into registers (hidden under epilogue)
        u16x8 nx0 = (u16x8)(0), nx1 = (u16x8)(0);
        if (s < 2) {
            const int ln = dir ? (1 - s) : (s + 1);
            const unsigned short* xsrc = xsb + ((size_t)ln * N + n0) * 128;
            {
                int r = t >> 4, kq = (t & 15) * 8;
                if (n0 + r < N) nx0 = *(const u16x8*)(xsrc + (size_t)r * 128 + kq);
            }
            if (t < 256) {
                int i = t + 768, r = i >> 4, kq = (i & 15) * 8;
                if (n0 + r < N) nx1 = *(const u16x8*)(xsrc + (size_t)r * 128 + kq);
            }
        }

        // ---- cell epilogue: one unit per thread, 16 rows (rcp-based) ----
        float sp[16];
        #pragma unroll
        for (int rf = 0; rf < 4; ++rf) {
            #pragma unroll
            for (int reg = 0; reg < 4; ++reg) {
                float gI = acc[rf][0][reg] + bI;
                float gF = acc[rf][1][reg] + bF;
                float gG = acc[rf][2][reg] + bG;
                float gO = acc[rf][3][reg] + bO;
                float ig = sigm(gI);
                float fg = sigm(gF);
                float gt = fast_tanh(gG);
                float og = sigm(gO);
                int ci = rf * 4 + reg;
                float cn = fg * cst[ci] + ig * gt;
                cst[ci] = cn;
                float hh = og * fast_tanh(cn);
                AS[rf * 16 + lrow + reg][128 + m] = f2bf(hh);
                sp[ci] = hh * awt;
            }
        }
        #pragma unroll
        for (int o = 1; o < 16; o <<= 1) {
            #pragma unroll
            for (int i = 0; i < 16; ++i) sp[i] += __shfl_xor(sp[i], o);
        }
        if (ccol == 0) {
            #pragma unroll
            for (int i = 0; i < 16; ++i)
                atomicAdd(&scoreS[(i >> 2) * 16 + lrow + (i & 3)], sp[i]);
        }

        // ---- write staged next-x into LDS x region ----
        if (s < 2) {
            {
                int r = t >> 4, kq = (t & 15) * 8;
                *(u16x8*)&AS[r][kq] = nx0;
            }
            if (t < 256) {
                int i = t + 768, r = i >> 4, kq = (i & 15) * 8;
                *(u16x8*)&AS[r][kq] = nx1;
            }
        }
        __syncthreads();   // SYNC3: h writes + score atomics + x staging

        if (t < 64) {
            if (n0 + t < N)
                scoreP[(size_t)(dir * 3 + l) * N + n0 + t] = scoreS[t];
            scoreS[t] = 0.f;   // reset; visible before next epilogue (SYNC2)
        }
    }
}

// ---------------- fused MFMA tail: JK sum + node MLP + P/Q, 64 nodes -------
__global__ __launch_bounds__(512) void k_tailm(
    const unsigned short* __restrict__ xsb, const float* __restrict__ scoreP,
    const unsigned short* __restrict__ Wt,   // [4][24][512] bf16
    const float* __restrict__ nb1, const float* __restrict__ nW2,
    const float* __restrict__ nb2, const float* __restrict__ eb1,
    unsigned short* __restrict__ P, unsigned short* __restrict__ Q,
    float* __restrict__ out, int N) {
    __shared__ unsigned short AS[64][136];
    __shared__ float al[64][4];
    __shared__ float lgt[64][2];
    const int t = threadIdx.x;
    const int f = t >> 6, lane = t & 63;
    const int n0 = blockIdx.x * 64;
    const int ccol = lane & 15;
    const int klane = lane >> 4;
    const int lrow = klane * 4;
    const int akl = klane * 4;
    const int m = f * 16 + ccol;                 // output col in [0,128)

    if (t < 64) {
        int n = n0 + t;
        float e0 = 0.f, e1 = 0.f, e2 = 0.f;
        if (n < N) {
            float s0 = scoreP[n]                 + scoreP[(size_t)3 * N + n];
            float s1 = scoreP[(size_t)N + n]     + scoreP[(size_t)4 * N + n];
            float s2 = scoreP[(size_t)2 * N + n] + scoreP[(size_t)5 * N + n];
            float mm = fmaxf(s0, fmaxf(s1, s2));
            e0 = __expf(s0 - mm); e1 = __expf(s1 - mm); e2 = __expf(s2 - mm);
            float inv = frcp(e0 + e1 + e2);
            e0 *= inv; e1 *= inv; e2 *= inv;
        }
        al[t][0] = e0; al[t][1] = e1; al[t][2] = e2;
        lgt[t][0] = 0.f; lgt[t][1] = 0.f;
    }
    __syncthreads();

    const size_t L1o = (size_t)N * 128, L2o = 2 * L1o;
    for (int i = t; i < 1024; i += 512) {
        int r = i >> 4, kq = (i & 15) * 8;
        u16x8 o8 = (u16x8)(0);
        if (n0 + r < N) {
            size_t base = (size_t)(n0 + r) * 128 + kq;
            u16x8 a = *(const u16x8*)(xsb + base);
            u16x8 b = *(const u16x8*)(xsb + L1o + base);
            u16x8 c = *(const u16x8*)(xsb + L2o + base);
            float w0 = al[r][0], w1 = al[r][1], w2 = al[r][2];
            #pragma unroll
            for (int j = 0; j < 8; ++j)
                o8[j] = f2bf(w0 * bf2f(a[j]) + w1 * bf2f(b[j]) + w2 * bf2f(c[j]));
        }
        *(u16x8*)&AS[r][kq] = o8;
    }
    __syncthreads();

    f32x4 accN[4], accP[4], accQ[4];
    #pragma unroll
    for (int rf = 0; rf < 4; ++rf) { accN[rf] = (f32x4)(0.f); accP[rf] = (f32x4)(0.f); accQ[rf] = (f32x4)(0.f); }
    #pragma unroll
    for (int kb = 0; kb < 4; ++kb) {
        s16x8 bN = *(const s16x8*)(Wt + ((size_t)kb * 24 + f) * 512 + lane * 8);
        s16x8 bP = *(const s16x8*)(Wt + ((size_t)kb * 24 + 8 + f) * 512 + lane * 8);
        s16x8 bQ = *(const s16x8*)(Wt + ((size_t)kb * 24 + 16 + f) * 512 + lane * 8);
        const int k0 = kb * 32 + akl;
        #pragma unroll
        for (int rf = 0; rf < 4; ++rf) {
            s16x4 alo = *(const s16x4*)&AS[rf * 16 + ccol][k0];
            s16x4 ahi = *(const s16x4*)&AS[rf * 16 + ccol][k0 + 16];
            s16x8 av = __builtin_shufflevector(alo, ahi, 0, 1, 2, 3, 4, 5, 6, 7);
            accN[rf] = __builtin_amdgcn_mfma_f32_16x16x32_bf16(av, bN, accN[rf], 0, 0, 0);
            accP[rf] = __builtin_amdgcn_mfma_f32_16x16x32_bf16(av, bP, accP[rf], 0, 0, 0);
            accQ[rf] = __builtin_amdgcn_mfma_f32_16x16x32_bf16(av, bQ, accQ[rf], 0, 0, 0);
        }
    }
    __syncthreads();   // all A reads done before overwrite

    {
        const float nb1v = nb1[m];
        const float w20 = nW2[2 * m], w21 = nW2[2 * m + 1];
        float s0[16], s1[16];
        #pragma unroll
        for (int rf = 0; rf < 4; ++rf) {
            #pragma unroll
            for (int reg = 0; reg < 4; ++reg) {
                float h = fmaxf(accN[rf][reg] + nb1v, 0.f);
                int ci = rf * 4 + reg;
                s0[ci] = h * w20;
                s1[ci] = h * w21;
            }
        }
        #pragma unroll
        for (int o = 1; o < 16; o <<= 1) {
            #pragma unroll
            for (int i = 0; i < 16; ++i) { s0[i] += __shfl_xor(s0[i], o); s1[i] += __shfl_xor(s1[i], o); }
        }
        if (ccol == 0) {
            #pragma unroll
            for (int i = 0; i < 16; ++i) {
                int row = (i >> 2) * 16 + lrow + (i & 3);
                atomicAdd(&lgt[row][0], s0[i]);
                atomicAdd(&lgt[row][1], s1[i]);
            }
        }
    }
    {
        const float eb1v = eb1[m];
        #pragma unroll
        for (int rf = 0; rf < 4; ++rf)
            #pragma unroll
            for (int reg = 0; reg < 4; ++reg)
                AS[rf * 16 + lrow + reg][m] = f2bf(accP[rf][reg] + eb1v);
    }
    __syncthreads();
    if (t < 64 && n0 + t < N) {
        float l0 = lgt[t][0] + nb2[0], l1 = lgt[t][1] + nb2[1];
        float mm = fmaxf(l0, l1);
        float e0 = __expf(l0 - mm), e1 = __expf(l1 - mm);
        float inv = frcp(e0 + e1);
        out[2 * (size_t)(n0 + t)]     = e0 * inv;
        out[2 * (size_t)(n0 + t) + 1] = e1 * inv;
    }
    for (int i = t; i < 1024; i += 512) {
        int r = i >> 4, kq = (i & 15) * 8;
        if (n0 + r < N)
            *(u16x8*)(P + (size_t)(n0 + r) * 128 + kq) = *(const u16x8*)&AS[r][kq];
    }
    __syncthreads();
    #pragma unroll
    for (int rf = 0; rf < 4; ++rf)
        #pragma unroll
        for (int reg = 0; reg < 4; ++reg)
            AS[rf * 16 + lrow + reg][m] = f2bf(accQ[rf][reg]);
    __syncthreads();
    for (int i = t; i < 1024; i += 512) {
        int r = i >> 4, kq = (i & 15) * 8;
        if (n0 + r < N)
            *(u16x8*)(Q + (size_t)(n0 + r) * 128 + kq) = *(const u16x8*)&AS[r][kq];
    }
}

// ---------------- edge MLP finish: CSR order, 4-deep edge pipeline ---------
__global__ __launch_bounds__(256) void k_edge3(
    const unsigned short* __restrict__ P, const unsigned short* __restrict__ Q,
    const int* __restrict__ indptr, const int* __restrict__ colS,
    const int* __restrict__ eidx,
    const float* __restrict__ W2, const float* __restrict__ b2,
    float* __restrict__ out, int N) {
    const int wid = threadIdx.x >> 6, lane = threadIdx.x & 63;
    const int n = blockIdx.x * 4 + wid;
    if (n >= N) return;
    const int sl = lane & 15, g = lane >> 4;
    const int s = indptr[n], e = indptr[n + 1];
    float pf[8];
    {
        u16x8 pv = *(const u16x8*)(P + (size_t)n * 128 + sl * 8);
        #pragma unroll
        for (int j = 0; j < 8; ++j) pf[j] = bf2f(pv[j]);
    }
    const float* W2f = W2;
    const float b20 = b2[0], b21 = b2[1];
    for (int p = s + g; p < e; p += 16) {
        int pp[4];
        bool vv[4];
        int col[4], eo[4];
        #pragma unroll
        for (int k = 0; k < 4; ++k) {
            pp[k] = p + 4 * k;
            vv[k] = pp[k] < e;
            col[k] = vv[k] ? colS[pp[k]] : colS[p];
            eo[k]  = vv[k] ? eidx[pp[k]] : 0;
        }
        u16x8 qv[4];
        #pragma unroll
        for (int k = 0; k < 4; ++k)
            qv[k] = *(const u16x8*)(Q + (size_t)col[k] * 128 + sl * 8);
        float l0[4] = {0.f, 0.f, 0.f, 0.f}, l1[4] = {0.f, 0.f, 0.f, 0.f};
        #pragma unroll
        for (int j = 0; j < 8; ++j) {
            int ch = sl * 8 + j;
            float wA = W2f[ch * 2], wB = W2f[ch * 2 + 1];
            #pragma unroll
            for (int k = 0; k < 4; ++k) {
                float h = fmaxf(pf[j] + bf2f(qv[k][j]), 0.f);
                l0[k] += h * wA;
                l1[k] += h * wB;
            }
        }
        #pragma unroll
        for (int o = 1; o < 16; o <<= 1) {
            #pragma unroll
            for (int k = 0; k < 4; ++k) {
                l0[k] += __shfl_xor(l0[k], o);
                l1[k] += __shfl_xor(l1[k], o);
            }
        }
        if (sl == 0) {
            #pragma unroll
            for (int k = 0; k < 4; ++k) {
                if (!vv[k]) continue;
                float a = l0[k] + b20, bq = l1[k] + b21;
                float mm = fmaxf(a, bq);
                float e0 = __expf(a - mm), e1 = __expf(bq - mm);
                float inv = frcp(e0 + e1);
                out[2 * (size_t)N + 2 * (size_t)eo[k]]     = e0 * inv;
                out[2 * (size_t)N + 2 * (size_t)eo[k] + 1] = e1 * inv;
            }
        }
    }
}

// ---------------------------------------------------------------------------
extern "C" void kernel_launch(void* const* d_in, const int* in_sizes, int n_in,
                              void* d_out, int out_size, void* d_ws, size_t ws_size,
                              hipStream_t stream) {
    if (n_in < NIN) return;
    const int N = in_sizes[0] / 3;
    const int E = in_sizes[1] / 2;

    char* ws = (char*)d_ws;
    size_t off = 0;
    auto alloc = [&](size_t bytes) -> char* {
        char* p = ws + off;
        off = (off + bytes + 255) & ~(size_t)255;
        return p;
    };
    auto skipCanon = [](int i) {
        return i == 0 || i == 1 || i == 2 || i == 4 || i == 5 ||
               (i >= 10 && i <= 17) || i == 6 || i == 20 || i == 24;
    };
    int* flags = (int*)alloc(32 * sizeof(int));
    int* bsums = (int*)alloc(128 * sizeof(int));
    float* canon[NIN];
    for (int i = 0; i < NIN; ++i) canon[i] = nullptr;
    for (int i = 0; i < NIN; ++i) {
        if (skipCanon(i)) continue;      // these are read raw by k_prep
        canon[i] = (float*)alloc((size_t)in_sizes[i] * 4);
    }
    int* row32  = (int*)alloc((size_t)E * 4);
    int* col32  = (int*)alloc((size_t)E * 4);
    int* indptr = (int*)alloc((size_t)(N + 1) * 4);
    int* cnt    = (int*)alloc((size_t)N * 4);
    int* colS   = (int*)alloc((size_t)E * 4);
    int* eidx   = (int*)alloc((size_t)E * 4);
    float* hs   = (float*)alloc((size_t)N * 4);
    float* hd   = (float*)alloc((size_t)N * 4);
    // hJK buffer: bf16 hlin during GAT phase; bf16 P/Q after the LSTM
    float* hJK  = (float*)alloc((size_t)N * 128 * 4);
    unsigned short* hlin = (unsigned short*)hJK;
    unsigned short* xsb = (unsigned short*)alloc((size_t)3 * N * 128 * 2);  // bf16 xs
    unsigned short* Bpack = (unsigned short*)alloc((size_t)2 * 10 * 48 * 512 * 2);
    unsigned short* Wg = (unsigned short*)alloc((size_t)2 * 4 * 8 * 512 * 2);
    unsigned short* Wt = (unsigned short*)alloc((size_t)4 * 24 * 512 * 2);
    float* bsum = (float*)alloc((size_t)2 * 768 * 4);
    float* scoreP = (float*)alloc((size_t)6 * N * 4);
    if (off > ws_size) return;
    unsigned short* P = (unsigned short*)hJK;           // bf16, N*128
    unsigned short* Q = (unsigned short*)hJK + (size_t)N * 128;

    InPtrs ip;
    for (int i = 0; i < NIN; ++i) { ip.p[i] = d_in[i]; ip.n[i] = in_sizes[i]; }

    // sniff + cnt zeroing in one launch
    k_sniff<<<NIN + (N + 255) / 256, 256, 0, stream>>>(ip, flags, cnt, N);

    // mega-prep: conv + edge decode/hist + all weight packs + GAT layer-0 lin
    {
        PrepCfg C;
        int nj = 0, blk = 0;
        for (int i = 0; i < NIN; ++i) {
            if (skipCanon(i)) continue;
            C.src[nj] = d_in[i];
            C.dst[nj] = canon[i];
            C.n[nj] = in_sizes[i];
            C.ai[nj] = i;
            C.blk0[nj] = blk;
            blk += (in_sizes[i] + 255) / 256;
            ++nj;
        }
        C.blk0[nj] = blk;
        C.njobs = nj;
        C.cvB = blk;
        blk += (E + 255) / 256;                      C.wB = blk;
        blk += (2 * 10 * 48 * 512 + 255) / 256;      C.gB = blk;
        blk += (2 * 4 * 8 * 512 + 255) / 256;        C.tB = blk;
        blk += (4 * 24 * 512 + 255) / 256;           C.l0B = blk;
        blk += (N + 3) / 4;
        C.esrc = d_in[1]; C.row = row32; C.col = col32; C.cnt = cnt; C.E = E;
        C.Wihf = d_in[10]; C.Whhf = d_in[11]; C.Wihb = d_in[14]; C.Whhb = d_in[15];
        C.bihf = d_in[12]; C.bhhf = d_in[13]; C.bihb = d_in[16]; C.bhhb = d_in[17];
        C.Bpack = Bpack; C.bsum = bsum;
        C.Wgsrc = d_in[6]; C.Wg = Wg;
        C.nW1src = d_in[20]; C.eW1src = d_in[24]; C.Wt = Wt;
        C.xsrc0 = d_in[0]; C.W0src = d_in[2]; C.as0src = d_in[4]; C.ad0src = d_in[5];
        C.hlin = hlin; C.hs = hs; C.hd = hd; C.N = N;
        k_prep<<<blk, 256, 0, stream>>>(C, flags);
    }

    // CSR scan (scan3 does block-sum prefix in LDS + applies + resets cnt)
    const int nb1k = (N + 1023) / 1024;
    k_scan1<<<nb1k, 1024, 0, stream>>>(cnt, indptr, bsums, N);
    k_scan3<<<(N + 255) / 256, 256, 0, stream>>>(bsums, indptr, cnt, N, nb1k);
    k_fill<<<(E + 255) / 256, 256, 0, stream>>>(row32, col32, indptr, cnt, colS, eidx, E);

    // GAT layer 0 aggregation (lin0 already done inside k_prep)
    k_aggr<<<(N + 3) / 4, 256, 0, stream>>>(hlin, hs, hd, indptr, colS, canon[3], xsb, N);
    // GAT layers 1..2 (MFMA linear, bf16 in/out)
    for (int l = 1; l < 3; ++l) {
        const unsigned short* Wgl = Wg + (size_t)(l - 1) * 4 * 8 * 512;
        const float* bb = canon[7] + (size_t)(l - 1) * 128;
        const float* as = canon[8] + (size_t)(l - 1) * 128;
        const float* ad = canon[9] + (size_t)(l - 1) * 128;
        k_linm<<<(N + 63) / 64, 512, 0, stream>>>(xsb + (size_t)(l - 1) * N * 128, Wgl,
                                                  as, ad, hlin, hs, hd, N);
        k_aggr<<<(N + 3) / 4, 256, 0, stream>>>(hlin, hs, hd, indptr, colS, bb,
                                                xsb + (size_t)l * N * 128, N);
    }

    // fused bidirectional LSTM (MFMA, 64-row 12-wave) -> scores
    dim3 lgrid((N + 63) / 64, 2);
    k_lstm_mfma<<<lgrid, 768, 0, stream>>>(xsb, Bpack, bsum, canon[18], scoreP, N);

    float* out = (float*)d_out;
    // fused MFMA tail: JK finish + node MLP + P/Q
    k_tailm<<<(N + 63) / 64, 512, 0, stream>>>(xsb, scoreP, Wt,
                                               canon[21], canon[22], canon[23], canon[25],
                                               P, Q, out, N);
    // edge MLP in CSR order (P amortized per node; scatter via eidx)
    k_edge3<<<(N + 3) / 4, 256, 0, stream>>>(P, Q, indptr, colS, eidx,
                                             canon[26], canon[27], out, N);
}